// Round 9
// baseline (381.762 us; speedup 1.0000x reference)
//
#include <hip/hip_runtime.h>
#include <hip/hip_bf16.h>

#define BB 32
#define IDF 64
#define CDF 256
#define SSZ 1024
#define NH 8
#define LL 256
#define KHC 2048   // NH*CDF

typedef __attribute__((ext_vector_type(8))) short short8v;   // 8 bf16 (4 VGPR)
typedef __attribute__((ext_vector_type(4))) float f32x4;     // MFMA acc

__device__ inline void split_bf16(float x, __hip_bfloat16& h, __hip_bfloat16& l) {
  h = __float2bfloat16(x);
  l = __float2bfloat16(x - __bfloat162float(h));
}

// ---------------------------------------------------------------------------
// Split wc (fp32) -> wch, wcl (bf16 hi/lo), same [b][i][o] layout.
// ---------------------------------------------------------------------------
__global__ __launch_bounds__(256) void k_split_wc(const float* __restrict__ wc,
                                                  __hip_bfloat16* __restrict__ wch,
                                                  __hip_bfloat16* __restrict__ wcl) {
  int idx = (blockIdx.x * 256 + threadIdx.x) * 4;
  float4 v = *reinterpret_cast<const float4*>(&wc[idx]);
  __align__(16) __hip_bfloat16 hb[4], lb[4];
  split_bf16(v.x, hb[0], lb[0]); split_bf16(v.y, hb[1], lb[1]);
  split_bf16(v.z, hb[2], lb[2]); split_bf16(v.w, hb[3], lb[3]);
  *reinterpret_cast<int2*>(&wch[idx]) = *reinterpret_cast<int2*>(hb);
  *reinterpret_cast<int2*>(&wcl[idx]) = *reinterpret_cast<int2*>(lb);
}

// ---------------------------------------------------------------------------
// Split W (fp32, [h][o][c]) -> Wh, Wl (bf16, same layout). For K4.
// ---------------------------------------------------------------------------
__global__ __launch_bounds__(256) void k_split_W(const float* __restrict__ W,
                                                 __hip_bfloat16* __restrict__ Wh,
                                                 __hip_bfloat16* __restrict__ Wl) {
  int idx = (blockIdx.x * 256 + threadIdx.x) * 4;
  float4 v = *reinterpret_cast<const float4*>(&W[idx]);
  __align__(16) __hip_bfloat16 hb[4], lb[4];
  split_bf16(v.x, hb[0], lb[0]); split_bf16(v.y, hb[1], lb[1]);
  split_bf16(v.z, hb[2], lb[2]); split_bf16(v.w, hb[3], lb[3]);
  *reinterpret_cast<int2*>(&Wh[idx]) = *reinterpret_cast<int2*>(hb);
  *reinterpret_cast<int2*>(&Wl[idx]) = *reinterpret_cast<int2*>(lb);
}

// ---------------------------------------------------------------------------
// Split+transpose W[h][o][c] (fp32) -> Wt hi/lo [h][c][o] (bf16). For K1.
// ---------------------------------------------------------------------------
__global__ __launch_bounds__(256) void k_split_Wt(const float* __restrict__ W,
                                                  __hip_bfloat16* __restrict__ wth,
                                                  __hip_bfloat16* __restrict__ wtl) {
  __shared__ float Tt[64][65];   // [c][o]
  int blk = blockIdx.x;
  int h = blk >> 6, ot = (blk >> 2) & 15, ct = blk & 3;
  int og = ot * 64, cg = ct * 64;
  int t = threadIdx.x;
  int o_l = t >> 4, c4 = (t & 15) * 4;
#pragma unroll
  for (int p = 0; p < 4; ++p) {
    int o = o_l + 16 * p;
    float4 v = *reinterpret_cast<const float4*>(
        &W[((size_t)h * SSZ + og + o) * CDF + cg + c4]);
    Tt[c4 + 0][o] = v.x; Tt[c4 + 1][o] = v.y;
    Tt[c4 + 2][o] = v.z; Tt[c4 + 3][o] = v.w;
  }
  __syncthreads();
  int c_l = t >> 2;
#pragma unroll
  for (int p = 0; p < 4; ++p) {
    int oq = (t & 3) + 4 * p;
    int o0 = oq * 4;
    __hip_bfloat16 hv[4], lv[4];
#pragma unroll
    for (int j = 0; j < 4; ++j)
      split_bf16(Tt[c_l][o0 + j], hv[j], lv[j]);
    size_t base = ((size_t)h * CDF + cg + c_l) * SSZ + og + o0;
#pragma unroll
    for (int j = 0; j < 4; ++j) { wth[base + j] = hv[j]; wtl[base + j] = lv[j]; }
  }
}

// ---------------------------------------------------------------------------
// K1 (MFMA, LDS-free, 8-wave): M[bh][i][c] = sum_o wc[b][i][o] * W[h][o][c]
// grid 512 x 512 threads: (bh, nh-half of 128c). 8 waves x (64i x 16c).
// Wave state: acc 16 + 2 fragment sets (2x40) + addr ~= 120 VGPR -> fits the
// 128-VGPR / 4-waves-per-SIMD boundary (round-8 failure: 64x32 tile needed
// ~150 VGPR so regalloc sank the prefetch; this tile fits).
// sched_barrier(0) pins next-step loads above current-step MFMAs.
// ---------------------------------------------------------------------------
#define K1_STEP(KS, CAH, CAL, CBH, CBL, NAH, NAL, NBH, NBL)                    \
  {                                                                            \
    if ((KS) < 31) {                                                           \
      int nk0 = ((KS) + 1) * 32;                                               \
      _Pragma("unroll")                                                        \
      for (int r = 0; r < 4; ++r) {                                            \
        NAH[r] = *reinterpret_cast<const short8v*>(&gA_h[offA[r] + nk0]);      \
        NAL[r] = *reinterpret_cast<const short8v*>(&gA_l[offA[r] + nk0]);      \
      }                                                                        \
      NBH = *reinterpret_cast<const short8v*>(&gB_h[offB0 + nk0]);             \
      NBL = *reinterpret_cast<const short8v*>(&gB_l[offB0 + nk0]);             \
    }                                                                          \
    __builtin_amdgcn_sched_barrier(0);                                         \
    _Pragma("unroll")                                                          \
    for (int r = 0; r < 4; ++r) {                                              \
      acc[r] = __builtin_amdgcn_mfma_f32_16x16x32_bf16(CAH[r], CBH, acc[r], 0, 0, 0); \
      acc[r] = __builtin_amdgcn_mfma_f32_16x16x32_bf16(CAH[r], CBL, acc[r], 0, 0, 0); \
      acc[r] = __builtin_amdgcn_mfma_f32_16x16x32_bf16(CAL[r], CBH, acc[r], 0, 0, 0); \
    }                                                                          \
  }

__global__ __launch_bounds__(512, 4) void k1_mfma(const __hip_bfloat16* __restrict__ wch,
                                                  const __hip_bfloat16* __restrict__ wcl,
                                                  const __hip_bfloat16* __restrict__ wth,
                                                  const __hip_bfloat16* __restrict__ wtl,
                                                  float* __restrict__ Mout) {
  int blk = blockIdx.x;
  int bh = blk >> 1, nh = blk & 1;
  int b = bh >> 3, h = bh & 7;
  int t = threadIdx.x;
  int lane = t & 63, wave = t >> 6;          // wave 0..7
  int ln15 = lane & 15, kh = lane >> 4;

  const short* gA_h = (const short*)wch + (size_t)b * IDF * SSZ;
  const short* gA_l = (const short*)wcl + (size_t)b * IDF * SSZ;
  const short* gB_h = (const short*)wth + (size_t)(h * CDF + nh * 128) * SSZ;
  const short* gB_l = (const short*)wtl + (size_t)(h * CDF + nh * 128) * SSZ;

  int offA[4];
#pragma unroll
  for (int r = 0; r < 4; ++r) offA[r] = (r * 16 + ln15) * SSZ + kh * 8;
  int offB0 = (wave * 16 + ln15) * SSZ + kh * 8;

  f32x4 acc[4] = {};
  short8v a0h[4], a0l[4], a1h[4], a1l[4];
  short8v b0h, b0l, b1h, b1l;

  // prologue: load k-step 0 into set0
#pragma unroll
  for (int r = 0; r < 4; ++r) {
    a0h[r] = *reinterpret_cast<const short8v*>(&gA_h[offA[r]]);
    a0l[r] = *reinterpret_cast<const short8v*>(&gA_l[offA[r]]);
  }
  b0h = *reinterpret_cast<const short8v*>(&gB_h[offB0]);
  b0l = *reinterpret_cast<const short8v*>(&gB_l[offB0]);

#pragma unroll 1
  for (int ks = 0; ks < 32; ks += 2) {
    K1_STEP(ks,     a0h, a0l, b0h, b0l, a1h, a1l, b1h, b1l);
    K1_STEP(ks + 1, a1h, a1l, b1h, b1l, a0h, a0l, b0h, b0l);
  }

  float* out = Mout + (size_t)bh * IDF * CDF + nh * 128;
  int rowq = (lane >> 4) * 4;
#pragma unroll
  for (int r = 0; r < 4; ++r)
#pragma unroll
    for (int reg = 0; reg < 4; ++reg)
      out[(r * 16 + rowq + reg) * CDF + wave * 16 + ln15] = acc[r][reg];
}

// ---------------------------------------------------------------------------
// K2: logits[bh][i][l] = sum_c M[bh][i][c] * ctx[b][c][l]; softmax over l.
// grid 512: (bh, i-half of 32). acc[4][8].
// ---------------------------------------------------------------------------
__global__ __launch_bounds__(256) void k_attn(const float* __restrict__ Mm,
                                              const float* __restrict__ ctx,
                                              float* __restrict__ attn) {
  __shared__ float As[32][32];
  __shared__ float Bs[32][LL];
  int blk = blockIdx.x;
  int bh = blk >> 1, ih = blk & 1;
  int b = bh >> 3;
  int ibase = ih * 32;
  const float* A  = Mm + ((size_t)bh * IDF + ibase) * CDF;
  const float* Bm = ctx + (size_t)b * CDF * LL;
  int tid = threadIdx.x;
  int tc = tid & 31, ti = tid >> 5;
  int c0 = tc * 8, i0 = ti * 4;
  float acc[4][8];
#pragma unroll
  for (int r = 0; r < 4; ++r)
#pragma unroll
    for (int s = 0; s < 8; ++s) acc[r][s] = 0.f;

  for (int k0 = 0; k0 < CDF; k0 += 32) {
    {                                        // A tile: 32 rows x 8 f4
      int row = tid >> 3, seg = tid & 7;
      *reinterpret_cast<float4*>(&As[row][seg * 4]) =
          *reinterpret_cast<const float4*>(&A[row * CDF + k0 + seg * 4]);
    }
#pragma unroll
    for (int p = 0; p < 8; ++p) {            // B tile: 32 rows x 64 f4
      int f = tid + p * 256;
      int kk = f >> 6, cs = f & 63;
      *reinterpret_cast<float4*>(&Bs[kk][cs * 4]) =
          *reinterpret_cast<const float4*>(&Bm[(size_t)(k0 + kk) * LL + cs * 4]);
    }
    __syncthreads();
#pragma unroll
    for (int kq = 0; kq < 8; ++kq) {
      float4 av[4];
#pragma unroll
      for (int r = 0; r < 4; ++r)
        av[r] = *reinterpret_cast<const float4*>(&As[i0 + r][kq * 4]);
#pragma unroll
      for (int kk = 0; kk < 4; ++kk) {
        float4 b0 = *reinterpret_cast<const float4*>(&Bs[kq * 4 + kk][c0]);
        float4 b1 = *reinterpret_cast<const float4*>(&Bs[kq * 4 + kk][c0 + 4]);
        float bv[8] = {b0.x, b0.y, b0.z, b0.w, b1.x, b1.y, b1.z, b1.w};
#pragma unroll
        for (int r = 0; r < 4; ++r) {
          float a = (kk == 0) ? av[r].x : (kk == 1) ? av[r].y : (kk == 2) ? av[r].z : av[r].w;
#pragma unroll
          for (int s = 0; s < 8; ++s) acc[r][s] += a * bv[s];
        }
      }
    }
    __syncthreads();
  }
  float* out = attn + ((size_t)bh * IDF + ibase) * LL;
#pragma unroll
  for (int r = 0; r < 4; ++r) {
    float mx = acc[r][0];
#pragma unroll
    for (int s = 1; s < 8; ++s) mx = fmaxf(mx, acc[r][s]);
#pragma unroll
    for (int m = 16; m >= 1; m >>= 1) mx = fmaxf(mx, __shfl_xor(mx, m, 64));
    float ex[8]; float sum = 0.f;
#pragma unroll
    for (int s = 0; s < 8; ++s) { ex[s] = __expf(acc[r][s] - mx); sum += ex[s]; }
#pragma unroll
    for (int m = 16; m >= 1; m >>= 1) sum += __shfl_xor(sum, m, 64);
    float inv = 1.f / sum;
    float4 v0 = {ex[0] * inv, ex[1] * inv, ex[2] * inv, ex[3] * inv};
    float4 v1 = {ex[4] * inv, ex[5] * inv, ex[6] * inv, ex[7] * inv};
    *reinterpret_cast<float4*>(&out[(i0 + r) * LL + c0]) = v0;
    *reinterpret_cast<float4*>(&out[(i0 + r) * LL + c0 + 4]) = v1;
  }
}

// ---------------------------------------------------------------------------
// K3: N2{h,l}[b][i][h*256+c] = split(sum_l attn[bh][i][l]*ctx[b][c][l])
// grid 512: (bh, c-half of 128). acc[4][8].
// ---------------------------------------------------------------------------
__global__ __launch_bounds__(256) void k_N2(const float* __restrict__ attn,
                                            const float* __restrict__ ctx,
                                            __hip_bfloat16* __restrict__ N2h,
                                            __hip_bfloat16* __restrict__ N2l) {
  __shared__ float As[IDF][32];    // [i][l]
  __shared__ float Bs[32][132];    // [l][c], padded
  int blk = blockIdx.x;
  int bh = blk >> 1, ch = blk & 1;
  int b = bh >> 3, h = bh & 7;
  int cgbase = ch * 128;
  const float* A  = attn + (size_t)bh * IDF * LL;
  const float* Cm = ctx + ((size_t)b * CDF + cgbase) * LL;
  int tid = threadIdx.x;
  int tc = tid & 15, ti = tid >> 4;
  int c0 = tc * 8, i0 = ti * 4;
  float acc[4][8];
#pragma unroll
  for (int r = 0; r < 4; ++r)
#pragma unroll
    for (int s = 0; s < 8; ++s) acc[r][s] = 0.f;

  for (int l0 = 0; l0 < LL; l0 += 32) {
#pragma unroll
    for (int p = 0; p < 2; ++p) {            // attn tile: 64 rows x 8 f4
      int f = tid + p * 256;
      int row = f >> 3, seg = f & 7;
      *reinterpret_cast<float4*>(&As[row][seg * 4]) =
          *reinterpret_cast<const float4*>(&A[row * LL + l0 + seg * 4]);
    }
#pragma unroll
    for (int p = 0; p < 4; ++p) {            // ctx tile: transpose-stage 128 rows
      int f = tid + p * 256;
      int c = f >> 3, seg = f & 7;
      float4 v = *reinterpret_cast<const float4*>(&Cm[(size_t)c * LL + l0 + seg * 4]);
      Bs[seg * 4 + 0][c] = v.x; Bs[seg * 4 + 1][c] = v.y;
      Bs[seg * 4 + 2][c] = v.z; Bs[seg * 4 + 3][c] = v.w;
    }
    __syncthreads();
#pragma unroll
    for (int kq = 0; kq < 8; ++kq) {
      float4 av[4];
#pragma unroll
      for (int r = 0; r < 4; ++r)
        av[r] = *reinterpret_cast<const float4*>(&As[i0 + r][kq * 4]);
#pragma unroll
      for (int kk = 0; kk < 4; ++kk) {
        float4 b0 = *reinterpret_cast<const float4*>(&Bs[kq * 4 + kk][c0]);
        float4 b1 = *reinterpret_cast<const float4*>(&Bs[kq * 4 + kk][c0 + 4]);
        float bv[8] = {b0.x, b0.y, b0.z, b0.w, b1.x, b1.y, b1.z, b1.w};
#pragma unroll
        for (int r = 0; r < 4; ++r) {
          float a = (kk == 0) ? av[r].x : (kk == 1) ? av[r].y : (kk == 2) ? av[r].z : av[r].w;
#pragma unroll
          for (int s = 0; s < 8; ++s) acc[r][s] += a * bv[s];
        }
      }
    }
    __syncthreads();
  }
  // epilogue: split to bf16 hi/lo, write [b][i][h*256 + cgbase + c]
  size_t base = (size_t)b * IDF * KHC + h * CDF + cgbase;
#pragma unroll
  for (int r = 0; r < 4; ++r) {
    __align__(16) __hip_bfloat16 hb[8], lb[8];
#pragma unroll
    for (int s = 0; s < 8; ++s) split_bf16(acc[r][s], hb[s], lb[s]);
    size_t idx = base + (size_t)(i0 + r) * KHC + c0;
    *reinterpret_cast<int4*>(&N2h[idx]) = *reinterpret_cast<int4*>(hb);
    *reinterpret_cast<int4*>(&N2l[idx]) = *reinterpret_cast<int4*>(lb);
  }
}

// ---------------------------------------------------------------------------
// K4 (MFMA, LDS-free, 8-wave): ctx_out[b][i][o] = sum_{hc} N2[b][i][hc]*W[h][o][c]
// grid 512 x 512 threads: g(2 K-halves) x b(32) x ot(8 of 128 o).
// 8 waves x (64i x 16o). Same pipeline rationale as k1_mfma.
// ---------------------------------------------------------------------------
#define K4_STEP(KS, CAH, CAL, CBH, CBL, NAH, NAL, NBH, NBL)                    \
  {                                                                            \
    if ((KS) < 31) {                                                           \
      int nkk0 = kbase + ((KS) + 1) * 32;                                      \
      int nh4 = nkk0 >> 8, ncb = nkk0 & 255;                                   \
      size_t wb = (size_t)nh4 * SSZ * CDF + ncb;                               \
      _Pragma("unroll")                                                        \
      for (int r = 0; r < 4; ++r) {                                            \
        NAH[r] = *reinterpret_cast<const short8v*>(&gA_h[offA[r] + nkk0]);     \
        NAL[r] = *reinterpret_cast<const short8v*>(&gA_l[offA[r] + nkk0]);     \
      }                                                                        \
      NBH = *reinterpret_cast<const short8v*>(&gB_h[wb + offB0]);              \
      NBL = *reinterpret_cast<const short8v*>(&gB_l[wb + offB0]);              \
    }                                                                          \
    __builtin_amdgcn_sched_barrier(0);                                         \
    _Pragma("unroll")                                                          \
    for (int r = 0; r < 4; ++r) {                                              \
      acc[r] = __builtin_amdgcn_mfma_f32_16x16x32_bf16(CAH[r], CBH, acc[r], 0, 0, 0); \
      acc[r] = __builtin_amdgcn_mfma_f32_16x16x32_bf16(CAH[r], CBL, acc[r], 0, 0, 0); \
      acc[r] = __builtin_amdgcn_mfma_f32_16x16x32_bf16(CAL[r], CBH, acc[r], 0, 0, 0); \
    }                                                                          \
  }

__global__ __launch_bounds__(512, 4) void k4_mfma(const __hip_bfloat16* __restrict__ N2h,
                                                  const __hip_bfloat16* __restrict__ N2l,
                                                  const __hip_bfloat16* __restrict__ Wh,
                                                  const __hip_bfloat16* __restrict__ Wl,
                                                  float* __restrict__ out0,
                                                  float* __restrict__ out1) {
  int blk = blockIdx.x;
  int g = blk >> 8;
  int r8 = blk & 255;
  int b = r8 >> 3, ot = r8 & 7;
  int obase = ot * 128;
  int t = threadIdx.x;
  int lane = t & 63, wave = t >> 6;          // wave 0..7
  int ln15 = lane & 15, kh = lane >> 4;

  const short* gA_h = (const short*)N2h + (size_t)b * IDF * KHC;
  const short* gA_l = (const short*)N2l + (size_t)b * IDF * KHC;
  const short* gB_h = (const short*)Wh;
  const short* gB_l = (const short*)Wl;

  int offA[4];
#pragma unroll
  for (int r = 0; r < 4; ++r) offA[r] = (r * 16 + ln15) * KHC + kh * 8;
  int offB0 = (obase + wave * 16 + ln15) * CDF + kh * 8;

  int kbase = g * (KHC / 2);

  f32x4 acc[4] = {};
  short8v a0h[4], a0l[4], a1h[4], a1l[4];
  short8v b0h, b0l, b1h, b1l;

  // prologue: load k-step 0 into set0
  {
    int kk0 = kbase;
    int h4 = kk0 >> 8, cb = kk0 & 255;
    size_t wb = (size_t)h4 * SSZ * CDF + cb;
#pragma unroll
    for (int r = 0; r < 4; ++r) {
      a0h[r] = *reinterpret_cast<const short8v*>(&gA_h[offA[r] + kk0]);
      a0l[r] = *reinterpret_cast<const short8v*>(&gA_l[offA[r] + kk0]);
    }
    b0h = *reinterpret_cast<const short8v*>(&gB_h[wb + offB0]);
    b0l = *reinterpret_cast<const short8v*>(&gB_l[wb + offB0]);
  }

#pragma unroll 1
  for (int ks = 0; ks < 32; ks += 2) {
    K4_STEP(ks,     a0h, a0l, b0h, b0l, a1h, a1l, b1h, b1l);
    K4_STEP(ks + 1, a1h, a1l, b1h, b1l, a0h, a0l, b0h, b0l);
  }

  float* dst = (g == 0) ? out0 : out1;
  int rowq = (lane >> 4) * 4;
#pragma unroll
  for (int r = 0; r < 4; ++r)
#pragma unroll
    for (int reg = 0; reg < 4; ++reg)
      dst[((size_t)b * IDF + r * 16 + rowq + reg) * SSZ +
          obase + wave * 16 + ln15] = acc[r][reg];
}

// out += P
__global__ __launch_bounds__(256) void k_add(float* __restrict__ out,
                                             const float* __restrict__ P) {
  int idx = blockIdx.x * 256 + threadIdx.x;
  float4 a = reinterpret_cast<float4*>(out)[idx];
  float4 p = reinterpret_cast<const float4*>(P)[idx];
  a.x += p.x; a.y += p.y; a.z += p.z; a.w += p.w;
  reinterpret_cast<float4*>(out)[idx] = a;
}

// ---------------------------------------------------------------------------
// K5: attn_out[b][l][i] = sum_h attn[bh][i][l]
// ---------------------------------------------------------------------------
__global__ __launch_bounds__(256) void k_attnout(const float* __restrict__ attn,
                                                 float* __restrict__ outa) {
  __shared__ float T[64][65];
  int blk = blockIdx.x; int b = blk >> 2, lt = blk & 3;
  int l0 = lt * 64;
  int tid = threadIdx.x;
  float4 acc[4];
#pragma unroll
  for (int p = 0; p < 4; ++p) acc[p] = make_float4(0.f, 0.f, 0.f, 0.f);
  for (int h = 0; h < NH; ++h) {
    const float* src = attn + (size_t)(b * NH + h) * IDF * LL;
#pragma unroll
    for (int p = 0; p < 4; ++p) {
      int f = tid + p * 256;
      int i = f >> 4, lc = (f & 15) * 4;
      float4 v = *reinterpret_cast<const float4*>(&src[i * LL + l0 + lc]);
      acc[p].x += v.x; acc[p].y += v.y; acc[p].z += v.z; acc[p].w += v.w;
    }
  }
#pragma unroll
  for (int p = 0; p < 4; ++p) {
    int f = tid + p * 256;
    int i = f >> 4, lc = (f & 15) * 4;
    T[i][lc + 0] = acc[p].x; T[i][lc + 1] = acc[p].y;
    T[i][lc + 2] = acc[p].z; T[i][lc + 3] = acc[p].w;
  }
  __syncthreads();
#pragma unroll
  for (int p = 0; p < 4; ++p) {
    int f = tid + p * 256;
    int lr = f >> 4, ic = (f & 15) * 4;
    float4 v = {T[ic + 0][lr], T[ic + 1][lr], T[ic + 2][lr], T[ic + 3][lr]};
    *reinterpret_cast<float4*>(&outa[((size_t)b * LL + l0 + lr) * IDF + ic]) = v;
  }
}

// ---------------------------------------------------------------------------
extern "C" void kernel_launch(void* const* d_in, const int* in_sizes, int n_in,
                              void* d_out, int out_size, void* d_ws, size_t ws_size,
                              hipStream_t stream) {
  const float* wc  = (const float*)d_in[0];   // [32][64][1024]
  const float* ctx = (const float*)d_in[1];   // [32][256][256]
  const float* W   = (const float*)d_in[2];   // [8][1024][256]
  float* out = (float*)d_out;

  // Region A (4.19M floats): M (fp32) -> N2h/N2l (bf16)
  float* RA = (float*)d_ws;
  // Region B (4.19M floats): wc/Wt splits -> attn -> {Pbuf, Wh/Wl}
  float* RB = RA + (size_t)4194304;

  float* Mbuf = RA;
  __hip_bfloat16* N2h = (__hip_bfloat16*)RA;                 // 4.19M bf16
  __hip_bfloat16* N2l = N2h + (size_t)BB * IDF * KHC;        // 4.19M bf16

  __hip_bfloat16* wch = (__hip_bfloat16*)RB;                 // 2.1M bf16
  __hip_bfloat16* wcl = wch + (size_t)BB * IDF * SSZ;
  __hip_bfloat16* wth = wcl + (size_t)BB * IDF * SSZ;
  __hip_bfloat16* wtl = wth + (size_t)NH * CDF * SSZ;
  float* Abuf = RB;                                          // attn, 4.19M floats
  float* Pbuf = RB;                                          // 2.1M floats
  __hip_bfloat16* Wh = (__hip_bfloat16*)(RB + (size_t)2097152);
  __hip_bfloat16* Wl = Wh + (size_t)NH * SSZ * CDF;

  k_split_wc<<<2048, 256, 0, stream>>>(wc, wch, wcl);
  k_split_Wt<<<512, 256, 0, stream>>>(W, wth, wtl);
  k1_mfma   <<<BB * NH * 2, 512, 0, stream>>>(wch, wcl, wth, wtl, Mbuf);
  k_attn    <<<BB * NH * 2, 256, 0, stream>>>(Mbuf, ctx, Abuf);
  k_N2      <<<BB * NH * 2, 256, 0, stream>>>(Abuf, ctx, N2h, N2l);
  k_attnout <<<BB * 4, 256, 0, stream>>>(Abuf, out + (size_t)BB * IDF * SSZ);
  k_split_W <<<2048, 256, 0, stream>>>(W, Wh, Wl);
  k4_mfma   <<<512, 512, 0, stream>>>(N2h, N2l, Wh, Wl, out, Pbuf);
  k_add     <<<2048, 256, 0, stream>>>(out, Pbuf);
}

// Round 10
// 176.857 us; speedup vs baseline: 2.1586x; 2.1586x over previous
//
#include <hip/hip_runtime.h>
#include <hip/hip_bf16.h>

#define BB 32
#define IDF 64
#define CDF 256
#define SSZ 1024
#define NH 8
#define LL 256
#define KHC 2048   // NH*CDF

typedef __attribute__((ext_vector_type(8))) short short8v;   // 8 bf16 (4 VGPR)
typedef __attribute__((ext_vector_type(4))) float f32x4;     // MFMA acc

// async global->LDS, 16B per lane, LDS dest = wave-uniform base + lane*16
#define GLDS16(g, l) __builtin_amdgcn_global_load_lds(                        \
    (const __attribute__((address_space(1))) void*)(g),                       \
    (__attribute__((address_space(3))) void*)(l), 16, 0, 0)

__device__ inline void split_bf16(float x, __hip_bfloat16& h, __hip_bfloat16& l) {
  h = __float2bfloat16(x);
  l = __float2bfloat16(x - __bfloat162float(h));
}

// ---------------------------------------------------------------------------
// Split wc (fp32) -> wch, wcl (bf16 hi/lo), same [b][i][o] layout.
// ---------------------------------------------------------------------------
__global__ __launch_bounds__(256) void k_split_wc(const float* __restrict__ wc,
                                                  __hip_bfloat16* __restrict__ wch,
                                                  __hip_bfloat16* __restrict__ wcl) {
  int idx = (blockIdx.x * 256 + threadIdx.x) * 4;
  float4 v = *reinterpret_cast<const float4*>(&wc[idx]);
  __align__(16) __hip_bfloat16 hb[4], lb[4];
  split_bf16(v.x, hb[0], lb[0]); split_bf16(v.y, hb[1], lb[1]);
  split_bf16(v.z, hb[2], lb[2]); split_bf16(v.w, hb[3], lb[3]);
  *reinterpret_cast<int2*>(&wch[idx]) = *reinterpret_cast<int2*>(hb);
  *reinterpret_cast<int2*>(&wcl[idx]) = *reinterpret_cast<int2*>(lb);
}

// ---------------------------------------------------------------------------
// Split W (fp32, [h][o][c]) -> Wh, Wl (bf16, same layout). For K4.
// ---------------------------------------------------------------------------
__global__ __launch_bounds__(256) void k_split_W(const float* __restrict__ W,
                                                 __hip_bfloat16* __restrict__ Wh,
                                                 __hip_bfloat16* __restrict__ Wl) {
  int idx = (blockIdx.x * 256 + threadIdx.x) * 4;
  float4 v = *reinterpret_cast<const float4*>(&W[idx]);
  __align__(16) __hip_bfloat16 hb[4], lb[4];
  split_bf16(v.x, hb[0], lb[0]); split_bf16(v.y, hb[1], lb[1]);
  split_bf16(v.z, hb[2], lb[2]); split_bf16(v.w, hb[3], lb[3]);
  *reinterpret_cast<int2*>(&Wh[idx]) = *reinterpret_cast<int2*>(hb);
  *reinterpret_cast<int2*>(&Wl[idx]) = *reinterpret_cast<int2*>(lb);
}

// ---------------------------------------------------------------------------
// Split+transpose W[h][o][c] (fp32) -> Wt hi/lo [h][c][o] (bf16). For K1.
// ---------------------------------------------------------------------------
__global__ __launch_bounds__(256) void k_split_Wt(const float* __restrict__ W,
                                                  __hip_bfloat16* __restrict__ wth,
                                                  __hip_bfloat16* __restrict__ wtl) {
  __shared__ float Tt[64][65];   // [c][o]
  int blk = blockIdx.x;
  int h = blk >> 6, ot = (blk >> 2) & 15, ct = blk & 3;
  int og = ot * 64, cg = ct * 64;
  int t = threadIdx.x;
  int o_l = t >> 4, c4 = (t & 15) * 4;
#pragma unroll
  for (int p = 0; p < 4; ++p) {
    int o = o_l + 16 * p;
    float4 v = *reinterpret_cast<const float4*>(
        &W[((size_t)h * SSZ + og + o) * CDF + cg + c4]);
    Tt[c4 + 0][o] = v.x; Tt[c4 + 1][o] = v.y;
    Tt[c4 + 2][o] = v.z; Tt[c4 + 3][o] = v.w;
  }
  __syncthreads();
  int c_l = t >> 2;
#pragma unroll
  for (int p = 0; p < 4; ++p) {
    int oq = (t & 3) + 4 * p;
    int o0 = oq * 4;
    __hip_bfloat16 hv[4], lv[4];
#pragma unroll
    for (int j = 0; j < 4; ++j)
      split_bf16(Tt[c_l][o0 + j], hv[j], lv[j]);
    size_t base = ((size_t)h * CDF + cg + c_l) * SSZ + og + o0;
#pragma unroll
    for (int j = 0; j < 4; ++j) { wth[base + j] = hv[j]; wtl[base + j] = lv[j]; }
  }
}

// ---------------------------------------------------------------------------
// K1 (MFMA, global_load_lds dbuf): M[bh][i][c] = sum_o wc[b][i][o]*W[h][o][c]
// grid 512: (bh, nh-half of 128c). 256 thr = 4 waves x (64i x 32c). BK=32.
// LDS buffer (shorts): Ah[0..2048) Al[2048..4096) Bh[4096..8192) Bl[8192..12288)
// rows of 32 shorts; physical chunk pc holds global chunk pc^((row>>1)&3)
// (pre-swizzled SOURCE + swizzled ds_read = rule-21 involution pair; mapping
// identical to rounds 3-6 where it was verified).
// T3-minimum loop: STAGE(next) -> ds_read(cur) -> MFMA -> __syncthreads().
// global_load_lds is fire-and-forget: compiler cannot sink it (rounds 7-9
// failure mode was regalloc sinking register prefetch).
// ---------------------------------------------------------------------------
__device__ __forceinline__ void k1_stage(short* dst,            // &S[buf][0]
                                         const short* gA_h, const short* gA_l,
                                         const short* gB_h, const short* gB_l,
                                         int wave, int lane, int k0) {
#pragma unroll
  for (int j = 0; j < 6; ++j) {
    int inst = wave * 6 + j;               // 0..23, wave-uniform
    const short* src; int tile_off, rb;
    if (inst < 4)       { src = gA_h; tile_off = 0;    rb = inst * 16; }
    else if (inst < 8)  { src = gA_l; tile_off = 2048; rb = (inst - 4) * 16; }
    else if (inst < 16) { src = gB_h; tile_off = 4096; rb = (inst - 8) * 16; }
    else                { src = gB_l; tile_off = 8192; rb = (inst - 16) * 16; }
    int r  = rb + (lane >> 2);
    int gc = (lane & 3) ^ ((r >> 1) & 3);
    const short* g = src + (size_t)r * SSZ + k0 + gc * 8;
    short* l = dst + tile_off + rb * 32;   // wave-uniform; lane writes +lane*16B
    GLDS16(g, l);
  }
}

__global__ __launch_bounds__(256) void k1_mfma(const __hip_bfloat16* __restrict__ wch,
                                               const __hip_bfloat16* __restrict__ wcl,
                                               const __hip_bfloat16* __restrict__ wth,
                                               const __hip_bfloat16* __restrict__ wtl,
                                               float* __restrict__ Mout) {
  __shared__ __align__(16) short S[2][12288];   // 48 KB

  int blk = blockIdx.x;
  int bh = blk >> 1, nh = blk & 1;
  int b = bh >> 3, h = bh & 7;
  int t = threadIdx.x;
  int lane = t & 63, wave = t >> 6;
  int ln15 = lane & 15, kh = lane >> 4;

  const short* gA_h = (const short*)wch + (size_t)b * IDF * SSZ;
  const short* gA_l = (const short*)wcl + (size_t)b * IDF * SSZ;
  const short* gB_h = (const short*)wth + (size_t)(h * CDF + nh * 128) * SSZ;
  const short* gB_l = (const short*)wtl + (size_t)(h * CDF + nh * 128) * SSZ;

  int offA[4], offB[2];
#pragma unroll
  for (int r = 0; r < 4; ++r) {
    int row = r * 16 + ln15;
    offA[r] = row * 32 + ((kh ^ ((row >> 1) & 3)) * 8);
  }
#pragma unroll
  for (int c = 0; c < 2; ++c) {
    int row = wave * 32 + c * 16 + ln15;
    offB[c] = row * 32 + ((kh ^ ((row >> 1) & 3)) * 8);
  }

  f32x4 acc[4][2] = {};

  k1_stage(&S[0][0], gA_h, gA_l, gB_h, gB_l, wave, lane, 0);
  __syncthreads();                         // vmcnt(0) drained: buf0 ready
  int cur = 0;

#pragma unroll 1
  for (int ks = 0; ks < 32; ++ks) {
    if (ks < 31)
      k1_stage(&S[cur ^ 1][0], gA_h, gA_l, gB_h, gB_l, wave, lane, (ks + 1) * 32);
    short8v fa_h[4], fa_l[4], fb_h[2], fb_l[2];
#pragma unroll
    for (int r = 0; r < 4; ++r) {
      fa_h[r] = *reinterpret_cast<const short8v*>(&S[cur][offA[r]]);
      fa_l[r] = *reinterpret_cast<const short8v*>(&S[cur][2048 + offA[r]]);
    }
#pragma unroll
    for (int c = 0; c < 2; ++c) {
      fb_h[c] = *reinterpret_cast<const short8v*>(&S[cur][4096 + offB[c]]);
      fb_l[c] = *reinterpret_cast<const short8v*>(&S[cur][8192 + offB[c]]);
    }
#pragma unroll
    for (int r = 0; r < 4; ++r)
#pragma unroll
      for (int c = 0; c < 2; ++c) {
        acc[r][c] = __builtin_amdgcn_mfma_f32_16x16x32_bf16(fa_h[r], fb_h[c], acc[r][c], 0, 0, 0);
        acc[r][c] = __builtin_amdgcn_mfma_f32_16x16x32_bf16(fa_h[r], fb_l[c], acc[r][c], 0, 0, 0);
        acc[r][c] = __builtin_amdgcn_mfma_f32_16x16x32_bf16(fa_l[r], fb_h[c], acc[r][c], 0, 0, 0);
      }
    __syncthreads();                       // stage complete + reads drained
    cur ^= 1;
  }

  float* out = Mout + (size_t)bh * IDF * CDF + nh * 128;
  int rowq = (lane >> 4) * 4;
#pragma unroll
  for (int r = 0; r < 4; ++r)
#pragma unroll
    for (int c = 0; c < 2; ++c)
#pragma unroll
      for (int reg = 0; reg < 4; ++reg)
        out[(r * 16 + rowq + reg) * CDF + wave * 32 + c * 16 + ln15] = acc[r][c][reg];
}

// ---------------------------------------------------------------------------
// K2: logits[bh][i][l] = sum_c M[bh][i][c] * ctx[b][c][l]; softmax over l.
// grid 512: (bh, i-half of 32). acc[4][8].
// ---------------------------------------------------------------------------
__global__ __launch_bounds__(256) void k_attn(const float* __restrict__ Mm,
                                              const float* __restrict__ ctx,
                                              float* __restrict__ attn) {
  __shared__ float As[32][32];
  __shared__ float Bs[32][LL];
  int blk = blockIdx.x;
  int bh = blk >> 1, ih = blk & 1;
  int b = bh >> 3;
  int ibase = ih * 32;
  const float* A  = Mm + ((size_t)bh * IDF + ibase) * CDF;
  const float* Bm = ctx + (size_t)b * CDF * LL;
  int tid = threadIdx.x;
  int tc = tid & 31, ti = tid >> 5;
  int c0 = tc * 8, i0 = ti * 4;
  float acc[4][8];
#pragma unroll
  for (int r = 0; r < 4; ++r)
#pragma unroll
    for (int s = 0; s < 8; ++s) acc[r][s] = 0.f;

  for (int k0 = 0; k0 < CDF; k0 += 32) {
    {                                        // A tile: 32 rows x 8 f4
      int row = tid >> 3, seg = tid & 7;
      *reinterpret_cast<float4*>(&As[row][seg * 4]) =
          *reinterpret_cast<const float4*>(&A[row * CDF + k0 + seg * 4]);
    }
#pragma unroll
    for (int p = 0; p < 8; ++p) {            // B tile: 32 rows x 64 f4
      int f = tid + p * 256;
      int kk = f >> 6, cs = f & 63;
      *reinterpret_cast<float4*>(&Bs[kk][cs * 4]) =
          *reinterpret_cast<const float4*>(&Bm[(size_t)(k0 + kk) * LL + cs * 4]);
    }
    __syncthreads();
#pragma unroll
    for (int kq = 0; kq < 8; ++kq) {
      float4 av[4];
#pragma unroll
      for (int r = 0; r < 4; ++r)
        av[r] = *reinterpret_cast<const float4*>(&As[i0 + r][kq * 4]);
#pragma unroll
      for (int kk = 0; kk < 4; ++kk) {
        float4 b0 = *reinterpret_cast<const float4*>(&Bs[kq * 4 + kk][c0]);
        float4 b1 = *reinterpret_cast<const float4*>(&Bs[kq * 4 + kk][c0 + 4]);
        float bv[8] = {b0.x, b0.y, b0.z, b0.w, b1.x, b1.y, b1.z, b1.w};
#pragma unroll
        for (int r = 0; r < 4; ++r) {
          float a = (kk == 0) ? av[r].x : (kk == 1) ? av[r].y : (kk == 2) ? av[r].z : av[r].w;
#pragma unroll
          for (int s = 0; s < 8; ++s) acc[r][s] += a * bv[s];
        }
      }
    }
    __syncthreads();
  }
  float* out = attn + ((size_t)bh * IDF + ibase) * LL;
#pragma unroll
  for (int r = 0; r < 4; ++r) {
    float mx = acc[r][0];
#pragma unroll
    for (int s = 1; s < 8; ++s) mx = fmaxf(mx, acc[r][s]);
#pragma unroll
    for (int m = 16; m >= 1; m >>= 1) mx = fmaxf(mx, __shfl_xor(mx, m, 64));
    float ex[8]; float sum = 0.f;
#pragma unroll
    for (int s = 0; s < 8; ++s) { ex[s] = __expf(acc[r][s] - mx); sum += ex[s]; }
#pragma unroll
    for (int m = 16; m >= 1; m >>= 1) sum += __shfl_xor(sum, m, 64);
    float inv = 1.f / sum;
    float4 v0 = {ex[0] * inv, ex[1] * inv, ex[2] * inv, ex[3] * inv};
    float4 v1 = {ex[4] * inv, ex[5] * inv, ex[6] * inv, ex[7] * inv};
    *reinterpret_cast<float4*>(&out[(i0 + r) * LL + c0]) = v0;
    *reinterpret_cast<float4*>(&out[(i0 + r) * LL + c0 + 4]) = v1;
  }
}

// ---------------------------------------------------------------------------
// K3: N2{h,l}[b][i][h*256+c] = split(sum_l attn[bh][i][l]*ctx[b][c][l])
// grid 512: (bh, c-half of 128). acc[4][8].
// ---------------------------------------------------------------------------
__global__ __launch_bounds__(256) void k_N2(const float* __restrict__ attn,
                                            const float* __restrict__ ctx,
                                            __hip_bfloat16* __restrict__ N2h,
                                            __hip_bfloat16* __restrict__ N2l) {
  __shared__ float As[IDF][32];    // [i][l]
  __shared__ float Bs[32][132];    // [l][c], padded
  int blk = blockIdx.x;
  int bh = blk >> 1, ch = blk & 1;
  int b = bh >> 3, h = bh & 7;
  int cgbase = ch * 128;
  const float* A  = attn + (size_t)bh * IDF * LL;
  const float* Cm = ctx + ((size_t)b * CDF + cgbase) * LL;
  int tid = threadIdx.x;
  int tc = tid & 15, ti = tid >> 4;
  int c0 = tc * 8, i0 = ti * 4;
  float acc[4][8];
#pragma unroll
  for (int r = 0; r < 4; ++r)
#pragma unroll
    for (int s = 0; s < 8; ++s) acc[r][s] = 0.f;

  for (int l0 = 0; l0 < LL; l0 += 32) {
#pragma unroll
    for (int p = 0; p < 2; ++p) {            // attn tile: 64 rows x 8 f4
      int f = tid + p * 256;
      int row = f >> 3, seg = f & 7;
      *reinterpret_cast<float4*>(&As[row][seg * 4]) =
          *reinterpret_cast<const float4*>(&A[row * LL + l0 + seg * 4]);
    }
#pragma unroll
    for (int p = 0; p < 4; ++p) {            // ctx tile: transpose-stage 128 rows
      int f = tid + p * 256;
      int c = f >> 3, seg = f & 7;
      float4 v = *reinterpret_cast<const float4*>(&Cm[(size_t)c * LL + l0 + seg * 4]);
      Bs[seg * 4 + 0][c] = v.x; Bs[seg * 4 + 1][c] = v.y;
      Bs[seg * 4 + 2][c] = v.z; Bs[seg * 4 + 3][c] = v.w;
    }
    __syncthreads();
#pragma unroll
    for (int kq = 0; kq < 8; ++kq) {
      float4 av[4];
#pragma unroll
      for (int r = 0; r < 4; ++r)
        av[r] = *reinterpret_cast<const float4*>(&As[i0 + r][kq * 4]);
#pragma unroll
      for (int kk = 0; kk < 4; ++kk) {
        float4 b0 = *reinterpret_cast<const float4*>(&Bs[kq * 4 + kk][c0]);
        float4 b1 = *reinterpret_cast<const float4*>(&Bs[kq * 4 + kk][c0 + 4]);
        float bv[8] = {b0.x, b0.y, b0.z, b0.w, b1.x, b1.y, b1.z, b1.w};
#pragma unroll
        for (int r = 0; r < 4; ++r) {
          float a = (kk == 0) ? av[r].x : (kk == 1) ? av[r].y : (kk == 2) ? av[r].z : av[r].w;
#pragma unroll
          for (int s = 0; s < 8; ++s) acc[r][s] += a * bv[s];
        }
      }
    }
    __syncthreads();
  }
  // epilogue: split to bf16 hi/lo, write [b][i][h*256 + cgbase + c]
  size_t base = (size_t)b * IDF * KHC + h * CDF + cgbase;
#pragma unroll
  for (int r = 0; r < 4; ++r) {
    __align__(16) __hip_bfloat16 hb[8], lb[8];
#pragma unroll
    for (int s = 0; s < 8; ++s) split_bf16(acc[r][s], hb[s], lb[s]);
    size_t idx = base + (size_t)(i0 + r) * KHC + c0;
    *reinterpret_cast<int4*>(&N2h[idx]) = *reinterpret_cast<int4*>(hb);
    *reinterpret_cast<int4*>(&N2l[idx]) = *reinterpret_cast<int4*>(lb);
  }
}

// ---------------------------------------------------------------------------
// K4 (MFMA, global_load_lds dbuf): ctx_out[b][i][o] = sum_{hc} N2*W
// grid 512: g(2 K-halves) x b(32) x ot(8 of 128 o). 4 waves x (64i x 32o).
// Same structure/swizzle as k1_mfma; A ldK=KHC, B rows h*SSZ+obase, ldK=CDF.
// ---------------------------------------------------------------------------
__device__ __forceinline__ void k4_stage(short* dst,
                                         const short* gA_h, const short* gA_l,
                                         const short* gB_h, const short* gB_l,
                                         int wave, int lane, int kk0, int obase) {
  int h4 = kk0 >> 8, cb = kk0 & 255;
#pragma unroll
  for (int j = 0; j < 6; ++j) {
    int inst = wave * 6 + j;
    if (inst < 8) {                          // A tiles (N2), ldK = KHC
      const short* src = (inst < 4) ? gA_h : gA_l;
      int tile_off = (inst < 4) ? 0 : 2048;
      int rb = (inst & 3) * 16;
      int r  = rb + (lane >> 2);
      int gc = (lane & 3) ^ ((r >> 1) & 3);
      const short* g = src + (size_t)r * KHC + kk0 + gc * 8;
      GLDS16(g, dst + tile_off + rb * 32);
    } else {                                 // B tiles (W), ldK = CDF
      int t2 = inst - 8;
      const short* src = (t2 < 8) ? gB_h : gB_l;
      int tile_off = (t2 < 8) ? 4096 : 8192;
      int rb = (t2 & 7) * 16;
      int r  = rb + (lane >> 2);
      int gc = (lane & 3) ^ ((r >> 1) & 3);
      const short* g = src + (size_t)(h4 * SSZ + obase + r) * CDF + cb + gc * 8;
      GLDS16(g, dst + tile_off + rb * 32);
    }
  }
}

__global__ __launch_bounds__(256) void k4_mfma(const __hip_bfloat16* __restrict__ N2h,
                                               const __hip_bfloat16* __restrict__ N2l,
                                               const __hip_bfloat16* __restrict__ Wh,
                                               const __hip_bfloat16* __restrict__ Wl,
                                               float* __restrict__ out0,
                                               float* __restrict__ out1) {
  __shared__ __align__(16) short S[2][12288];   // 48 KB

  int blk = blockIdx.x;
  int g = blk >> 8;
  int r8 = blk & 255;
  int b = r8 >> 3, ot = r8 & 7;
  int obase = ot * 128;
  int t = threadIdx.x;
  int lane = t & 63, wave = t >> 6;
  int ln15 = lane & 15, kh = lane >> 4;

  const short* gA_h = (const short*)N2h + (size_t)b * IDF * KHC;
  const short* gA_l = (const short*)N2l + (size_t)b * IDF * KHC;
  const short* gB_h = (const short*)Wh;
  const short* gB_l = (const short*)Wl;

  int offA[4], offB[2];
#pragma unroll
  for (int r = 0; r < 4; ++r) {
    int row = r * 16 + ln15;
    offA[r] = row * 32 + ((kh ^ ((row >> 1) & 3)) * 8);
  }
#pragma unroll
  for (int c = 0; c < 2; ++c) {
    int row = wave * 32 + c * 16 + ln15;
    offB[c] = row * 32 + ((kh ^ ((row >> 1) & 3)) * 8);
  }

  int kbase = g * (KHC / 2);
  f32x4 acc[4][2] = {};

  k4_stage(&S[0][0], gA_h, gA_l, gB_h, gB_l, wave, lane, kbase, obase);
  __syncthreads();
  int cur = 0;

#pragma unroll 1
  for (int ks = 0; ks < 32; ++ks) {
    if (ks < 31)
      k4_stage(&S[cur ^ 1][0], gA_h, gA_l, gB_h, gB_l, wave, lane,
               kbase + (ks + 1) * 32, obase);
    short8v fa_h[4], fa_l[4], fb_h[2], fb_l[2];
#pragma unroll
    for (int r = 0; r < 4; ++r) {
      fa_h[r] = *reinterpret_cast<const short8v*>(&S[cur][offA[r]]);
      fa_l[r] = *reinterpret_cast<const short8v*>(&S[cur][2048 + offA[r]]);
    }
#pragma unroll
    for (int c = 0; c < 2; ++c) {
      fb_h[c] = *reinterpret_cast<const short8v*>(&S[cur][4096 + offB[c]]);
      fb_l[c] = *reinterpret_cast<const short8v*>(&S[cur][8192 + offB[c]]);
    }
#pragma unroll
    for (int r = 0; r < 4; ++r)
#pragma unroll
      for (int c = 0; c < 2; ++c) {
        acc[r][c] = __builtin_amdgcn_mfma_f32_16x16x32_bf16(fa_h[r], fb_h[c], acc[r][c], 0, 0, 0);
        acc[r][c] = __builtin_amdgcn_mfma_f32_16x16x32_bf16(fa_h[r], fb_l[c], acc[r][c], 0, 0, 0);
        acc[r][c] = __builtin_amdgcn_mfma_f32_16x16x32_bf16(fa_l[r], fb_h[c], acc[r][c], 0, 0, 0);
      }
    __syncthreads();
    cur ^= 1;
  }

  float* dst = (g == 0) ? out0 : out1;
  int rowq = (lane >> 4) * 4;
#pragma unroll
  for (int r = 0; r < 4; ++r)
#pragma unroll
    for (int c = 0; c < 2; ++c)
#pragma unroll
      for (int reg = 0; reg < 4; ++reg)
        dst[((size_t)b * IDF + r * 16 + rowq + reg) * SSZ +
            obase + wave * 32 + c * 16 + ln15] = acc[r][c][reg];
}

// out += P
__global__ __launch_bounds__(256) void k_add(float* __restrict__ out,
                                             const float* __restrict__ P) {
  int idx = blockIdx.x * 256 + threadIdx.x;
  float4 a = reinterpret_cast<float4*>(out)[idx];
  float4 p = reinterpret_cast<const float4*>(P)[idx];
  a.x += p.x; a.y += p.y; a.z += p.z; a.w += p.w;
  reinterpret_cast<float4*>(out)[idx] = a;
}

// ---------------------------------------------------------------------------
// K5: attn_out[b][l][i] = sum_h attn[bh][i][l]
// ---------------------------------------------------------------------------
__global__ __launch_bounds__(256) void k_attnout(const float* __restrict__ attn,
                                                 float* __restrict__ outa) {
  __shared__ float T[64][65];
  int blk = blockIdx.x; int b = blk >> 2, lt = blk & 3;
  int l0 = lt * 64;
  int tid = threadIdx.x;
  float4 acc[4];
#pragma unroll
  for (int p = 0; p < 4; ++p) acc[p] = make_float4(0.f, 0.f, 0.f, 0.f);
  for (int h = 0; h < NH; ++h) {
    const float* src = attn + (size_t)(b * NH + h) * IDF * LL;
#pragma unroll
    for (int p = 0; p < 4; ++p) {
      int f = tid + p * 256;
      int i = f >> 4, lc = (f & 15) * 4;
      float4 v = *reinterpret_cast<const float4*>(&src[i * LL + l0 + lc]);
      acc[p].x += v.x; acc[p].y += v.y; acc[p].z += v.z; acc[p].w += v.w;
    }
  }
#pragma unroll
  for (int p = 0; p < 4; ++p) {
    int f = tid + p * 256;
    int i = f >> 4, lc = (f & 15) * 4;
    T[i][lc + 0] = acc[p].x; T[i][lc + 1] = acc[p].y;
    T[i][lc + 2] = acc[p].z; T[i][lc + 3] = acc[p].w;
  }
  __syncthreads();
#pragma unroll
  for (int p = 0; p < 4; ++p) {
    int f = tid + p * 256;
    int lr = f >> 4, ic = (f & 15) * 4;
    float4 v = {T[ic + 0][lr], T[ic + 1][lr], T[ic + 2][lr], T[ic + 3][lr]};
    *reinterpret_cast<float4*>(&outa[((size_t)b * LL + l0 + lr) * IDF + ic]) = v;
  }
}

// ---------------------------------------------------------------------------
extern "C" void kernel_launch(void* const* d_in, const int* in_sizes, int n_in,
                              void* d_out, int out_size, void* d_ws, size_t ws_size,
                              hipStream_t stream) {
  const float* wc  = (const float*)d_in[0];   // [32][64][1024]
  const float* ctx = (const float*)d_in[1];   // [32][256][256]
  const float* W   = (const float*)d_in[2];   // [8][1024][256]
  float* out = (float*)d_out;

  // Region A (4.19M floats): M (fp32) -> N2h/N2l (bf16)
  float* RA = (float*)d_ws;
  // Region B (4.19M floats): wc/Wt splits -> attn -> {Pbuf, Wh/Wl}
  float* RB = RA + (size_t)4194304;

  float* Mbuf = RA;
  __hip_bfloat16* N2h = (__hip_bfloat16*)RA;                 // 4.19M bf16
  __hip_bfloat16* N2l = N2h + (size_t)BB * IDF * KHC;        // 4.19M bf16

  __hip_bfloat16* wch = (__hip_bfloat16*)RB;                 // 2.1M bf16
  __hip_bfloat16* wcl = wch + (size_t)BB * IDF * SSZ;
  __hip_bfloat16* wth = wcl + (size_t)BB * IDF * SSZ;
  __hip_bfloat16* wtl = wth + (size_t)NH * CDF * SSZ;
  float* Abuf = RB;                                          // attn, 4.19M floats
  float* Pbuf = RB;                                          // 2.1M floats
  __hip_bfloat16* Wh = (__hip_bfloat16*)(RB + (size_t)2097152);
  __hip_bfloat16* Wl = Wh + (size_t)NH * SSZ * CDF;

  k_split_wc<<<2048, 256, 0, stream>>>(wc, wch, wcl);
  k_split_Wt<<<512, 256, 0, stream>>>(W, wth, wtl);
  k1_mfma   <<<BB * NH * 2, 256, 0, stream>>>(wch, wcl, wth, wtl, Mbuf);
  k_attn    <<<BB * NH * 2, 256, 0, stream>>>(Mbuf, ctx, Abuf);
  k_N2      <<<BB * NH * 2, 256, 0, stream>>>(Abuf, ctx, N2h, N2l);
  k_attnout <<<BB * 4, 256, 0, stream>>>(Abuf, out + (size_t)BB * IDF * SSZ);
  k_split_W <<<2048, 256, 0, stream>>>(W, Wh, Wl);
  k4_mfma   <<<512, 256, 0, stream>>>(N2h, N2l, Wh, Wl, out, Pbuf);
  k_add     <<<2048, 256, 0, stream>>>(out, Pbuf);
}

// Round 11
// 154.824 us; speedup vs baseline: 2.4658x; 1.1423x over previous
//
#include <hip/hip_runtime.h>
#include <hip/hip_bf16.h>

#define BB 32
#define IDF 64
#define CDF 256
#define SSZ 1024
#define NH 8
#define LL 256
#define KHC 2048   // NH*CDF

typedef __attribute__((ext_vector_type(8))) short short8v;   // 8 bf16 (4 VGPR)
typedef __attribute__((ext_vector_type(4))) float f32x4;     // MFMA acc

// async global->LDS, 16B per lane, LDS dest = wave-uniform base + lane*16
#define GLDS16(g, l) __builtin_amdgcn_global_load_lds(                        \
    (const __attribute__((address_space(1))) void*)(g),                       \
    (__attribute__((address_space(3))) void*)(l), 16, 0, 0)

__device__ inline void split_bf16(float x, __hip_bfloat16& h, __hip_bfloat16& l) {
  h = __float2bfloat16(x);
  l = __float2bfloat16(x - __bfloat162float(h));
}
__device__ inline float bf2f(unsigned short u) {
  return __uint_as_float(((unsigned int)u) << 16);
}

// ---------------------------------------------------------------------------
// Generic elementwise split (2.097M elems): used for wc, W, ctx (same size).
// ---------------------------------------------------------------------------
__global__ __launch_bounds__(256) void k_split(const float* __restrict__ src,
                                               __hip_bfloat16* __restrict__ dh,
                                               __hip_bfloat16* __restrict__ dl) {
  int idx = (blockIdx.x * 256 + threadIdx.x) * 4;
  float4 v = *reinterpret_cast<const float4*>(&src[idx]);
  __align__(16) __hip_bfloat16 hb[4], lb[4];
  split_bf16(v.x, hb[0], lb[0]); split_bf16(v.y, hb[1], lb[1]);
  split_bf16(v.z, hb[2], lb[2]); split_bf16(v.w, hb[3], lb[3]);
  *reinterpret_cast<int2*>(&dh[idx]) = *reinterpret_cast<int2*>(hb);
  *reinterpret_cast<int2*>(&dl[idx]) = *reinterpret_cast<int2*>(lb);
}

// ---------------------------------------------------------------------------
// Split+transpose W[h][o][c] -> Wt hi/lo [h][c][o]. For K1.
// ---------------------------------------------------------------------------
__global__ __launch_bounds__(256) void k_split_Wt(const float* __restrict__ W,
                                                  __hip_bfloat16* __restrict__ wth,
                                                  __hip_bfloat16* __restrict__ wtl) {
  __shared__ float Tt[64][65];   // [c][o]
  int blk = blockIdx.x;
  int h = blk >> 6, ot = (blk >> 2) & 15, ct = blk & 3;
  int og = ot * 64, cg = ct * 64;
  int t = threadIdx.x;
  int o_l = t >> 4, c4 = (t & 15) * 4;
#pragma unroll
  for (int p = 0; p < 4; ++p) {
    int o = o_l + 16 * p;
    float4 v = *reinterpret_cast<const float4*>(
        &W[((size_t)h * SSZ + og + o) * CDF + cg + c4]);
    Tt[c4 + 0][o] = v.x; Tt[c4 + 1][o] = v.y;
    Tt[c4 + 2][o] = v.z; Tt[c4 + 3][o] = v.w;
  }
  __syncthreads();
  int c_l = t >> 2;
#pragma unroll
  for (int p = 0; p < 4; ++p) {
    int o0 = ((t & 3) + 4 * p) * 4;
    __hip_bfloat16 hv[4], lv[4];
#pragma unroll
    for (int j = 0; j < 4; ++j) split_bf16(Tt[c_l][o0 + j], hv[j], lv[j]);
    size_t base = ((size_t)h * CDF + cg + c_l) * SSZ + og + o0;
#pragma unroll
    for (int j = 0; j < 4; ++j) { wth[base + j] = hv[j]; wtl[base + j] = lv[j]; }
  }
}

// ---------------------------------------------------------------------------
// Split+transpose ctx[b][c][l] -> ctxT hi/lo [b][l][c]. For K2.
// grid: b(32) x ct(4) x lt(4) = 512.
// ---------------------------------------------------------------------------
__global__ __launch_bounds__(256) void k_split_ctxT(const float* __restrict__ ctx,
                                                    __hip_bfloat16* __restrict__ Th,
                                                    __hip_bfloat16* __restrict__ Tl) {
  __shared__ float Tt[64][65];   // [l][c]
  int blk = blockIdx.x;
  int b = blk >> 4, ct = (blk >> 2) & 3, lt = blk & 3;
  int cg = ct * 64, lg = lt * 64;
  int t = threadIdx.x;
  int c_l = t >> 4, l4 = (t & 15) * 4;
#pragma unroll
  for (int p = 0; p < 4; ++p) {
    int c = c_l + 16 * p;
    float4 v = *reinterpret_cast<const float4*>(
        &ctx[((size_t)b * CDF + cg + c) * LL + lg + l4]);
    Tt[l4 + 0][c] = v.x; Tt[l4 + 1][c] = v.y;
    Tt[l4 + 2][c] = v.z; Tt[l4 + 3][c] = v.w;
  }
  __syncthreads();
  int l_l = t >> 2;
#pragma unroll
  for (int p = 0; p < 4; ++p) {
    int c0 = ((t & 3) + 4 * p) * 4;
    __hip_bfloat16 hv[4], lv[4];
#pragma unroll
    for (int j = 0; j < 4; ++j) split_bf16(Tt[l_l][c0 + j], hv[j], lv[j]);
    size_t base = ((size_t)b * LL + lg + l_l) * CDF + cg + c0;
#pragma unroll
    for (int j = 0; j < 4; ++j) { Th[base + j] = hv[j]; Tl[base + j] = lv[j]; }
  }
}

// ---------------------------------------------------------------------------
// K1 (MFMA, gload_lds dbuf): M = wc*W^T. Epilogue writes Mh/Ml bf16 split.
// grid 512: (bh, nh-half of 128c). 4 waves x (64i x 32c). BK=32.
// ---------------------------------------------------------------------------
__device__ __forceinline__ void k1_stage(short* dst,
                                         const short* gA_h, const short* gA_l,
                                         const short* gB_h, const short* gB_l,
                                         int wave, int lane, int k0) {
#pragma unroll
  for (int j = 0; j < 6; ++j) {
    int inst = wave * 6 + j;
    const short* src; int tile_off, rb;
    if (inst < 4)       { src = gA_h; tile_off = 0;    rb = inst * 16; }
    else if (inst < 8)  { src = gA_l; tile_off = 2048; rb = (inst - 4) * 16; }
    else if (inst < 16) { src = gB_h; tile_off = 4096; rb = (inst - 8) * 16; }
    else                { src = gB_l; tile_off = 8192; rb = (inst - 16) * 16; }
    int r  = rb + (lane >> 2);
    int gc = (lane & 3) ^ ((r >> 1) & 3);
    GLDS16(src + (size_t)r * SSZ + k0 + gc * 8, dst + tile_off + rb * 32);
  }
}

__global__ __launch_bounds__(256) void k1_mfma(const __hip_bfloat16* __restrict__ wch,
                                               const __hip_bfloat16* __restrict__ wcl,
                                               const __hip_bfloat16* __restrict__ wth,
                                               const __hip_bfloat16* __restrict__ wtl,
                                               __hip_bfloat16* __restrict__ Mh,
                                               __hip_bfloat16* __restrict__ Ml) {
  __shared__ __align__(16) short S[2][12288];   // 48 KB

  int blk = blockIdx.x;
  int bh = blk >> 1, nh = blk & 1;
  int b = bh >> 3, h = bh & 7;
  int t = threadIdx.x;
  int lane = t & 63, wave = t >> 6;
  int ln15 = lane & 15, kh = lane >> 4;

  const short* gA_h = (const short*)wch + (size_t)b * IDF * SSZ;
  const short* gA_l = (const short*)wcl + (size_t)b * IDF * SSZ;
  const short* gB_h = (const short*)wth + (size_t)(h * CDF + nh * 128) * SSZ;
  const short* gB_l = (const short*)wtl + (size_t)(h * CDF + nh * 128) * SSZ;

  int offA[4], offB[2];
#pragma unroll
  for (int r = 0; r < 4; ++r) {
    int row = r * 16 + ln15;
    offA[r] = row * 32 + ((kh ^ ((row >> 1) & 3)) * 8);
  }
#pragma unroll
  for (int c = 0; c < 2; ++c) {
    int row = wave * 32 + c * 16 + ln15;
    offB[c] = row * 32 + ((kh ^ ((row >> 1) & 3)) * 8);
  }

  f32x4 acc[4][2] = {};
  k1_stage(&S[0][0], gA_h, gA_l, gB_h, gB_l, wave, lane, 0);
  __syncthreads();
  int cur = 0;

#pragma unroll 1
  for (int ks = 0; ks < 32; ++ks) {
    if (ks < 31)
      k1_stage(&S[cur ^ 1][0], gA_h, gA_l, gB_h, gB_l, wave, lane, (ks + 1) * 32);
    short8v fa_h[4], fa_l[4], fb_h[2], fb_l[2];
#pragma unroll
    for (int r = 0; r < 4; ++r) {
      fa_h[r] = *reinterpret_cast<const short8v*>(&S[cur][offA[r]]);
      fa_l[r] = *reinterpret_cast<const short8v*>(&S[cur][2048 + offA[r]]);
    }
#pragma unroll
    for (int c = 0; c < 2; ++c) {
      fb_h[c] = *reinterpret_cast<const short8v*>(&S[cur][4096 + offB[c]]);
      fb_l[c] = *reinterpret_cast<const short8v*>(&S[cur][8192 + offB[c]]);
    }
#pragma unroll
    for (int r = 0; r < 4; ++r)
#pragma unroll
      for (int c = 0; c < 2; ++c) {
        acc[r][c] = __builtin_amdgcn_mfma_f32_16x16x32_bf16(fa_h[r], fb_h[c], acc[r][c], 0, 0, 0);
        acc[r][c] = __builtin_amdgcn_mfma_f32_16x16x32_bf16(fa_h[r], fb_l[c], acc[r][c], 0, 0, 0);
        acc[r][c] = __builtin_amdgcn_mfma_f32_16x16x32_bf16(fa_l[r], fb_h[c], acc[r][c], 0, 0, 0);
      }
    __syncthreads();
    cur ^= 1;
  }

  size_t obase = (size_t)bh * IDF * CDF + nh * 128;
  int rowq = (lane >> 4) * 4;
#pragma unroll
  for (int r = 0; r < 4; ++r)
#pragma unroll
    for (int c = 0; c < 2; ++c)
#pragma unroll
      for (int reg = 0; reg < 4; ++reg) {
        __hip_bfloat16 hb, lb;
        split_bf16(acc[r][c][reg], hb, lb);
        size_t idx = obase + (size_t)(r * 16 + rowq + reg) * CDF + wave * 32 + c * 16 + ln15;
        Mh[idx] = hb; Ml[idx] = lb;
      }
}

// ---------------------------------------------------------------------------
// K2 (MFMA + fused softmax): P[bh][i][l] = softmax_l( M[i][:]*ctxT[l][:] ).
// grid 256 (bh), 512 thr = 8 waves x (64i x 32l). K=256(c), BK=32, 8 steps.
// LDS/buf: Mh[0,2048) Ml[2048,4096) Th[4096,12288) Tl[12288,20480) shorts.
// Softmax: quadrant shfl reduce (row lives in 16 lanes x 2 frags) +
// 8-wave LDS partial combine; probs written as Ph/Pl bf16 split.
// ---------------------------------------------------------------------------
__device__ __forceinline__ void k2_stage(short* dst,
                                         const short* gMh, const short* gMl,
                                         const short* gTh, const short* gTl,
                                         int wave, int lane, int k0) {
#pragma unroll
  for (int j = 0; j < 5; ++j) {
    int inst = wave * 5 + j;               // 0..39
    const short* src; int tile_off, rb;
    if (inst < 4)       { src = gMh; tile_off = 0;     rb = inst * 16; }
    else if (inst < 8)  { src = gMl; tile_off = 2048;  rb = (inst - 4) * 16; }
    else if (inst < 24) { src = gTh; tile_off = 4096;  rb = (inst - 8) * 16; }
    else                { src = gTl; tile_off = 12288; rb = (inst - 24) * 16; }
    int r  = rb + (lane >> 2);
    int gc = (lane & 3) ^ ((r >> 1) & 3);
    GLDS16(src + (size_t)r * CDF + k0 + gc * 8, dst + tile_off + rb * 32);
  }
}

__global__ __launch_bounds__(512) void k_attn(const __hip_bfloat16* __restrict__ Mh,
                                              const __hip_bfloat16* __restrict__ Ml,
                                              const __hip_bfloat16* __restrict__ cTh,
                                              const __hip_bfloat16* __restrict__ cTl,
                                              __hip_bfloat16* __restrict__ Ph,
                                              __hip_bfloat16* __restrict__ Pl) {
  __shared__ __align__(16) short S[2][20480];   // 80 KB

  int bh = blockIdx.x;
  int b = bh >> 3;
  int t = threadIdx.x;
  int lane = t & 63, wave = t >> 6;             // wave 0..7
  int ln15 = lane & 15, kh = lane >> 4;

  const short* gMh = (const short*)Mh + (size_t)bh * IDF * CDF;
  const short* gMl = (const short*)Ml + (size_t)bh * IDF * CDF;
  const short* gTh = (const short*)cTh + (size_t)b * LL * CDF;
  const short* gTl = (const short*)cTl + (size_t)b * LL * CDF;

  int offA[4], offB[2];
#pragma unroll
  for (int r = 0; r < 4; ++r) {
    int row = r * 16 + ln15;
    offA[r] = row * 32 + ((kh ^ ((row >> 1) & 3)) * 8);
  }
#pragma unroll
  for (int c = 0; c < 2; ++c) {
    int row = wave * 32 + c * 16 + ln15;       // 0..255 within 256-row B tile
    offB[c] = row * 32 + ((kh ^ ((row >> 1) & 3)) * 8);
  }

  f32x4 acc[4][2] = {};
  k2_stage(&S[0][0], gMh, gMl, gTh, gTl, wave, lane, 0);
  __syncthreads();
  int cur = 0;

#pragma unroll 1
  for (int ks = 0; ks < 8; ++ks) {
    if (ks < 7)
      k2_stage(&S[cur ^ 1][0], gMh, gMl, gTh, gTl, wave, lane, (ks + 1) * 32);
    short8v fa_h[4], fa_l[4], fb_h[2], fb_l[2];
#pragma unroll
    for (int r = 0; r < 4; ++r) {
      fa_h[r] = *reinterpret_cast<const short8v*>(&S[cur][offA[r]]);
      fa_l[r] = *reinterpret_cast<const short8v*>(&S[cur][2048 + offA[r]]);
    }
#pragma unroll
    for (int c = 0; c < 2; ++c) {
      fb_h[c] = *reinterpret_cast<const short8v*>(&S[cur][4096 + offB[c]]);
      fb_l[c] = *reinterpret_cast<const short8v*>(&S[cur][12288 + offB[c]]);
    }
#pragma unroll
    for (int r = 0; r < 4; ++r)
#pragma unroll
      for (int c = 0; c < 2; ++c) {
        acc[r][c] = __builtin_amdgcn_mfma_f32_16x16x32_bf16(fa_h[r], fb_h[c], acc[r][c], 0, 0, 0);
        acc[r][c] = __builtin_amdgcn_mfma_f32_16x16x32_bf16(fa_h[r], fb_l[c], acc[r][c], 0, 0, 0);
        acc[r][c] = __builtin_amdgcn_mfma_f32_16x16x32_bf16(fa_l[r], fb_h[c], acc[r][c], 0, 0, 0);
      }
    __syncthreads();
    cur ^= 1;
  }

  // ---- fused softmax over l (cols). acc[r][c][reg]: row=r*16+(lane>>4)*4+reg,
  //      col = wave*32 + c*16 + (lane&15). pm[row][w] partials in LDS.
  float* pm = reinterpret_cast<float*>(&S[0][0]);   // 64*8 floats
  int rowq = (lane >> 4) * 4;
  float gmax[4][4], ginv[4][4];
  // phase 1: row max
#pragma unroll
  for (int r = 0; r < 4; ++r)
#pragma unroll
    for (int reg = 0; reg < 4; ++reg) {
      float m = fmaxf(acc[r][0][reg], acc[r][1][reg]);
#pragma unroll
      for (int msk = 8; msk >= 1; msk >>= 1) m = fmaxf(m, __shfl_xor(m, msk, 64));
      if (ln15 == 0) pm[(r * 16 + rowq + reg) * 8 + wave] = m;
    }
  __syncthreads();
#pragma unroll
  for (int r = 0; r < 4; ++r)
#pragma unroll
    for (int reg = 0; reg < 4; ++reg) {
      int row = r * 16 + rowq + reg;
      float4 p0 = *reinterpret_cast<const float4*>(&pm[row * 8]);
      float4 p1 = *reinterpret_cast<const float4*>(&pm[row * 8 + 4]);
      gmax[r][reg] = fmaxf(fmaxf(fmaxf(p0.x, p0.y), fmaxf(p0.z, p0.w)),
                           fmaxf(fmaxf(p1.x, p1.y), fmaxf(p1.z, p1.w)));
    }
  __syncthreads();   // pm reads done before reuse for sums
  // phase 2: exp in place + row sum
#pragma unroll
  for (int r = 0; r < 4; ++r)
#pragma unroll
    for (int reg = 0; reg < 4; ++reg) {
      acc[r][0][reg] = __expf(acc[r][0][reg] - gmax[r][reg]);
      acc[r][1][reg] = __expf(acc[r][1][reg] - gmax[r][reg]);
      float s = acc[r][0][reg] + acc[r][1][reg];
#pragma unroll
      for (int msk = 8; msk >= 1; msk >>= 1) s += __shfl_xor(s, msk, 64);
      if (ln15 == 0) pm[(r * 16 + rowq + reg) * 8 + wave] = s;
    }
  __syncthreads();
#pragma unroll
  for (int r = 0; r < 4; ++r)
#pragma unroll
    for (int reg = 0; reg < 4; ++reg) {
      int row = r * 16 + rowq + reg;
      float4 p0 = *reinterpret_cast<const float4*>(&pm[row * 8]);
      float4 p1 = *reinterpret_cast<const float4*>(&pm[row * 8 + 4]);
      ginv[r][reg] = 1.f / (p0.x + p0.y + p0.z + p0.w + p1.x + p1.y + p1.z + p1.w);
    }
  // write split probs
  size_t obase = (size_t)bh * IDF * LL;
#pragma unroll
  for (int r = 0; r < 4; ++r)
#pragma unroll
    for (int c = 0; c < 2; ++c)
#pragma unroll
      for (int reg = 0; reg < 4; ++reg) {
        float p = acc[r][c][reg] * ginv[r][reg];
        __hip_bfloat16 hb, lb;
        split_bf16(p, hb, lb);
        size_t idx = obase + (size_t)(r * 16 + rowq + reg) * LL + wave * 32 + c * 16 + ln15;
        Ph[idx] = hb; Pl[idx] = lb;
      }
}

// ---------------------------------------------------------------------------
// K3 (MFMA): N2[b][i][h*256+c] = sum_l P[i][l]*ctx[c][l]. grid 512 (bh, ch).
// 4 waves x (64i x 32c). K=256(l), BK=32, 8 steps. Epilogue split.
// ---------------------------------------------------------------------------
__device__ __forceinline__ void k3_stage(short* dst,
                                         const short* gPh, const short* gPl,
                                         const short* gCh, const short* gCl,
                                         int wave, int lane, int k0) {
#pragma unroll
  for (int j = 0; j < 6; ++j) {
    int inst = wave * 6 + j;
    const short* src; int tile_off, rb;
    if (inst < 4)       { src = gPh; tile_off = 0;    rb = inst * 16; }
    else if (inst < 8)  { src = gPl; tile_off = 2048; rb = (inst - 4) * 16; }
    else if (inst < 16) { src = gCh; tile_off = 4096; rb = (inst - 8) * 16; }
    else                { src = gCl; tile_off = 8192; rb = (inst - 16) * 16; }
    int r  = rb + (lane >> 2);
    int gc = (lane & 3) ^ ((r >> 1) & 3);
    GLDS16(src + (size_t)r * LL + k0 + gc * 8, dst + tile_off + rb * 32);
  }
}

__global__ __launch_bounds__(256) void k_N2(const __hip_bfloat16* __restrict__ Ph,
                                            const __hip_bfloat16* __restrict__ Pl,
                                            const __hip_bfloat16* __restrict__ cNh,
                                            const __hip_bfloat16* __restrict__ cNl,
                                            __hip_bfloat16* __restrict__ N2h,
                                            __hip_bfloat16* __restrict__ N2l) {
  __shared__ __align__(16) short S[2][12288];   // 48 KB

  int blk = blockIdx.x;
  int bh = blk >> 1, ch = blk & 1;
  int b = bh >> 3, h = bh & 7;
  int cgbase = ch * 128;
  int t = threadIdx.x;
  int lane = t & 63, wave = t >> 6;
  int ln15 = lane & 15, kh = lane >> 4;

  const short* gPh = (const short*)Ph + (size_t)bh * IDF * LL;
  const short* gPl = (const short*)Pl + (size_t)bh * IDF * LL;
  const short* gCh = (const short*)cNh + (size_t)(b * CDF + cgbase) * LL;
  const short* gCl = (const short*)cNl + (size_t)(b * CDF + cgbase) * LL;

  int offA[4], offB[2];
#pragma unroll
  for (int r = 0; r < 4; ++r) {
    int row = r * 16 + ln15;
    offA[r] = row * 32 + ((kh ^ ((row >> 1) & 3)) * 8);
  }
#pragma unroll
  for (int c = 0; c < 2; ++c) {
    int row = wave * 32 + c * 16 + ln15;
    offB[c] = row * 32 + ((kh ^ ((row >> 1) & 3)) * 8);
  }

  f32x4 acc[4][2] = {};
  k3_stage(&S[0][0], gPh, gPl, gCh, gCl, wave, lane, 0);
  __syncthreads();
  int cur = 0;

#pragma unroll 1
  for (int ks = 0; ks < 8; ++ks) {
    if (ks < 7)
      k3_stage(&S[cur ^ 1][0], gPh, gPl, gCh, gCl, wave, lane, (ks + 1) * 32);
    short8v fa_h[4], fa_l[4], fb_h[2], fb_l[2];
#pragma unroll
    for (int r = 0; r < 4; ++r) {
      fa_h[r] = *reinterpret_cast<const short8v*>(&S[cur][offA[r]]);
      fa_l[r] = *reinterpret_cast<const short8v*>(&S[cur][2048 + offA[r]]);
    }
#pragma unroll
    for (int c = 0; c < 2; ++c) {
      fb_h[c] = *reinterpret_cast<const short8v*>(&S[cur][4096 + offB[c]]);
      fb_l[c] = *reinterpret_cast<const short8v*>(&S[cur][8192 + offB[c]]);
    }
#pragma unroll
    for (int r = 0; r < 4; ++r)
#pragma unroll
      for (int c = 0; c < 2; ++c) {
        acc[r][c] = __builtin_amdgcn_mfma_f32_16x16x32_bf16(fa_h[r], fb_h[c], acc[r][c], 0, 0, 0);
        acc[r][c] = __builtin_amdgcn_mfma_f32_16x16x32_bf16(fa_h[r], fb_l[c], acc[r][c], 0, 0, 0);
        acc[r][c] = __builtin_amdgcn_mfma_f32_16x16x32_bf16(fa_l[r], fb_h[c], acc[r][c], 0, 0, 0);
      }
    __syncthreads();
    cur ^= 1;
  }

  size_t base = (size_t)b * IDF * KHC + h * CDF + cgbase;
  int rowq = (lane >> 4) * 4;
#pragma unroll
  for (int r = 0; r < 4; ++r)
#pragma unroll
    for (int c = 0; c < 2; ++c)
#pragma unroll
      for (int reg = 0; reg < 4; ++reg) {
        __hip_bfloat16 hb, lb;
        split_bf16(acc[r][c][reg], hb, lb);
        size_t idx = base + (size_t)(r * 16 + rowq + reg) * KHC + wave * 32 + c * 16 + ln15;
        N2h[idx] = hb; N2l[idx] = lb;
      }
}

// ---------------------------------------------------------------------------
// K4 (MFMA, gload_lds dbuf): ctx_out[b][i][o] = sum_{hc} N2*W. Unchanged.
// ---------------------------------------------------------------------------
__device__ __forceinline__ void k4_stage(short* dst,
                                         const short* gA_h, const short* gA_l,
                                         const short* gB_h, const short* gB_l,
                                         int wave, int lane, int kk0, int obase) {
  int h4 = kk0 >> 8, cb = kk0 & 255;
#pragma unroll
  for (int j = 0; j < 6; ++j) {
    int inst = wave * 6 + j;
    if (inst < 8) {
      const short* src = (inst < 4) ? gA_h : gA_l;
      int tile_off = (inst < 4) ? 0 : 2048;
      int rb = (inst & 3) * 16;
      int r  = rb + (lane >> 2);
      int gc = (lane & 3) ^ ((r >> 1) & 3);
      GLDS16(src + (size_t)r * KHC + kk0 + gc * 8, dst + tile_off + rb * 32);
    } else {
      int t2 = inst - 8;
      const short* src = (t2 < 8) ? gB_h : gB_l;
      int tile_off = (t2 < 8) ? 4096 : 8192;
      int rb = (t2 & 7) * 16;
      int r  = rb + (lane >> 2);
      int gc = (lane & 3) ^ ((r >> 1) & 3);
      GLDS16(src + (size_t)(h4 * SSZ + obase + r) * CDF + cb + gc * 8, dst + tile_off + rb * 32);
    }
  }
}

__global__ __launch_bounds__(256) void k4_mfma(const __hip_bfloat16* __restrict__ N2h,
                                               const __hip_bfloat16* __restrict__ N2l,
                                               const __hip_bfloat16* __restrict__ Wh,
                                               const __hip_bfloat16* __restrict__ Wl,
                                               float* __restrict__ out0,
                                               float* __restrict__ out1) {
  __shared__ __align__(16) short S[2][12288];   // 48 KB

  int blk = blockIdx.x;
  int g = blk >> 8;
  int r8 = blk & 255;
  int b = r8 >> 3, ot = r8 & 7;
  int obase = ot * 128;
  int t = threadIdx.x;
  int lane = t & 63, wave = t >> 6;
  int ln15 = lane & 15, kh = lane >> 4;

  const short* gA_h = (const short*)N2h + (size_t)b * IDF * KHC;
  const short* gA_l = (const short*)N2l + (size_t)b * IDF * KHC;
  const short* gB_h = (const short*)Wh;
  const short* gB_l = (const short*)Wl;

  int offA[4], offB[2];
#pragma unroll
  for (int r = 0; r < 4; ++r) {
    int row = r * 16 + ln15;
    offA[r] = row * 32 + ((kh ^ ((row >> 1) & 3)) * 8);
  }
#pragma unroll
  for (int c = 0; c < 2; ++c) {
    int row = wave * 32 + c * 16 + ln15;
    offB[c] = row * 32 + ((kh ^ ((row >> 1) & 3)) * 8);
  }

  int kbase = g * (KHC / 2);
  f32x4 acc[4][2] = {};

  k4_stage(&S[0][0], gA_h, gA_l, gB_h, gB_l, wave, lane, kbase, obase);
  __syncthreads();
  int cur = 0;

#pragma unroll 1
  for (int ks = 0; ks < 32; ++ks) {
    if (ks < 31)
      k4_stage(&S[cur ^ 1][0], gA_h, gA_l, gB_h, gB_l, wave, lane,
               kbase + (ks + 1) * 32, obase);
    short8v fa_h[4], fa_l[4], fb_h[2], fb_l[2];
#pragma unroll
    for (int r = 0; r < 4; ++r) {
      fa_h[r] = *reinterpret_cast<const short8v*>(&S[cur][offA[r]]);
      fa_l[r] = *reinterpret_cast<const short8v*>(&S[cur][2048 + offA[r]]);
    }
#pragma unroll
    for (int c = 0; c < 2; ++c) {
      fb_h[c] = *reinterpret_cast<const short8v*>(&S[cur][4096 + offB[c]]);
      fb_l[c] = *reinterpret_cast<const short8v*>(&S[cur][8192 + offB[c]]);
    }
#pragma unroll
    for (int r = 0; r < 4; ++r)
#pragma unroll
      for (int c = 0; c < 2; ++c) {
        acc[r][c] = __builtin_amdgcn_mfma_f32_16x16x32_bf16(fa_h[r], fb_h[c], acc[r][c], 0, 0, 0);
        acc[r][c] = __builtin_amdgcn_mfma_f32_16x16x32_bf16(fa_h[r], fb_l[c], acc[r][c], 0, 0, 0);
        acc[r][c] = __builtin_amdgcn_mfma_f32_16x16x32_bf16(fa_l[r], fb_h[c], acc[r][c], 0, 0, 0);
      }
    __syncthreads();
    cur ^= 1;
  }

  float* dst = (g == 0) ? out0 : out1;
  int rowq = (lane >> 4) * 4;
#pragma unroll
  for (int r = 0; r < 4; ++r)
#pragma unroll
    for (int c = 0; c < 2; ++c)
#pragma unroll
      for (int reg = 0; reg < 4; ++reg)
        dst[((size_t)b * IDF + r * 16 + rowq + reg) * SSZ +
            obase + wave * 32 + c * 16 + ln15] = acc[r][c][reg];
}

// out += P
__global__ __launch_bounds__(256) void k_add(float* __restrict__ out,
                                             const float* __restrict__ P) {
  int idx = blockIdx.x * 256 + threadIdx.x;
  float4 a = reinterpret_cast<float4*>(out)[idx];
  float4 p = reinterpret_cast<const float4*>(P)[idx];
  a.x += p.x; a.y += p.y; a.z += p.z; a.w += p.w;
  reinterpret_cast<float4*>(out)[idx] = a;
}

// ---------------------------------------------------------------------------
// K5: attn_out[b][l][i] = sum_h (Ph+Pl)[bh][i][l]  (bf16 pair input)
// ---------------------------------------------------------------------------
__global__ __launch_bounds__(256) void k_attnout(const __hip_bfloat16* __restrict__ Ph,
                                                 const __hip_bfloat16* __restrict__ Pl,
                                                 float* __restrict__ outa) {
  __shared__ float T[64][65];
  int blk = blockIdx.x; int b = blk >> 2, lt = blk & 3;
  int l0 = lt * 64;
  int tid = threadIdx.x;
  const unsigned short* ph = (const unsigned short*)Ph;
  const unsigned short* pl = (const unsigned short*)Pl;
  float4 acc[4];
#pragma unroll
  for (int p = 0; p < 4; ++p) acc[p] = make_float4(0.f, 0.f, 0.f, 0.f);
  for (int h = 0; h < NH; ++h) {
    size_t src = (size_t)(b * NH + h) * IDF * LL;
#pragma unroll
    for (int p = 0; p < 4; ++p) {
      int f = tid + p * 256;
      int i = f >> 4, lc = (f & 15) * 4;
      ushort4 uh = *reinterpret_cast<const ushort4*>(&ph[src + i * LL + l0 + lc]);
      ushort4 ul = *reinterpret_cast<const ushort4*>(&pl[src + i * LL + l0 + lc]);
      acc[p].x += bf2f(uh.x) + bf2f(ul.x); acc[p].y += bf2f(uh.y) + bf2f(ul.y);
      acc[p].z += bf2f(uh.z) + bf2f(ul.z); acc[p].w += bf2f(uh.w) + bf2f(ul.w);
    }
  }
#pragma unroll
  for (int p = 0; p < 4; ++p) {
    int f = tid + p * 256;
    int i = f >> 4, lc = (f & 15) * 4;
    T[i][lc + 0] = acc[p].x; T[i][lc + 1] = acc[p].y;
    T[i][lc + 2] = acc[p].z; T[i][lc + 3] = acc[p].w;
  }
  __syncthreads();
#pragma unroll
  for (int p = 0; p < 4; ++p) {
    int f = tid + p * 256;
    int lr = f >> 4, ic = (f & 15) * 4;
    float4 v = {T[ic + 0][lr], T[ic + 1][lr], T[ic + 2][lr], T[ic + 3][lr]};
    *reinterpret_cast<float4*>(&outa[((size_t)b * LL + l0 + lr) * IDF + ic]) = v;
  }
}

// ---------------------------------------------------------------------------
extern "C" void kernel_launch(void* const* d_in, const int* in_sizes, int n_in,
                              void* d_out, int out_size, void* d_ws, size_t ws_size,
                              hipStream_t stream) {
  const float* wc  = (const float*)d_in[0];   // [32][64][1024]
  const float* ctx = (const float*)d_in[1];   // [32][256][256]
  const float* W   = (const float*)d_in[2];   // [8][1024][256]
  float* out = (float*)d_out;

  // ws ~= 256 MB (fillBuffer WRITE_SIZE evidence, round 10). Disjoint regions:
  const size_t NE = 2097152;   // elems of wc == W == ctx
  const size_t NM = 4194304;   // elems of M == P == N2
  __hip_bfloat16* p = (__hip_bfloat16*)d_ws;
  __hip_bfloat16 *wch = p, *wcl = wch + NE, *wth = wcl + NE, *wtl = wth + NE;
  p = wtl + NE;
  __hip_bfloat16 *Mh = p, *Ml = Mh + NM;            p = Ml + NM;
  __hip_bfloat16 *cTh = p, *cTl = cTh + NE;         p = cTl + NE;
  __hip_bfloat16 *cNh = p, *cNl = cNh + NE;         p = cNl + NE;
  __hip_bfloat16 *Ph = p, *Pl = Ph + NM;            p = Pl + NM;
  __hip_bfloat16 *N2h = p, *N2l = N2h + NM;         p = N2l + NM;
  __hip_bfloat16 *Wh = p, *Wl = Wh + NE;            p = Wl + NE;
  float* Pbuf = (float*)p;                          // 2.1M floats

  k_split      <<<2048, 256, 0, stream>>>(wc, wch, wcl);
  k_split_Wt   <<<512, 256, 0, stream>>>(W, wth, wtl);
  k_split      <<<2048, 256, 0, stream>>>(W, Wh, Wl);
  k_split      <<<2048, 256, 0, stream>>>(ctx, cNh, cNl);
  k_split_ctxT <<<512, 256, 0, stream>>>(ctx, cTh, cTl);
  k1_mfma      <<<BB * NH * 2, 256, 0, stream>>>(wch, wcl, wth, wtl, Mh, Ml);
  k_attn       <<<BB * NH, 512, 0, stream>>>(Mh, Ml, cTh, cTl, Ph, Pl);
  k_N2         <<<BB * NH * 2, 256, 0, stream>>>(Ph, Pl, cNh, cNl, N2h, N2l);
  k_attnout    <<<BB * 4, 256, 0, stream>>>(Ph, Pl, out + (size_t)BB * IDF * SSZ);
  k4_mfma      <<<512, 256, 0, stream>>>(N2h, N2l, Wh, Wl, out, Pbuf);
  k_add        <<<2048, 256, 0, stream>>>(out, Pbuf);
}

// Round 12
// 152.374 us; speedup vs baseline: 2.5054x; 1.0161x over previous
//
#include <hip/hip_runtime.h>
#include <hip/hip_bf16.h>

#define BB 32
#define IDF 64
#define CDF 256
#define SSZ 1024
#define NH 8
#define LL 256
#define KHC 2048   // NH*CDF

typedef __attribute__((ext_vector_type(8))) short short8v;   // 8 bf16 (4 VGPR)
typedef __attribute__((ext_vector_type(4))) float f32x4;     // MFMA acc

// async global->LDS, 16B per lane, LDS dest = wave-uniform base + lane*16
#define GLDS16(g, l) __builtin_amdgcn_global_load_lds(                        \
    (const __attribute__((address_space(1))) void*)(g),                       \
    (__attribute__((address_space(3))) void*)(l), 16, 0, 0)

// counted-vmcnt phase boundaries (T4): wait for CURRENT buffer's DMA (leave
// NEXT buffer's N in flight), then barrier. Never vmcnt(0) mid-loop.
#define WAIT_BAR_ENTER(N)                                                     \
  { if (ks < NSTEP - 1) asm volatile("s_waitcnt vmcnt(" #N ")" ::: "memory"); \
    else                asm volatile("s_waitcnt vmcnt(0)" ::: "memory");      \
    __builtin_amdgcn_s_barrier();                                             \
    __builtin_amdgcn_sched_barrier(0); }
#define BAR_EXIT()                                                            \
  { __builtin_amdgcn_sched_barrier(0);                                        \
    __builtin_amdgcn_s_barrier();                                             \
    __builtin_amdgcn_sched_barrier(0); }

__device__ inline void split_bf16(float x, __hip_bfloat16& h, __hip_bfloat16& l) {
  h = __float2bfloat16(x);
  l = __float2bfloat16(x - __bfloat162float(h));
}
__device__ inline float bf2f(unsigned short u) {
  return __uint_as_float(((unsigned int)u) << 16);
}

// ---------------------------------------------------------------------------
// Generic elementwise split (2.097M elems): used for wc, W, ctx (same size).
// ---------------------------------------------------------------------------
__global__ __launch_bounds__(256) void k_split(const float* __restrict__ src,
                                               __hip_bfloat16* __restrict__ dh,
                                               __hip_bfloat16* __restrict__ dl) {
  int idx = (blockIdx.x * 256 + threadIdx.x) * 4;
  float4 v = *reinterpret_cast<const float4*>(&src[idx]);
  __align__(16) __hip_bfloat16 hb[4], lb[4];
  split_bf16(v.x, hb[0], lb[0]); split_bf16(v.y, hb[1], lb[1]);
  split_bf16(v.z, hb[2], lb[2]); split_bf16(v.w, hb[3], lb[3]);
  *reinterpret_cast<int2*>(&dh[idx]) = *reinterpret_cast<int2*>(hb);
  *reinterpret_cast<int2*>(&dl[idx]) = *reinterpret_cast<int2*>(lb);
}

// ---------------------------------------------------------------------------
// Split+transpose W[h][o][c] -> Wt hi/lo [h][c][o]. For K1.
// ---------------------------------------------------------------------------
__global__ __launch_bounds__(256) void k_split_Wt(const float* __restrict__ W,
                                                  __hip_bfloat16* __restrict__ wth,
                                                  __hip_bfloat16* __restrict__ wtl) {
  __shared__ float Tt[64][65];   // [c][o]
  int blk = blockIdx.x;
  int h = blk >> 6, ot = (blk >> 2) & 15, ct = blk & 3;
  int og = ot * 64, cg = ct * 64;
  int t = threadIdx.x;
  int o_l = t >> 4, c4 = (t & 15) * 4;
#pragma unroll
  for (int p = 0; p < 4; ++p) {
    int o = o_l + 16 * p;
    float4 v = *reinterpret_cast<const float4*>(
        &W[((size_t)h * SSZ + og + o) * CDF + cg + c4]);
    Tt[c4 + 0][o] = v.x; Tt[c4 + 1][o] = v.y;
    Tt[c4 + 2][o] = v.z; Tt[c4 + 3][o] = v.w;
  }
  __syncthreads();
  int c_l = t >> 2;
#pragma unroll
  for (int p = 0; p < 4; ++p) {
    int o0 = ((t & 3) + 4 * p) * 4;
    __hip_bfloat16 hv[4], lv[4];
#pragma unroll
    for (int j = 0; j < 4; ++j) split_bf16(Tt[c_l][o0 + j], hv[j], lv[j]);
    size_t base = ((size_t)h * CDF + cg + c_l) * SSZ + og + o0;
#pragma unroll
    for (int j = 0; j < 4; ++j) { wth[base + j] = hv[j]; wtl[base + j] = lv[j]; }
  }
}

// ---------------------------------------------------------------------------
// Split+transpose ctx[b][c][l] -> ctxT hi/lo [b][l][c]. For K2.
// ---------------------------------------------------------------------------
__global__ __launch_bounds__(256) void k_split_ctxT(const float* __restrict__ ctx,
                                                    __hip_bfloat16* __restrict__ Th,
                                                    __hip_bfloat16* __restrict__ Tl) {
  __shared__ float Tt[64][65];   // [l][c]
  int blk = blockIdx.x;
  int b = blk >> 4, ct = (blk >> 2) & 3, lt = blk & 3;
  int cg = ct * 64, lg = lt * 64;
  int t = threadIdx.x;
  int c_l = t >> 4, l4 = (t & 15) * 4;
#pragma unroll
  for (int p = 0; p < 4; ++p) {
    int c = c_l + 16 * p;
    float4 v = *reinterpret_cast<const float4*>(
        &ctx[((size_t)b * CDF + cg + c) * LL + lg + l4]);
    Tt[l4 + 0][c] = v.x; Tt[l4 + 1][c] = v.y;
    Tt[l4 + 2][c] = v.z; Tt[l4 + 3][c] = v.w;
  }
  __syncthreads();
  int l_l = t >> 2;
#pragma unroll
  for (int p = 0; p < 4; ++p) {
    int c0 = ((t & 3) + 4 * p) * 4;
    __hip_bfloat16 hv[4], lv[4];
#pragma unroll
    for (int j = 0; j < 4; ++j) split_bf16(Tt[l_l][c0 + j], hv[j], lv[j]);
    size_t base = ((size_t)b * LL + lg + l_l) * CDF + cg + c0;
#pragma unroll
    for (int j = 0; j < 4; ++j) { Th[base + j] = hv[j]; Tl[base + j] = lv[j]; }
  }
}

// ---------------------------------------------------------------------------
// K1 (MFMA, gload_lds, counted-vmcnt dbuf): M = wc*W^T -> Mh/Ml split.
// grid 512: (bh, nh-half of 128c). 4 waves x (64i x 32c). BK=32, 32 steps.
// 6 GLDS16 / wave / stage.
// ---------------------------------------------------------------------------
__device__ __forceinline__ void k1_stage(short* dst,
                                         const short* gA_h, const short* gA_l,
                                         const short* gB_h, const short* gB_l,
                                         int wave, int lane, int k0) {
#pragma unroll
  for (int j = 0; j < 6; ++j) {
    int inst = wave * 6 + j;
    const short* src; int tile_off, rb;
    if (inst < 4)       { src = gA_h; tile_off = 0;    rb = inst * 16; }
    else if (inst < 8)  { src = gA_l; tile_off = 2048; rb = (inst - 4) * 16; }
    else if (inst < 16) { src = gB_h; tile_off = 4096; rb = (inst - 8) * 16; }
    else                { src = gB_l; tile_off = 8192; rb = (inst - 16) * 16; }
    int r  = rb + (lane >> 2);
    int gc = (lane & 3) ^ ((r >> 1) & 3);
    GLDS16(src + (size_t)r * SSZ + k0 + gc * 8, dst + tile_off + rb * 32);
  }
}

__global__ __launch_bounds__(256) void k1_mfma(const __hip_bfloat16* __restrict__ wch,
                                               const __hip_bfloat16* __restrict__ wcl,
                                               const __hip_bfloat16* __restrict__ wth,
                                               const __hip_bfloat16* __restrict__ wtl,
                                               __hip_bfloat16* __restrict__ Mh,
                                               __hip_bfloat16* __restrict__ Ml) {
  __shared__ __align__(16) short S[2][12288];   // 48 KB

  int blk = blockIdx.x;
  int bh = blk >> 1, nh = blk & 1;
  int b = bh >> 3, h = bh & 7;
  int t = threadIdx.x;
  int lane = t & 63, wave = t >> 6;
  int ln15 = lane & 15, kh = lane >> 4;

  const short* gA_h = (const short*)wch + (size_t)b * IDF * SSZ;
  const short* gA_l = (const short*)wcl + (size_t)b * IDF * SSZ;
  const short* gB_h = (const short*)wth + (size_t)(h * CDF + nh * 128) * SSZ;
  const short* gB_l = (const short*)wtl + (size_t)(h * CDF + nh * 128) * SSZ;

  int offA[4], offB[2];
#pragma unroll
  for (int r = 0; r < 4; ++r) {
    int row = r * 16 + ln15;
    offA[r] = row * 32 + ((kh ^ ((row >> 1) & 3)) * 8);
  }
#pragma unroll
  for (int c = 0; c < 2; ++c) {
    int row = wave * 32 + c * 16 + ln15;
    offB[c] = row * 32 + ((kh ^ ((row >> 1) & 3)) * 8);
  }

  f32x4 acc[4][2] = {};
  k1_stage(&S[0][0], gA_h, gA_l, gB_h, gB_l, wave, lane, 0);
  k1_stage(&S[1][0], gA_h, gA_l, gB_h, gB_l, wave, lane, 32);
  int cur = 0;

  const int NSTEP = 32;
#pragma unroll 1
  for (int ks = 0; ks < NSTEP; ++ks) {
    WAIT_BAR_ENTER(6)
    short8v fa_h[4], fa_l[4], fb_h[2], fb_l[2];
#pragma unroll
    for (int r = 0; r < 4; ++r) {
      fa_h[r] = *reinterpret_cast<const short8v*>(&S[cur][offA[r]]);
      fa_l[r] = *reinterpret_cast<const short8v*>(&S[cur][2048 + offA[r]]);
    }
#pragma unroll
    for (int c = 0; c < 2; ++c) {
      fb_h[c] = *reinterpret_cast<const short8v*>(&S[cur][4096 + offB[c]]);
      fb_l[c] = *reinterpret_cast<const short8v*>(&S[cur][8192 + offB[c]]);
    }
#pragma unroll
    for (int r = 0; r < 4; ++r)
#pragma unroll
      for (int c = 0; c < 2; ++c) {
        acc[r][c] = __builtin_amdgcn_mfma_f32_16x16x32_bf16(fa_h[r], fb_h[c], acc[r][c], 0, 0, 0);
        acc[r][c] = __builtin_amdgcn_mfma_f32_16x16x32_bf16(fa_h[r], fb_l[c], acc[r][c], 0, 0, 0);
        acc[r][c] = __builtin_amdgcn_mfma_f32_16x16x32_bf16(fa_l[r], fb_h[c], acc[r][c], 0, 0, 0);
      }
    BAR_EXIT()
    if (ks + 2 < NSTEP)
      k1_stage(&S[cur][0], gA_h, gA_l, gB_h, gB_l, wave, lane, (ks + 2) * 32);
    cur ^= 1;
  }

  size_t obase = (size_t)bh * IDF * CDF + nh * 128;
  int rowq = (lane >> 4) * 4;
#pragma unroll
  for (int r = 0; r < 4; ++r)
#pragma unroll
    for (int c = 0; c < 2; ++c)
#pragma unroll
      for (int reg = 0; reg < 4; ++reg) {
        __hip_bfloat16 hb, lb;
        split_bf16(acc[r][c][reg], hb, lb);
        size_t idx = obase + (size_t)(r * 16 + rowq + reg) * CDF + wave * 32 + c * 16 + ln15;
        Mh[idx] = hb; Ml[idx] = lb;
      }
}

// ---------------------------------------------------------------------------
// K2 (MFMA + fused softmax, counted-vmcnt): P = softmax_l(M*ctxT^T) split.
// grid 256 (bh), 512 thr = 8 waves x (64i x 32l). K=256, BK=32, 8 steps.
// 5 GLDS16 / wave / stage.
// ---------------------------------------------------------------------------
__device__ __forceinline__ void k2_stage(short* dst,
                                         const short* gMh, const short* gMl,
                                         const short* gTh, const short* gTl,
                                         int wave, int lane, int k0) {
#pragma unroll
  for (int j = 0; j < 5; ++j) {
    int inst = wave * 5 + j;               // 0..39
    const short* src; int tile_off, rb;
    if (inst < 4)       { src = gMh; tile_off = 0;     rb = inst * 16; }
    else if (inst < 8)  { src = gMl; tile_off = 2048;  rb = (inst - 4) * 16; }
    else if (inst < 24) { src = gTh; tile_off = 4096;  rb = (inst - 8) * 16; }
    else                { src = gTl; tile_off = 12288; rb = (inst - 24) * 16; }
    int r  = rb + (lane >> 2);
    int gc = (lane & 3) ^ ((r >> 1) & 3);
    GLDS16(src + (size_t)r * CDF + k0 + gc * 8, dst + tile_off + rb * 32);
  }
}

__global__ __launch_bounds__(512) void k_attn(const __hip_bfloat16* __restrict__ Mh,
                                              const __hip_bfloat16* __restrict__ Ml,
                                              const __hip_bfloat16* __restrict__ cTh,
                                              const __hip_bfloat16* __restrict__ cTl,
                                              __hip_bfloat16* __restrict__ Ph,
                                              __hip_bfloat16* __restrict__ Pl) {
  __shared__ __align__(16) short S[2][20480];   // 80 KB

  int bh = blockIdx.x;
  int b = bh >> 3;
  int t = threadIdx.x;
  int lane = t & 63, wave = t >> 6;             // wave 0..7
  int ln15 = lane & 15, kh = lane >> 4;

  const short* gMh = (const short*)Mh + (size_t)bh * IDF * CDF;
  const short* gMl = (const short*)Ml + (size_t)bh * IDF * CDF;
  const short* gTh = (const short*)cTh + (size_t)b * LL * CDF;
  const short* gTl = (const short*)cTl + (size_t)b * LL * CDF;

  int offA[4], offB[2];
#pragma unroll
  for (int r = 0; r < 4; ++r) {
    int row = r * 16 + ln15;
    offA[r] = row * 32 + ((kh ^ ((row >> 1) & 3)) * 8);
  }
#pragma unroll
  for (int c = 0; c < 2; ++c) {
    int row = wave * 32 + c * 16 + ln15;
    offB[c] = row * 32 + ((kh ^ ((row >> 1) & 3)) * 8);
  }

  f32x4 acc[4][2] = {};
  k2_stage(&S[0][0], gMh, gMl, gTh, gTl, wave, lane, 0);
  k2_stage(&S[1][0], gMh, gMl, gTh, gTl, wave, lane, 32);
  int cur = 0;

  const int NSTEP = 8;
#pragma unroll 1
  for (int ks = 0; ks < NSTEP; ++ks) {
    WAIT_BAR_ENTER(5)
    short8v fa_h[4], fa_l[4], fb_h[2], fb_l[2];
#pragma unroll
    for (int r = 0; r < 4; ++r) {
      fa_h[r] = *reinterpret_cast<const short8v*>(&S[cur][offA[r]]);
      fa_l[r] = *reinterpret_cast<const short8v*>(&S[cur][2048 + offA[r]]);
    }
#pragma unroll
    for (int c = 0; c < 2; ++c) {
      fb_h[c] = *reinterpret_cast<const short8v*>(&S[cur][4096 + offB[c]]);
      fb_l[c] = *reinterpret_cast<const short8v*>(&S[cur][12288 + offB[c]]);
    }
#pragma unroll
    for (int r = 0; r < 4; ++r)
#pragma unroll
      for (int c = 0; c < 2; ++c) {
        acc[r][c] = __builtin_amdgcn_mfma_f32_16x16x32_bf16(fa_h[r], fb_h[c], acc[r][c], 0, 0, 0);
        acc[r][c] = __builtin_amdgcn_mfma_f32_16x16x32_bf16(fa_h[r], fb_l[c], acc[r][c], 0, 0, 0);
        acc[r][c] = __builtin_amdgcn_mfma_f32_16x16x32_bf16(fa_l[r], fb_h[c], acc[r][c], 0, 0, 0);
      }
    BAR_EXIT()
    if (ks + 2 < NSTEP)
      k2_stage(&S[cur][0], gMh, gMl, gTh, gTl, wave, lane, (ks + 2) * 32);
    cur ^= 1;
  }

  // ---- fused softmax over l (cols). row = r*16+(lane>>4)*4+reg,
  //      col = wave*32 + c*16 + (lane&15). pm[row][w] partials in LDS.
  float* pm = reinterpret_cast<float*>(&S[0][0]);   // 64*8 floats
  int rowq = (lane >> 4) * 4;
  float gmax[4][4], ginv[4][4];
#pragma unroll
  for (int r = 0; r < 4; ++r)
#pragma unroll
    for (int reg = 0; reg < 4; ++reg) {
      float m = fmaxf(acc[r][0][reg], acc[r][1][reg]);
#pragma unroll
      for (int msk = 8; msk >= 1; msk >>= 1) m = fmaxf(m, __shfl_xor(m, msk, 64));
      if (ln15 == 0) pm[(r * 16 + rowq + reg) * 8 + wave] = m;
    }
  __syncthreads();
#pragma unroll
  for (int r = 0; r < 4; ++r)
#pragma unroll
    for (int reg = 0; reg < 4; ++reg) {
      int row = r * 16 + rowq + reg;
      float4 p0 = *reinterpret_cast<const float4*>(&pm[row * 8]);
      float4 p1 = *reinterpret_cast<const float4*>(&pm[row * 8 + 4]);
      gmax[r][reg] = fmaxf(fmaxf(fmaxf(p0.x, p0.y), fmaxf(p0.z, p0.w)),
                           fmaxf(fmaxf(p1.x, p1.y), fmaxf(p1.z, p1.w)));
    }
  __syncthreads();
#pragma unroll
  for (int r = 0; r < 4; ++r)
#pragma unroll
    for (int reg = 0; reg < 4; ++reg) {
      acc[r][0][reg] = __expf(acc[r][0][reg] - gmax[r][reg]);
      acc[r][1][reg] = __expf(acc[r][1][reg] - gmax[r][reg]);
      float s = acc[r][0][reg] + acc[r][1][reg];
#pragma unroll
      for (int msk = 8; msk >= 1; msk >>= 1) s += __shfl_xor(s, msk, 64);
      if (ln15 == 0) pm[(r * 16 + rowq + reg) * 8 + wave] = s;
    }
  __syncthreads();
#pragma unroll
  for (int r = 0; r < 4; ++r)
#pragma unroll
    for (int reg = 0; reg < 4; ++reg) {
      int row = r * 16 + rowq + reg;
      float4 p0 = *reinterpret_cast<const float4*>(&pm[row * 8]);
      float4 p1 = *reinterpret_cast<const float4*>(&pm[row * 8 + 4]);
      ginv[r][reg] = 1.f / (p0.x + p0.y + p0.z + p0.w + p1.x + p1.y + p1.z + p1.w);
    }
  size_t obase = (size_t)bh * IDF * LL;
#pragma unroll
  for (int r = 0; r < 4; ++r)
#pragma unroll
    for (int c = 0; c < 2; ++c)
#pragma unroll
      for (int reg = 0; reg < 4; ++reg) {
        float p = acc[r][c][reg] * ginv[r][reg];
        __hip_bfloat16 hb, lb;
        split_bf16(p, hb, lb);
        size_t idx = obase + (size_t)(r * 16 + rowq + reg) * LL + wave * 32 + c * 16 + ln15;
        Ph[idx] = hb; Pl[idx] = lb;
      }
}

// ---------------------------------------------------------------------------
// K3 (MFMA, counted-vmcnt): N2[b][i][h*256+c] = sum_l P[i][l]*ctx[c][l].
// grid 512 (bh, ch). 4 waves x (64i x 32c). K=256, BK=32, 8 steps.
// ---------------------------------------------------------------------------
__device__ __forceinline__ void k3_stage(short* dst,
                                         const short* gPh, const short* gPl,
                                         const short* gCh, const short* gCl,
                                         int wave, int lane, int k0) {
#pragma unroll
  for (int j = 0; j < 6; ++j) {
    int inst = wave * 6 + j;
    const short* src; int tile_off, rb;
    if (inst < 4)       { src = gPh; tile_off = 0;    rb = inst * 16; }
    else if (inst < 8)  { src = gPl; tile_off = 2048; rb = (inst - 4) * 16; }
    else if (inst < 16) { src = gCh; tile_off = 4096; rb = (inst - 8) * 16; }
    else                { src = gCl; tile_off = 8192; rb = (inst - 16) * 16; }
    int r  = rb + (lane >> 2);
    int gc = (lane & 3) ^ ((r >> 1) & 3);
    GLDS16(src + (size_t)r * LL + k0 + gc * 8, dst + tile_off + rb * 32);
  }
}

__global__ __launch_bounds__(256) void k_N2(const __hip_bfloat16* __restrict__ Ph,
                                            const __hip_bfloat16* __restrict__ Pl,
                                            const __hip_bfloat16* __restrict__ cNh,
                                            const __hip_bfloat16* __restrict__ cNl,
                                            __hip_bfloat16* __restrict__ N2h,
                                            __hip_bfloat16* __restrict__ N2l) {
  __shared__ __align__(16) short S[2][12288];   // 48 KB

  int blk = blockIdx.x;
  int bh = blk >> 1, ch = blk & 1;
  int b = bh >> 3, h = bh & 7;
  int cgbase = ch * 128;
  int t = threadIdx.x;
  int lane = t & 63, wave = t >> 6;
  int ln15 = lane & 15, kh = lane >> 4;

  const short* gPh = (const short*)Ph + (size_t)bh * IDF * LL;
  const short* gPl = (const short*)Pl + (size_t)bh * IDF * LL;
  const short* gCh = (const short*)cNh + (size_t)(b * CDF + cgbase) * LL;
  const short* gCl = (const short*)cNl + (size_t)(b * CDF + cgbase) * LL;

  int offA[4], offB[2];
#pragma unroll
  for (int r = 0; r < 4; ++r) {
    int row = r * 16 + ln15;
    offA[r] = row * 32 + ((kh ^ ((row >> 1) & 3)) * 8);
  }
#pragma unroll
  for (int c = 0; c < 2; ++c) {
    int row = wave * 32 + c * 16 + ln15;
    offB[c] = row * 32 + ((kh ^ ((row >> 1) & 3)) * 8);
  }

  f32x4 acc[4][2] = {};
  k3_stage(&S[0][0], gPh, gPl, gCh, gCl, wave, lane, 0);
  k3_stage(&S[1][0], gPh, gPl, gCh, gCl, wave, lane, 32);
  int cur = 0;

  const int NSTEP = 8;
#pragma unroll 1
  for (int ks = 0; ks < NSTEP; ++ks) {
    WAIT_BAR_ENTER(6)
    short8v fa_h[4], fa_l[4], fb_h[2], fb_l[2];
#pragma unroll
    for (int r = 0; r < 4; ++r) {
      fa_h[r] = *reinterpret_cast<const short8v*>(&S[cur][offA[r]]);
      fa_l[r] = *reinterpret_cast<const short8v*>(&S[cur][2048 + offA[r]]);
    }
#pragma unroll
    for (int c = 0; c < 2; ++c) {
      fb_h[c] = *reinterpret_cast<const short8v*>(&S[cur][4096 + offB[c]]);
      fb_l[c] = *reinterpret_cast<const short8v*>(&S[cur][8192 + offB[c]]);
    }
#pragma unroll
    for (int r = 0; r < 4; ++r)
#pragma unroll
      for (int c = 0; c < 2; ++c) {
        acc[r][c] = __builtin_amdgcn_mfma_f32_16x16x32_bf16(fa_h[r], fb_h[c], acc[r][c], 0, 0, 0);
        acc[r][c] = __builtin_amdgcn_mfma_f32_16x16x32_bf16(fa_h[r], fb_l[c], acc[r][c], 0, 0, 0);
        acc[r][c] = __builtin_amdgcn_mfma_f32_16x16x32_bf16(fa_l[r], fb_h[c], acc[r][c], 0, 0, 0);
      }
    BAR_EXIT()
    if (ks + 2 < NSTEP)
      k3_stage(&S[cur][0], gPh, gPl, gCh, gCl, wave, lane, (ks + 2) * 32);
    cur ^= 1;
  }

  size_t base = (size_t)b * IDF * KHC + h * CDF + cgbase;
  int rowq = (lane >> 4) * 4;
#pragma unroll
  for (int r = 0; r < 4; ++r)
#pragma unroll
    for (int c = 0; c < 2; ++c)
#pragma unroll
      for (int reg = 0; reg < 4; ++reg) {
        __hip_bfloat16 hb, lb;
        split_bf16(acc[r][c][reg], hb, lb);
        size_t idx = base + (size_t)(r * 16 + rowq + reg) * KHC + wave * 32 + c * 16 + ln15;
        N2h[idx] = hb; N2l[idx] = lb;
      }
}

// ---------------------------------------------------------------------------
// K4 (MFMA, counted-vmcnt): ctx_out[b][i][o] = sum_{hc} N2*W.
// grid 512: g(2) x b(32) x ot(8). 4 waves x (64i x 32o). 32 steps.
// ---------------------------------------------------------------------------
__device__ __forceinline__ void k4_stage(short* dst,
                                         const short* gA_h, const short* gA_l,
                                         const short* gB_h, const short* gB_l,
                                         int wave, int lane, int kk0, int obase) {
  int h4 = kk0 >> 8, cb = kk0 & 255;
#pragma unroll
  for (int j = 0; j < 6; ++j) {
    int inst = wave * 6 + j;
    if (inst < 8) {
      const short* src = (inst < 4) ? gA_h : gA_l;
      int tile_off = (inst < 4) ? 0 : 2048;
      int rb = (inst & 3) * 16;
      int r  = rb + (lane >> 2);
      int gc = (lane & 3) ^ ((r >> 1) & 3);
      GLDS16(src + (size_t)r * KHC + kk0 + gc * 8, dst + tile_off + rb * 32);
    } else {
      int t2 = inst - 8;
      const short* src = (t2 < 8) ? gB_h : gB_l;
      int tile_off = (t2 < 8) ? 4096 : 8192;
      int rb = (t2 & 7) * 16;
      int r  = rb + (lane >> 2);
      int gc = (lane & 3) ^ ((r >> 1) & 3);
      GLDS16(src + (size_t)(h4 * SSZ + obase + r) * CDF + cb + gc * 8, dst + tile_off + rb * 32);
    }
  }
}

__global__ __launch_bounds__(256) void k4_mfma(const __hip_bfloat16* __restrict__ N2h,
                                               const __hip_bfloat16* __restrict__ N2l,
                                               const __hip_bfloat16* __restrict__ Wh,
                                               const __hip_bfloat16* __restrict__ Wl,
                                               float* __restrict__ out0,
                                               float* __restrict__ out1) {
  __shared__ __align__(16) short S[2][12288];   // 48 KB

  int blk = blockIdx.x;
  int g = blk >> 8;
  int r8 = blk & 255;
  int b = r8 >> 3, ot = r8 & 7;
  int obase = ot * 128;
  int t = threadIdx.x;
  int lane = t & 63, wave = t >> 6;
  int ln15 = lane & 15, kh = lane >> 4;

  const short* gA_h = (const short*)N2h + (size_t)b * IDF * KHC;
  const short* gA_l = (const short*)N2l + (size_t)b * IDF * KHC;
  const short* gB_h = (const short*)Wh;
  const short* gB_l = (const short*)Wl;

  int offA[4], offB[2];
#pragma unroll
  for (int r = 0; r < 4; ++r) {
    int row = r * 16 + ln15;
    offA[r] = row * 32 + ((kh ^ ((row >> 1) & 3)) * 8);
  }
#pragma unroll
  for (int c = 0; c < 2; ++c) {
    int row = wave * 32 + c * 16 + ln15;
    offB[c] = row * 32 + ((kh ^ ((row >> 1) & 3)) * 8);
  }

  int kbase = g * (KHC / 2);
  f32x4 acc[4][2] = {};

  k4_stage(&S[0][0], gA_h, gA_l, gB_h, gB_l, wave, lane, kbase, obase);
  k4_stage(&S[1][0], gA_h, gA_l, gB_h, gB_l, wave, lane, kbase + 32, obase);
  int cur = 0;

  const int NSTEP = 32;
#pragma unroll 1
  for (int ks = 0; ks < NSTEP; ++ks) {
    WAIT_BAR_ENTER(6)
    short8v fa_h[4], fa_l[4], fb_h[2], fb_l[2];
#pragma unroll
    for (int r = 0; r < 4; ++r) {
      fa_h[r] = *reinterpret_cast<const short8v*>(&S[cur][offA[r]]);
      fa_l[r] = *reinterpret_cast<const short8v*>(&S[cur][2048 + offA[r]]);
    }
#pragma unroll
    for (int c = 0; c < 2; ++c) {
      fb_h[c] = *reinterpret_cast<const short8v*>(&S[cur][4096 + offB[c]]);
      fb_l[c] = *reinterpret_cast<const short8v*>(&S[cur][8192 + offB[c]]);
    }
#pragma unroll
    for (int r = 0; r < 4; ++r)
#pragma unroll
      for (int c = 0; c < 2; ++c) {
        acc[r][c] = __builtin_amdgcn_mfma_f32_16x16x32_bf16(fa_h[r], fb_h[c], acc[r][c], 0, 0, 0);
        acc[r][c] = __builtin_amdgcn_mfma_f32_16x16x32_bf16(fa_h[r], fb_l[c], acc[r][c], 0, 0, 0);
        acc[r][c] = __builtin_amdgcn_mfma_f32_16x16x32_bf16(fa_l[r], fb_h[c], acc[r][c], 0, 0, 0);
      }
    BAR_EXIT()
    if (ks + 2 < NSTEP)
      k4_stage(&S[cur][0], gA_h, gA_l, gB_h, gB_l, wave, lane,
               kbase + (ks + 2) * 32, obase);
    cur ^= 1;
  }

  float* dst = (g == 0) ? out0 : out1;
  int rowq = (lane >> 4) * 4;
#pragma unroll
  for (int r = 0; r < 4; ++r)
#pragma unroll
    for (int c = 0; c < 2; ++c)
#pragma unroll
      for (int reg = 0; reg < 4; ++reg)
        dst[((size_t)b * IDF + r * 16 + rowq + reg) * SSZ +
            obase + wave * 32 + c * 16 + ln15] = acc[r][c][reg];
}

// out += P
__global__ __launch_bounds__(256) void k_add(float* __restrict__ out,
                                             const float* __restrict__ P) {
  int idx = blockIdx.x * 256 + threadIdx.x;
  float4 a = reinterpret_cast<float4*>(out)[idx];
  float4 p = reinterpret_cast<const float4*>(P)[idx];
  a.x += p.x; a.y += p.y; a.z += p.z; a.w += p.w;
  reinterpret_cast<float4*>(out)[idx] = a;
}

// ---------------------------------------------------------------------------
// K5: attn_out[b][l][i] = sum_h (Ph+Pl)[bh][i][l]  (bf16 pair input)
// ---------------------------------------------------------------------------
__global__ __launch_bounds__(256) void k_attnout(const __hip_bfloat16* __restrict__ Ph,
                                                 const __hip_bfloat16* __restrict__ Pl,
                                                 float* __restrict__ outa) {
  __shared__ float T[64][65];
  int blk = blockIdx.x; int b = blk >> 2, lt = blk & 3;
  int l0 = lt * 64;
  int tid = threadIdx.x;
  const unsigned short* ph = (const unsigned short*)Ph;
  const unsigned short* pl = (const unsigned short*)Pl;
  float4 acc[4];
#pragma unroll
  for (int p = 0; p < 4; ++p) acc[p] = make_float4(0.f, 0.f, 0.f, 0.f);
  for (int h = 0; h < NH; ++h) {
    size_t src = (size_t)(b * NH + h) * IDF * LL;
#pragma unroll
    for (int p = 0; p < 4; ++p) {
      int f = tid + p * 256;
      int i = f >> 4, lc = (f & 15) * 4;
      ushort4 uh = *reinterpret_cast<const ushort4*>(&ph[src + i * LL + l0 + lc]);
      ushort4 ul = *reinterpret_cast<const ushort4*>(&pl[src + i * LL + l0 + lc]);
      acc[p].x += bf2f(uh.x) + bf2f(ul.x); acc[p].y += bf2f(uh.y) + bf2f(ul.y);
      acc[p].z += bf2f(uh.z) + bf2f(ul.z); acc[p].w += bf2f(uh.w) + bf2f(ul.w);
    }
  }
#pragma unroll
  for (int p = 0; p < 4; ++p) {
    int f = tid + p * 256;
    int i = f >> 4, lc = (f & 15) * 4;
    T[i][lc + 0] = acc[p].x; T[i][lc + 1] = acc[p].y;
    T[i][lc + 2] = acc[p].z; T[i][lc + 3] = acc[p].w;
  }
  __syncthreads();
#pragma unroll
  for (int p = 0; p < 4; ++p) {
    int f = tid + p * 256;
    int lr = f >> 4, ic = (f & 15) * 4;
    float4 v = {T[ic + 0][lr], T[ic + 1][lr], T[ic + 2][lr], T[ic + 3][lr]};
    *reinterpret_cast<float4*>(&outa[((size_t)b * LL + l0 + lr) * IDF + ic]) = v;
  }
}

// ---------------------------------------------------------------------------
extern "C" void kernel_launch(void* const* d_in, const int* in_sizes, int n_in,
                              void* d_out, int out_size, void* d_ws, size_t ws_size,
                              hipStream_t stream) {
  const float* wc  = (const float*)d_in[0];   // [32][64][1024]
  const float* ctx = (const float*)d_in[1];   // [32][256][256]
  const float* W   = (const float*)d_in[2];   // [8][1024][256]
  float* out = (float*)d_out;

  const size_t NE = 2097152;   // elems of wc == W == ctx
  const size_t NM = 4194304;   // elems of M == P == N2
  __hip_bfloat16* p = (__hip_bfloat16*)d_ws;
  __hip_bfloat16 *wch = p, *wcl = wch + NE, *wth = wcl + NE, *wtl = wth + NE;
  p = wtl + NE;
  __hip_bfloat16 *Mh = p, *Ml = Mh + NM;            p = Ml + NM;
  __hip_bfloat16 *cTh = p, *cTl = cTh + NE;         p = cTl + NE;
  __hip_bfloat16 *cNh = p, *cNl = cNh + NE;         p = cNl + NE;
  __hip_bfloat16 *Ph = p, *Pl = Ph + NM;            p = Pl + NM;
  __hip_bfloat16 *N2h = p, *N2l = N2h + NM;         p = N2l + NM;
  __hip_bfloat16 *Wh = p, *Wl = Wh + NE;            p = Wl + NE;
  float* Pbuf = (float*)p;                          // 2.1M floats

  k_split      <<<2048, 256, 0, stream>>>(wc, wch, wcl);
  k_split_Wt   <<<512, 256, 0, stream>>>(W, wth, wtl);
  k_split      <<<2048, 256, 0, stream>>>(W, Wh, Wl);
  k_split      <<<2048, 256, 0, stream>>>(ctx, cNh, cNl);
  k_split_ctxT <<<512, 256, 0, stream>>>(ctx, cTh, cTl);
  k1_mfma      <<<BB * NH * 2, 256, 0, stream>>>(wch, wcl, wth, wtl, Mh, Ml);
  k_attn       <<<BB * NH, 512, 0, stream>>>(Mh, Ml, cTh, cTl, Ph, Pl);
  k_N2         <<<BB * NH * 2, 256, 0, stream>>>(Ph, Pl, cNh, cNl, N2h, N2l);
  k_attnout    <<<BB * 4, 256, 0, stream>>>(Ph, Pl, out + (size_t)BB * IDF * SSZ);
  k4_mfma      <<<512, 256, 0, stream>>>(N2h, N2l, Wh, Wl, out, Pbuf);
  k_add        <<<2048, 256, 0, stream>>>(out, Pbuf);
}

// Round 13
// 151.240 us; speedup vs baseline: 2.5242x; 1.0075x over previous
//
#include <hip/hip_runtime.h>
#include <hip/hip_bf16.h>

#define BB 32
#define IDF 64
#define CDF 256
#define SSZ 1024
#define NH 8
#define LL 256
#define KHC 2048   // NH*CDF

typedef __attribute__((ext_vector_type(8))) short short8v;   // 8 bf16 (4 VGPR)
typedef __attribute__((ext_vector_type(4))) float f32x4;     // MFMA acc

// async global->LDS, 16B per lane, LDS dest = wave-uniform base + lane*16
#define GLDS16(g, l) __builtin_amdgcn_global_load_lds(                        \
    (const __attribute__((address_space(1))) void*)(g),                       \
    (__attribute__((address_space(3))) void*)(l), 16, 0, 0)

// 3-deep pipeline phase entry (T3+T4): wait only for the CURRENT buffer's
// DMA, leaving the next TWO stages in flight. Never vmcnt(0) mid-loop.
#define WAIT_ENTER3(NFULL, NHALF)                                             \
  { if (ks < NSTEP - 2)                                                       \
      asm volatile("s_waitcnt vmcnt(" #NFULL ")" ::: "memory");               \
    else if (ks == NSTEP - 2)                                                 \
      asm volatile("s_waitcnt vmcnt(" #NHALF ")" ::: "memory");               \
    else                                                                      \
      asm volatile("s_waitcnt vmcnt(0)" ::: "memory");                        \
    __builtin_amdgcn_s_barrier();                                             \
    __builtin_amdgcn_sched_barrier(0); }
#define BAR_EXIT()                                                            \
  { __builtin_amdgcn_sched_barrier(0);                                        \
    __builtin_amdgcn_s_barrier();                                             \
    __builtin_amdgcn_sched_barrier(0); }

__device__ inline void split_bf16(float x, __hip_bfloat16& h, __hip_bfloat16& l) {
  h = __float2bfloat16(x);
  l = __float2bfloat16(x - __bfloat162float(h));
}
__device__ inline float bf2f(unsigned short u) {
  return __uint_as_float(((unsigned int)u) << 16);
}

// ---------------------------------------------------------------------------
// Generic elementwise split (2.097M elems): used for wc, W, ctx (same size).
// ---------------------------------------------------------------------------
__global__ __launch_bounds__(256) void k_split(const float* __restrict__ src,
                                               __hip_bfloat16* __restrict__ dh,
                                               __hip_bfloat16* __restrict__ dl) {
  int idx = (blockIdx.x * 256 + threadIdx.x) * 4;
  float4 v = *reinterpret_cast<const float4*>(&src[idx]);
  __align__(16) __hip_bfloat16 hb[4], lb[4];
  split_bf16(v.x, hb[0], lb[0]); split_bf16(v.y, hb[1], lb[1]);
  split_bf16(v.z, hb[2], lb[2]); split_bf16(v.w, hb[3], lb[3]);
  *reinterpret_cast<int2*>(&dh[idx]) = *reinterpret_cast<int2*>(hb);
  *reinterpret_cast<int2*>(&dl[idx]) = *reinterpret_cast<int2*>(lb);
}

// ---------------------------------------------------------------------------
// Split+transpose W[h][o][c] -> Wt hi/lo [h][c][o]. For K1.
// ---------------------------------------------------------------------------
__global__ __launch_bounds__(256) void k_split_Wt(const float* __restrict__ W,
                                                  __hip_bfloat16* __restrict__ wth,
                                                  __hip_bfloat16* __restrict__ wtl) {
  __shared__ float Tt[64][65];   // [c][o]
  int blk = blockIdx.x;
  int h = blk >> 6, ot = (blk >> 2) & 15, ct = blk & 3;
  int og = ot * 64, cg = ct * 64;
  int t = threadIdx.x;
  int o_l = t >> 4, c4 = (t & 15) * 4;
#pragma unroll
  for (int p = 0; p < 4; ++p) {
    int o = o_l + 16 * p;
    float4 v = *reinterpret_cast<const float4*>(
        &W[((size_t)h * SSZ + og + o) * CDF + cg + c4]);
    Tt[c4 + 0][o] = v.x; Tt[c4 + 1][o] = v.y;
    Tt[c4 + 2][o] = v.z; Tt[c4 + 3][o] = v.w;
  }
  __syncthreads();
  int c_l = t >> 2;
#pragma unroll
  for (int p = 0; p < 4; ++p) {
    int o0 = ((t & 3) + 4 * p) * 4;
    __hip_bfloat16 hv[4], lv[4];
#pragma unroll
    for (int j = 0; j < 4; ++j) split_bf16(Tt[c_l][o0 + j], hv[j], lv[j]);
    size_t base = ((size_t)h * CDF + cg + c_l) * SSZ + og + o0;
#pragma unroll
    for (int j = 0; j < 4; ++j) { wth[base + j] = hv[j]; wtl[base + j] = lv[j]; }
  }
}

// ---------------------------------------------------------------------------
// Split+transpose ctx[b][c][l] -> ctxT hi/lo [b][l][c]. For K2.
// ---------------------------------------------------------------------------
__global__ __launch_bounds__(256) void k_split_ctxT(const float* __restrict__ ctx,
                                                    __hip_bfloat16* __restrict__ Th,
                                                    __hip_bfloat16* __restrict__ Tl) {
  __shared__ float Tt[64][65];   // [l][c]
  int blk = blockIdx.x;
  int b = blk >> 4, ct = (blk >> 2) & 3, lt = blk & 3;
  int cg = ct * 64, lg = lt * 64;
  int t = threadIdx.x;
  int c_l = t >> 4, l4 = (t & 15) * 4;
#pragma unroll
  for (int p = 0; p < 4; ++p) {
    int c = c_l + 16 * p;
    float4 v = *reinterpret_cast<const float4*>(
        &ctx[((size_t)b * CDF + cg + c) * LL + lg + l4]);
    Tt[l4 + 0][c] = v.x; Tt[l4 + 1][c] = v.y;
    Tt[l4 + 2][c] = v.z; Tt[l4 + 3][c] = v.w;
  }
  __syncthreads();
  int l_l = t >> 2;
#pragma unroll
  for (int p = 0; p < 4; ++p) {
    int c0 = ((t & 3) + 4 * p) * 4;
    __hip_bfloat16 hv[4], lv[4];
#pragma unroll
    for (int j = 0; j < 4; ++j) split_bf16(Tt[l_l][c0 + j], hv[j], lv[j]);
    size_t base = ((size_t)b * LL + lg + l_l) * CDF + cg + c0;
#pragma unroll
    for (int j = 0; j < 4; ++j) { Th[base + j] = hv[j]; Tl[base + j] = lv[j]; }
  }
}

// ---------------------------------------------------------------------------
// K1 (MFMA, gload_lds, 3-deep counted-vmcnt): M = wc*W^T -> Mh/Ml split.
// grid 512: (bh, nh-half of 128c). 4 waves x (64i x 32c). BK=32, 32 steps.
// 6 GLDS16 / wave / stage; 3 x 24 KB LDS buffers.
// ---------------------------------------------------------------------------
__device__ __forceinline__ void k1_stage(short* dst,
                                         const short* gA_h, const short* gA_l,
                                         const short* gB_h, const short* gB_l,
                                         int wave, int lane, int k0) {
#pragma unroll
  for (int j = 0; j < 6; ++j) {
    int inst = wave * 6 + j;
    const short* src; int tile_off, rb;
    if (inst < 4)       { src = gA_h; tile_off = 0;    rb = inst * 16; }
    else if (inst < 8)  { src = gA_l; tile_off = 2048; rb = (inst - 4) * 16; }
    else if (inst < 16) { src = gB_h; tile_off = 4096; rb = (inst - 8) * 16; }
    else                { src = gB_l; tile_off = 8192; rb = (inst - 16) * 16; }
    int r  = rb + (lane >> 2);
    int gc = (lane & 3) ^ ((r >> 1) & 3);
    GLDS16(src + (size_t)r * SSZ + k0 + gc * 8, dst + tile_off + rb * 32);
  }
}

__global__ __launch_bounds__(256) void k1_mfma(const __hip_bfloat16* __restrict__ wch,
                                               const __hip_bfloat16* __restrict__ wcl,
                                               const __hip_bfloat16* __restrict__ wth,
                                               const __hip_bfloat16* __restrict__ wtl,
                                               __hip_bfloat16* __restrict__ Mh,
                                               __hip_bfloat16* __restrict__ Ml) {
  __shared__ __align__(16) short S[3 * 12288];   // 72 KB

  int blk = blockIdx.x;
  int bh = blk >> 1, nh = blk & 1;
  int b = bh >> 3, h = bh & 7;
  int t = threadIdx.x;
  int lane = t & 63, wave = t >> 6;
  int ln15 = lane & 15, kh = lane >> 4;

  const short* gA_h = (const short*)wch + (size_t)b * IDF * SSZ;
  const short* gA_l = (const short*)wcl + (size_t)b * IDF * SSZ;
  const short* gB_h = (const short*)wth + (size_t)(h * CDF + nh * 128) * SSZ;
  const short* gB_l = (const short*)wtl + (size_t)(h * CDF + nh * 128) * SSZ;

  int offA[4], offB[2];
#pragma unroll
  for (int r = 0; r < 4; ++r) {
    int row = r * 16 + ln15;
    offA[r] = row * 32 + ((kh ^ ((row >> 1) & 3)) * 8);
  }
#pragma unroll
  for (int c = 0; c < 2; ++c) {
    int row = wave * 32 + c * 16 + ln15;
    offB[c] = row * 32 + ((kh ^ ((row >> 1) & 3)) * 8);
  }

  f32x4 acc[4][2] = {};
  k1_stage(&S[0],         gA_h, gA_l, gB_h, gB_l, wave, lane, 0);
  k1_stage(&S[12288],     gA_h, gA_l, gB_h, gB_l, wave, lane, 32);
  k1_stage(&S[2 * 12288], gA_h, gA_l, gB_h, gB_l, wave, lane, 64);
  int cur = 0;

  const int NSTEP = 32;
#pragma unroll 1
  for (int ks = 0; ks < NSTEP; ++ks) {
    short* Sc = &S[cur * 12288];
    WAIT_ENTER3(12, 6)
    short8v fa_h[4], fa_l[4], fb_h[2], fb_l[2];
#pragma unroll
    for (int r = 0; r < 4; ++r) {
      fa_h[r] = *reinterpret_cast<const short8v*>(&Sc[offA[r]]);
      fa_l[r] = *reinterpret_cast<const short8v*>(&Sc[2048 + offA[r]]);
    }
#pragma unroll
    for (int c = 0; c < 2; ++c) {
      fb_h[c] = *reinterpret_cast<const short8v*>(&Sc[4096 + offB[c]]);
      fb_l[c] = *reinterpret_cast<const short8v*>(&Sc[8192 + offB[c]]);
    }
    __builtin_amdgcn_s_setprio(1);
#pragma unroll
    for (int r = 0; r < 4; ++r)
#pragma unroll
      for (int c = 0; c < 2; ++c) {
        acc[r][c] = __builtin_amdgcn_mfma_f32_16x16x32_bf16(fa_h[r], fb_h[c], acc[r][c], 0, 0, 0);
        acc[r][c] = __builtin_amdgcn_mfma_f32_16x16x32_bf16(fa_h[r], fb_l[c], acc[r][c], 0, 0, 0);
        acc[r][c] = __builtin_amdgcn_mfma_f32_16x16x32_bf16(fa_l[r], fb_h[c], acc[r][c], 0, 0, 0);
      }
    __builtin_amdgcn_s_setprio(0);
    BAR_EXIT()
    if (ks + 3 < NSTEP)
      k1_stage(Sc, gA_h, gA_l, gB_h, gB_l, wave, lane, (ks + 3) * 32);
    cur = (cur == 2) ? 0 : cur + 1;
  }

  size_t obase = (size_t)bh * IDF * CDF + nh * 128;
  int rowq = (lane >> 4) * 4;
#pragma unroll
  for (int r = 0; r < 4; ++r)
#pragma unroll
    for (int c = 0; c < 2; ++c)
#pragma unroll
      for (int reg = 0; reg < 4; ++reg) {
        __hip_bfloat16 hb, lb;
        split_bf16(acc[r][c][reg], hb, lb);
        size_t idx = obase + (size_t)(r * 16 + rowq + reg) * CDF + wave * 32 + c * 16 + ln15;
        Mh[idx] = hb; Ml[idx] = lb;
      }
}

// ---------------------------------------------------------------------------
// K2 (MFMA + fused softmax, 3-deep): P = softmax_l(M*ctxT^T) split.
// grid 256 (bh), 512 thr = 8 waves x (64i x 32l). K=256, BK=32, 8 steps.
// 5 GLDS16 / wave / stage; 3 x 40 KB LDS buffers (120 KB).
// ---------------------------------------------------------------------------
__device__ __forceinline__ void k2_stage(short* dst,
                                         const short* gMh, const short* gMl,
                                         const short* gTh, const short* gTl,
                                         int wave, int lane, int k0) {
#pragma unroll
  for (int j = 0; j < 5; ++j) {
    int inst = wave * 5 + j;               // 0..39
    const short* src; int tile_off, rb;
    if (inst < 4)       { src = gMh; tile_off = 0;     rb = inst * 16; }
    else if (inst < 8)  { src = gMl; tile_off = 2048;  rb = (inst - 4) * 16; }
    else if (inst < 24) { src = gTh; tile_off = 4096;  rb = (inst - 8) * 16; }
    else                { src = gTl; tile_off = 12288; rb = (inst - 24) * 16; }
    int r  = rb + (lane >> 2);
    int gc = (lane & 3) ^ ((r >> 1) & 3);
    GLDS16(src + (size_t)r * CDF + k0 + gc * 8, dst + tile_off + rb * 32);
  }
}

__global__ __launch_bounds__(512) void k_attn(const __hip_bfloat16* __restrict__ Mh,
                                              const __hip_bfloat16* __restrict__ Ml,
                                              const __hip_bfloat16* __restrict__ cTh,
                                              const __hip_bfloat16* __restrict__ cTl,
                                              __hip_bfloat16* __restrict__ Ph,
                                              __hip_bfloat16* __restrict__ Pl) {
  __shared__ __align__(16) short S[3 * 20480];   // 120 KB

  int bh = blockIdx.x;
  int b = bh >> 3;
  int t = threadIdx.x;
  int lane = t & 63, wave = t >> 6;             // wave 0..7
  int ln15 = lane & 15, kh = lane >> 4;

  const short* gMh = (const short*)Mh + (size_t)bh * IDF * CDF;
  const short* gMl = (const short*)Ml + (size_t)bh * IDF * CDF;
  const short* gTh = (const short*)cTh + (size_t)b * LL * CDF;
  const short* gTl = (const short*)cTl + (size_t)b * LL * CDF;

  int offA[4], offB[2];
#pragma unroll
  for (int r = 0; r < 4; ++r) {
    int row = r * 16 + ln15;
    offA[r] = row * 32 + ((kh ^ ((row >> 1) & 3)) * 8);
  }
#pragma unroll
  for (int c = 0; c < 2; ++c) {
    int row = wave * 32 + c * 16 + ln15;
    offB[c] = row * 32 + ((kh ^ ((row >> 1) & 3)) * 8);
  }

  f32x4 acc[4][2] = {};
  k2_stage(&S[0],         gMh, gMl, gTh, gTl, wave, lane, 0);
  k2_stage(&S[20480],     gMh, gMl, gTh, gTl, wave, lane, 32);
  k2_stage(&S[2 * 20480], gMh, gMl, gTh, gTl, wave, lane, 64);
  int cur = 0;

  const int NSTEP = 8;
#pragma unroll 1
  for (int ks = 0; ks < NSTEP; ++ks) {
    short* Sc = &S[cur * 20480];
    WAIT_ENTER3(10, 5)
    short8v fa_h[4], fa_l[4], fb_h[2], fb_l[2];
#pragma unroll
    for (int r = 0; r < 4; ++r) {
      fa_h[r] = *reinterpret_cast<const short8v*>(&Sc[offA[r]]);
      fa_l[r] = *reinterpret_cast<const short8v*>(&Sc[2048 + offA[r]]);
    }
#pragma unroll
    for (int c = 0; c < 2; ++c) {
      fb_h[c] = *reinterpret_cast<const short8v*>(&Sc[4096 + offB[c]]);
      fb_l[c] = *reinterpret_cast<const short8v*>(&Sc[12288 + offB[c]]);
    }
    __builtin_amdgcn_s_setprio(1);
#pragma unroll
    for (int r = 0; r < 4; ++r)
#pragma unroll
      for (int c = 0; c < 2; ++c) {
        acc[r][c] = __builtin_amdgcn_mfma_f32_16x16x32_bf16(fa_h[r], fb_h[c], acc[r][c], 0, 0, 0);
        acc[r][c] = __builtin_amdgcn_mfma_f32_16x16x32_bf16(fa_h[r], fb_l[c], acc[r][c], 0, 0, 0);
        acc[r][c] = __builtin_amdgcn_mfma_f32_16x16x32_bf16(fa_l[r], fb_h[c], acc[r][c], 0, 0, 0);
      }
    __builtin_amdgcn_s_setprio(0);
    BAR_EXIT()
    if (ks + 3 < NSTEP)
      k2_stage(Sc, gMh, gMl, gTh, gTl, wave, lane, (ks + 3) * 32);
    cur = (cur == 2) ? 0 : cur + 1;
  }

  // ---- fused softmax over l (cols). row = r*16+(lane>>4)*4+reg,
  //      col = wave*32 + c*16 + (lane&15). pm[row][w] partials in LDS.
  float* pm = reinterpret_cast<float*>(&S[0]);   // 64*8 floats
  int rowq = (lane >> 4) * 4;
  float gmax[4][4], ginv[4][4];
#pragma unroll
  for (int r = 0; r < 4; ++r)
#pragma unroll
    for (int reg = 0; reg < 4; ++reg) {
      float m = fmaxf(acc[r][0][reg], acc[r][1][reg]);
#pragma unroll
      for (int msk = 8; msk >= 1; msk >>= 1) m = fmaxf(m, __shfl_xor(m, msk, 64));
      if (ln15 == 0) pm[(r * 16 + rowq + reg) * 8 + wave] = m;
    }
  __syncthreads();
#pragma unroll
  for (int r = 0; r < 4; ++r)
#pragma unroll
    for (int reg = 0; reg < 4; ++reg) {
      int row = r * 16 + rowq + reg;
      float4 p0 = *reinterpret_cast<const float4*>(&pm[row * 8]);
      float4 p1 = *reinterpret_cast<const float4*>(&pm[row * 8 + 4]);
      gmax[r][reg] = fmaxf(fmaxf(fmaxf(p0.x, p0.y), fmaxf(p0.z, p0.w)),
                           fmaxf(fmaxf(p1.x, p1.y), fmaxf(p1.z, p1.w)));
    }
  __syncthreads();
#pragma unroll
  for (int r = 0; r < 4; ++r)
#pragma unroll
    for (int reg = 0; reg < 4; ++reg) {
      acc[r][0][reg] = __expf(acc[r][0][reg] - gmax[r][reg]);
      acc[r][1][reg] = __expf(acc[r][1][reg] - gmax[r][reg]);
      float s = acc[r][0][reg] + acc[r][1][reg];
#pragma unroll
      for (int msk = 8; msk >= 1; msk >>= 1) s += __shfl_xor(s, msk, 64);
      if (ln15 == 0) pm[(r * 16 + rowq + reg) * 8 + wave] = s;
    }
  __syncthreads();
#pragma unroll
  for (int r = 0; r < 4; ++r)
#pragma unroll
    for (int reg = 0; reg < 4; ++reg) {
      int row = r * 16 + rowq + reg;
      float4 p0 = *reinterpret_cast<const float4*>(&pm[row * 8]);
      float4 p1 = *reinterpret_cast<const float4*>(&pm[row * 8 + 4]);
      ginv[r][reg] = 1.f / (p0.x + p0.y + p0.z + p0.w + p1.x + p1.y + p1.z + p1.w);
    }
  size_t obase = (size_t)bh * IDF * LL;
#pragma unroll
  for (int r = 0; r < 4; ++r)
#pragma unroll
    for (int c = 0; c < 2; ++c)
#pragma unroll
      for (int reg = 0; reg < 4; ++reg) {
        float p = acc[r][c][reg] * ginv[r][reg];
        __hip_bfloat16 hb, lb;
        split_bf16(p, hb, lb);
        size_t idx = obase + (size_t)(r * 16 + rowq + reg) * LL + wave * 32 + c * 16 + ln15;
        Ph[idx] = hb; Pl[idx] = lb;
      }
}

// ---------------------------------------------------------------------------
// K3 (MFMA, 3-deep): N2[b][i][h*256+c] = sum_l P[i][l]*ctx[c][l].
// grid 512 (bh, ch). 4 waves x (64i x 32c). K=256, BK=32, 8 steps.
// ---------------------------------------------------------------------------
__device__ __forceinline__ void k3_stage(short* dst,
                                         const short* gPh, const short* gPl,
                                         const short* gCh, const short* gCl,
                                         int wave, int lane, int k0) {
#pragma unroll
  for (int j = 0; j < 6; ++j) {
    int inst = wave * 6 + j;
    const short* src; int tile_off, rb;
    if (inst < 4)       { src = gPh; tile_off = 0;    rb = inst * 16; }
    else if (inst < 8)  { src = gPl; tile_off = 2048; rb = (inst - 4) * 16; }
    else if (inst < 16) { src = gCh; tile_off = 4096; rb = (inst - 8) * 16; }
    else                { src = gCl; tile_off = 8192; rb = (inst - 16) * 16; }
    int r  = rb + (lane >> 2);
    int gc = (lane & 3) ^ ((r >> 1) & 3);
    GLDS16(src + (size_t)r * LL + k0 + gc * 8, dst + tile_off + rb * 32);
  }
}

__global__ __launch_bounds__(256) void k_N2(const __hip_bfloat16* __restrict__ Ph,
                                            const __hip_bfloat16* __restrict__ Pl,
                                            const __hip_bfloat16* __restrict__ cNh,
                                            const __hip_bfloat16* __restrict__ cNl,
                                            __hip_bfloat16* __restrict__ N2h,
                                            __hip_bfloat16* __restrict__ N2l) {
  __shared__ __align__(16) short S[3 * 12288];   // 72 KB

  int blk = blockIdx.x;
  int bh = blk >> 1, ch = blk & 1;
  int b = bh >> 3, h = bh & 7;
  int cgbase = ch * 128;
  int t = threadIdx.x;
  int lane = t & 63, wave = t >> 6;
  int ln15 = lane & 15, kh = lane >> 4;

  const short* gPh = (const short*)Ph + (size_t)bh * IDF * LL;
  const short* gPl = (const short*)Pl + (size_t)bh * IDF * LL;
  const short* gCh = (const short*)cNh + (size_t)(b * CDF + cgbase) * LL;
  const short* gCl = (const short*)cNl + (size_t)(b * CDF + cgbase) * LL;

  int offA[4], offB[2];
#pragma unroll
  for (int r = 0; r < 4; ++r) {
    int row = r * 16 + ln15;
    offA[r] = row * 32 + ((kh ^ ((row >> 1) & 3)) * 8);
  }
#pragma unroll
  for (int c = 0; c < 2; ++c) {
    int row = wave * 32 + c * 16 + ln15;
    offB[c] = row * 32 + ((kh ^ ((row >> 1) & 3)) * 8);
  }

  f32x4 acc[4][2] = {};
  k3_stage(&S[0],         gPh, gPl, gCh, gCl, wave, lane, 0);
  k3_stage(&S[12288],     gPh, gPl, gCh, gCl, wave, lane, 32);
  k3_stage(&S[2 * 12288], gPh, gPl, gCh, gCl, wave, lane, 64);
  int cur = 0;

  const int NSTEP = 8;
#pragma unroll 1
  for (int ks = 0; ks < NSTEP; ++ks) {
    short* Sc = &S[cur * 12288];
    WAIT_ENTER3(12, 6)
    short8v fa_h[4], fa_l[4], fb_h[2], fb_l[2];
#pragma unroll
    for (int r = 0; r < 4; ++r) {
      fa_h[r] = *reinterpret_cast<const short8v*>(&Sc[offA[r]]);
      fa_l[r] = *reinterpret_cast<const short8v*>(&Sc[2048 + offA[r]]);
    }
#pragma unroll
    for (int c = 0; c < 2; ++c) {
      fb_h[c] = *reinterpret_cast<const short8v*>(&Sc[4096 + offB[c]]);
      fb_l[c] = *reinterpret_cast<const short8v*>(&Sc[8192 + offB[c]]);
    }
    __builtin_amdgcn_s_setprio(1);
#pragma unroll
    for (int r = 0; r < 4; ++r)
#pragma unroll
      for (int c = 0; c < 2; ++c) {
        acc[r][c] = __builtin_amdgcn_mfma_f32_16x16x32_bf16(fa_h[r], fb_h[c], acc[r][c], 0, 0, 0);
        acc[r][c] = __builtin_amdgcn_mfma_f32_16x16x32_bf16(fa_h[r], fb_l[c], acc[r][c], 0, 0, 0);
        acc[r][c] = __builtin_amdgcn_mfma_f32_16x16x32_bf16(fa_l[r], fb_h[c], acc[r][c], 0, 0, 0);
      }
    __builtin_amdgcn_s_setprio(0);
    BAR_EXIT()
    if (ks + 3 < NSTEP)
      k3_stage(Sc, gPh, gPl, gCh, gCl, wave, lane, (ks + 3) * 32);
    cur = (cur == 2) ? 0 : cur + 1;
  }

  size_t base = (size_t)b * IDF * KHC + h * CDF + cgbase;
  int rowq = (lane >> 4) * 4;
#pragma unroll
  for (int r = 0; r < 4; ++r)
#pragma unroll
    for (int c = 0; c < 2; ++c)
#pragma unroll
      for (int reg = 0; reg < 4; ++reg) {
        __hip_bfloat16 hb, lb;
        split_bf16(acc[r][c][reg], hb, lb);
        size_t idx = base + (size_t)(r * 16 + rowq + reg) * KHC + wave * 32 + c * 16 + ln15;
        N2h[idx] = hb; N2l[idx] = lb;
      }
}

// ---------------------------------------------------------------------------
// K4 (MFMA, 3-deep): ctx_out[b][i][o] = sum_{hc} N2*W.
// grid 512: g(2) x b(32) x ot(8). 4 waves x (64i x 32o). 32 steps.
// ---------------------------------------------------------------------------
__device__ __forceinline__ void k4_stage(short* dst,
                                         const short* gA_h, const short* gA_l,
                                         const short* gB_h, const short* gB_l,
                                         int wave, int lane, int kk0, int obase) {
  int h4 = kk0 >> 8, cb = kk0 & 255;
#pragma unroll
  for (int j = 0; j < 6; ++j) {
    int inst = wave * 6 + j;
    if (inst < 8) {
      const short* src = (inst < 4) ? gA_h : gA_l;
      int tile_off = (inst < 4) ? 0 : 2048;
      int rb = (inst & 3) * 16;
      int r  = rb + (lane >> 2);
      int gc = (lane & 3) ^ ((r >> 1) & 3);
      GLDS16(src + (size_t)r * KHC + kk0 + gc * 8, dst + tile_off + rb * 32);
    } else {
      int t2 = inst - 8;
      const short* src = (t2 < 8) ? gB_h : gB_l;
      int tile_off = (t2 < 8) ? 4096 : 8192;
      int rb = (t2 & 7) * 16;
      int r  = rb + (lane >> 2);
      int gc = (lane & 3) ^ ((r >> 1) & 3);
      GLDS16(src + (size_t)(h4 * SSZ + obase + r) * CDF + cb + gc * 8, dst + tile_off + rb * 32);
    }
  }
}

__global__ __launch_bounds__(256) void k4_mfma(const __hip_bfloat16* __restrict__ N2h,
                                               const __hip_bfloat16* __restrict__ N2l,
                                               const __hip_bfloat16* __restrict__ Wh,
                                               const __hip_bfloat16* __restrict__ Wl,
                                               float* __restrict__ out0,
                                               float* __restrict__ out1) {
  __shared__ __align__(16) short S[3 * 12288];   // 72 KB

  int blk = blockIdx.x;
  int g = blk >> 8;
  int r8 = blk & 255;
  int b = r8 >> 3, ot = r8 & 7;
  int obase = ot * 128;
  int t = threadIdx.x;
  int lane = t & 63, wave = t >> 6;
  int ln15 = lane & 15, kh = lane >> 4;

  const short* gA_h = (const short*)N2h + (size_t)b * IDF * KHC;
  const short* gA_l = (const short*)N2l + (size_t)b * IDF * KHC;
  const short* gB_h = (const short*)Wh;
  const short* gB_l = (const short*)Wl;

  int offA[4], offB[2];
#pragma unroll
  for (int r = 0; r < 4; ++r) {
    int row = r * 16 + ln15;
    offA[r] = row * 32 + ((kh ^ ((row >> 1) & 3)) * 8);
  }
#pragma unroll
  for (int c = 0; c < 2; ++c) {
    int row = wave * 32 + c * 16 + ln15;
    offB[c] = row * 32 + ((kh ^ ((row >> 1) & 3)) * 8);
  }

  int kbase = g * (KHC / 2);
  f32x4 acc[4][2] = {};

  k4_stage(&S[0],         gA_h, gA_l, gB_h, gB_l, wave, lane, kbase, obase);
  k4_stage(&S[12288],     gA_h, gA_l, gB_h, gB_l, wave, lane, kbase + 32, obase);
  k4_stage(&S[2 * 12288], gA_h, gA_l, gB_h, gB_l, wave, lane, kbase + 64, obase);
  int cur = 0;

  const int NSTEP = 32;
#pragma unroll 1
  for (int ks = 0; ks < NSTEP; ++ks) {
    short* Sc = &S[cur * 12288];
    WAIT_ENTER3(12, 6)
    short8v fa_h[4], fa_l[4], fb_h[2], fb_l[2];
#pragma unroll
    for (int r = 0; r < 4; ++r) {
      fa_h[r] = *reinterpret_cast<const short8v*>(&Sc[offA[r]]);
      fa_l[r] = *reinterpret_cast<const short8v*>(&Sc[2048 + offA[r]]);
    }
#pragma unroll
    for (int c = 0; c < 2; ++c) {
      fb_h[c] = *reinterpret_cast<const short8v*>(&Sc[4096 + offB[c]]);
      fb_l[c] = *reinterpret_cast<const short8v*>(&Sc[8192 + offB[c]]);
    }
    __builtin_amdgcn_s_setprio(1);
#pragma unroll
    for (int r = 0; r < 4; ++r)
#pragma unroll
      for (int c = 0; c < 2; ++c) {
        acc[r][c] = __builtin_amdgcn_mfma_f32_16x16x32_bf16(fa_h[r], fb_h[c], acc[r][c], 0, 0, 0);
        acc[r][c] = __builtin_amdgcn_mfma_f32_16x16x32_bf16(fa_h[r], fb_l[c], acc[r][c], 0, 0, 0);
        acc[r][c] = __builtin_amdgcn_mfma_f32_16x16x32_bf16(fa_l[r], fb_h[c], acc[r][c], 0, 0, 0);
      }
    __builtin_amdgcn_s_setprio(0);
    BAR_EXIT()
    if (ks + 3 < NSTEP)
      k4_stage(Sc, gA_h, gA_l, gB_h, gB_l, wave, lane,
               kbase + (ks + 3) * 32, obase);
    cur = (cur == 2) ? 0 : cur + 1;
  }

  float* dst = (g == 0) ? out0 : out1;
  int rowq = (lane >> 4) * 4;
#pragma unroll
  for (int r = 0; r < 4; ++r)
#pragma unroll
    for (int c = 0; c < 2; ++c)
#pragma unroll
      for (int reg = 0; reg < 4; ++reg)
        dst[((size_t)b * IDF + r * 16 + rowq + reg) * SSZ +
            obase + wave * 32 + c * 16 + ln15] = acc[r][c][reg];
}

// out += P
__global__ __launch_bounds__(256) void k_add(float* __restrict__ out,
                                             const float* __restrict__ P) {
  int idx = blockIdx.x * 256 + threadIdx.x;
  float4 a = reinterpret_cast<float4*>(out)[idx];
  float4 p = reinterpret_cast<const float4*>(P)[idx];
  a.x += p.x; a.y += p.y; a.z += p.z; a.w += p.w;
  reinterpret_cast<float4*>(out)[idx] = a;
}

// ---------------------------------------------------------------------------
// K5: attn_out[b][l][i] = sum_h (Ph+Pl)[bh][i][l]  (bf16 pair input)
// ---------------------------------------------------------------------------
__global__ __launch_bounds__(256) void k_attnout(const __hip_bfloat16* __restrict__ Ph,
                                                 const __hip_bfloat16* __restrict__ Pl,
                                                 float* __restrict__ outa) {
  __shared__ float T[64][65];
  int blk = blockIdx.x; int b = blk >> 2, lt = blk & 3;
  int l0 = lt * 64;
  int tid = threadIdx.x;
  const unsigned short* ph = (const unsigned short*)Ph;
  const unsigned short* pl = (const unsigned short*)Pl;
  float4 acc[4];
#pragma unroll
  for (int p = 0; p < 4; ++p) acc[p] = make_float4(0.f, 0.f, 0.f, 0.f);
  for (int h = 0; h < NH; ++h) {
    size_t src = (size_t)(b * NH + h) * IDF * LL;
#pragma unroll
    for (int p = 0; p < 4; ++p) {
      int f = tid + p * 256;
      int i = f >> 4, lc = (f & 15) * 4;
      ushort4 uh = *reinterpret_cast<const ushort4*>(&ph[src + i * LL + l0 + lc]);
      ushort4 ul = *reinterpret_cast<const ushort4*>(&pl[src + i * LL + l0 + lc]);
      acc[p].x += bf2f(uh.x) + bf2f(ul.x); acc[p].y += bf2f(uh.y) + bf2f(ul.y);
      acc[p].z += bf2f(uh.z) + bf2f(ul.z); acc[p].w += bf2f(uh.w) + bf2f(ul.w);
    }
  }
#pragma unroll
  for (int p = 0; p < 4; ++p) {
    int f = tid + p * 256;
    int i = f >> 4, lc = (f & 15) * 4;
    T[i][lc + 0] = acc[p].x; T[i][lc + 1] = acc[p].y;
    T[i][lc + 2] = acc[p].z; T[i][lc + 3] = acc[p].w;
  }
  __syncthreads();
#pragma unroll
  for (int p = 0; p < 4; ++p) {
    int f = tid + p * 256;
    int lr = f >> 4, ic = (f & 15) * 4;
    float4 v = {T[ic + 0][lr], T[ic + 1][lr], T[ic + 2][lr], T[ic + 3][lr]};
    *reinterpret_cast<float4*>(&outa[((size_t)b * LL + l0 + lr) * IDF + ic]) = v;
  }
}

// ---------------------------------------------------------------------------
extern "C" void kernel_launch(void* const* d_in, const int* in_sizes, int n_in,
                              void* d_out, int out_size, void* d_ws, size_t ws_size,
                              hipStream_t stream) {
  const float* wc  = (const float*)d_in[0];   // [32][64][1024]
  const float* ctx = (const float*)d_in[1];   // [32][256][256]
  const float* W   = (const float*)d_in[2];   // [8][1024][256]
  float* out = (float*)d_out;

  const size_t NE = 2097152;   // elems of wc == W == ctx
  const size_t NM = 4194304;   // elems of M == P == N2
  __hip_bfloat16* p = (__hip_bfloat16*)d_ws;
  __hip_bfloat16 *wch = p, *wcl = wch + NE, *wth = wcl + NE, *wtl = wth + NE;
  p = wtl + NE;
  __hip_bfloat16 *Mh = p, *Ml = Mh + NM;            p = Ml + NM;
  __hip_bfloat16 *cTh = p, *cTl = cTh + NE;         p = cTl + NE;
  __hip_bfloat16 *cNh = p, *cNl = cNh + NE;         p = cNl + NE;
  __hip_bfloat16 *Ph = p, *Pl = Ph + NM;            p = Pl + NM;
  __hip_bfloat16 *N2h = p, *N2l = N2h + NM;         p = N2l + NM;
  __hip_bfloat16 *Wh = p, *Wl = Wh + NE;            p = Wl + NE;
  float* Pbuf = (float*)p;                          // 2.1M floats

  k_split      <<<2048, 256, 0, stream>>>(wc, wch, wcl);
  k_split_Wt   <<<512, 256, 0, stream>>>(W, wth, wtl);
  k_split      <<<2048, 256, 0, stream>>>(W, Wh, Wl);
  k_split      <<<2048, 256, 0, stream>>>(ctx, cNh, cNl);
  k_split_ctxT <<<512, 256, 0, stream>>>(ctx, cTh, cTl);
  k1_mfma      <<<BB * NH * 2, 256, 0, stream>>>(wch, wcl, wth, wtl, Mh, Ml);
  k_attn       <<<BB * NH, 512, 0, stream>>>(Mh, Ml, cTh, cTl, Ph, Pl);
  k_N2         <<<BB * NH * 2, 256, 0, stream>>>(Ph, Pl, cNh, cNl, N2h, N2l);
  k_attnout    <<<BB * 4, 256, 0, stream>>>(Ph, Pl, out + (size_t)BB * IDF * SSZ);
  k4_mfma      <<<512, 256, 0, stream>>>(N2h, N2l, Wh, Wl, out, Pbuf);
  k_add        <<<2048, 256, 0, stream>>>(out, Pbuf);
}

// Round 14
// 121.214 us; speedup vs baseline: 3.1495x; 1.2477x over previous
//
#include <hip/hip_runtime.h>
#include <hip/hip_bf16.h>

#define BB 32
#define IDF 64
#define CDF 256
#define SSZ 1024
#define NH 8
#define LL 256
#define KHC 2048   // NH*CDF

typedef __attribute__((ext_vector_type(8))) short short8v;     // 8 bf16
typedef __attribute__((ext_vector_type(8))) _Float16 half8v;   // 8 fp16
typedef __attribute__((ext_vector_type(4))) float f32x4;       // MFMA acc

// async global->LDS, 16B per lane, LDS dest = wave-uniform base + lane*16
#define GLDS16(g, l) __builtin_amdgcn_global_load_lds(                        \
    (const __attribute__((address_space(1))) void*)(g),                       \
    (__attribute__((address_space(3))) void*)(l), 16, 0, 0)

// 3-deep pipeline phase entry (T3+T4): wait only for the CURRENT buffer's
// DMA, leaving the next TWO stages in flight. Never vmcnt(0) mid-loop.
#define WAIT_ENTER3(NFULL, NHALF)                                             \
  { if (ks < NSTEP - 2)                                                       \
      asm volatile("s_waitcnt vmcnt(" #NFULL ")" ::: "memory");               \
    else if (ks == NSTEP - 2)                                                 \
      asm volatile("s_waitcnt vmcnt(" #NHALF ")" ::: "memory");               \
    else                                                                      \
      asm volatile("s_waitcnt vmcnt(0)" ::: "memory");                        \
    __builtin_amdgcn_s_barrier();                                             \
    __builtin_amdgcn_sched_barrier(0); }
#define BAR_EXIT()                                                            \
  { __builtin_amdgcn_sched_barrier(0);                                        \
    __builtin_amdgcn_s_barrier();                                             \
    __builtin_amdgcn_sched_barrier(0); }

__device__ inline void split_bf16(float x, __hip_bfloat16& h, __hip_bfloat16& l) {
  h = __float2bfloat16(x);
  l = __float2bfloat16(x - __bfloat162float(h));
}
__device__ inline unsigned short f2h(float x) {
  _Float16 h = (_Float16)x;
  return *reinterpret_cast<unsigned short*>(&h);
}
__device__ inline float h2f(unsigned short u) {
  _Float16 h = *reinterpret_cast<_Float16*>(&u);
  return (float)h;
}

// ---------------------------------------------------------------------------
// Elementwise bf16 hi/lo split (2.097M elems): wc.
// ---------------------------------------------------------------------------
__global__ __launch_bounds__(256) void k_split(const float* __restrict__ src,
                                               __hip_bfloat16* __restrict__ dh,
                                               __hip_bfloat16* __restrict__ dl) {
  int idx = (blockIdx.x * 256 + threadIdx.x) * 4;
  float4 v = *reinterpret_cast<const float4*>(&src[idx]);
  __align__(16) __hip_bfloat16 hb[4], lb[4];
  split_bf16(v.x, hb[0], lb[0]); split_bf16(v.y, hb[1], lb[1]);
  split_bf16(v.z, hb[2], lb[2]); split_bf16(v.w, hb[3], lb[3]);
  *reinterpret_cast<int2*>(&dh[idx]) = *reinterpret_cast<int2*>(hb);
  *reinterpret_cast<int2*>(&dl[idx]) = *reinterpret_cast<int2*>(lb);
}

// ---------------------------------------------------------------------------
// Elementwise fp16 single cast (2.097M elems): W16, ctx16 (for K3/K4).
// ---------------------------------------------------------------------------
__global__ __launch_bounds__(256) void k_split_f16(const float* __restrict__ src,
                                                   unsigned short* __restrict__ d) {
  int idx = (blockIdx.x * 256 + threadIdx.x) * 4;
  float4 v = *reinterpret_cast<const float4*>(&src[idx]);
  __align__(8) unsigned short h[4] = {f2h(v.x), f2h(v.y), f2h(v.z), f2h(v.w)};
  *reinterpret_cast<int2*>(&d[idx]) = *reinterpret_cast<int2*>(h);
}

// ---------------------------------------------------------------------------
// Split+transpose W[h][o][c] -> Wt hi/lo [h][c][o] (bf16). For K1.
// ---------------------------------------------------------------------------
__global__ __launch_bounds__(256) void k_split_Wt(const float* __restrict__ W,
                                                  __hip_bfloat16* __restrict__ wth,
                                                  __hip_bfloat16* __restrict__ wtl) {
  __shared__ float Tt[64][65];   // [c][o]
  int blk = blockIdx.x;
  int h = blk >> 6, ot = (blk >> 2) & 15, ct = blk & 3;
  int og = ot * 64, cg = ct * 64;
  int t = threadIdx.x;
  int o_l = t >> 4, c4 = (t & 15) * 4;
#pragma unroll
  for (int p = 0; p < 4; ++p) {
    int o = o_l + 16 * p;
    float4 v = *reinterpret_cast<const float4*>(
        &W[((size_t)h * SSZ + og + o) * CDF + cg + c4]);
    Tt[c4 + 0][o] = v.x; Tt[c4 + 1][o] = v.y;
    Tt[c4 + 2][o] = v.z; Tt[c4 + 3][o] = v.w;
  }
  __syncthreads();
  int c_l = t >> 2;
#pragma unroll
  for (int p = 0; p < 4; ++p) {
    int o0 = ((t & 3) + 4 * p) * 4;
    __hip_bfloat16 hv[4], lv[4];
#pragma unroll
    for (int j = 0; j < 4; ++j) split_bf16(Tt[c_l][o0 + j], hv[j], lv[j]);
    size_t base = ((size_t)h * CDF + cg + c_l) * SSZ + og + o0;
#pragma unroll
    for (int j = 0; j < 4; ++j) { wth[base + j] = hv[j]; wtl[base + j] = lv[j]; }
  }
}

// ---------------------------------------------------------------------------
// Split+transpose ctx[b][c][l] -> ctxT hi/lo [b][l][c] (bf16). For K2.
// ---------------------------------------------------------------------------
__global__ __launch_bounds__(256) void k_split_ctxT(const float* __restrict__ ctx,
                                                    __hip_bfloat16* __restrict__ Th,
                                                    __hip_bfloat16* __restrict__ Tl) {
  __shared__ float Tt[64][65];   // [l][c]
  int blk = blockIdx.x;
  int b = blk >> 4, ct = (blk >> 2) & 3, lt = blk & 3;
  int cg = ct * 64, lg = lt * 64;
  int t = threadIdx.x;
  int c_l = t >> 4, l4 = (t & 15) * 4;
#pragma unroll
  for (int p = 0; p < 4; ++p) {
    int c = c_l + 16 * p;
    float4 v = *reinterpret_cast<const float4*>(
        &ctx[((size_t)b * CDF + cg + c) * LL + lg + l4]);
    Tt[l4 + 0][c] = v.x; Tt[l4 + 1][c] = v.y;
    Tt[l4 + 2][c] = v.z; Tt[l4 + 3][c] = v.w;
  }
  __syncthreads();
  int l_l = t >> 2;
#pragma unroll
  for (int p = 0; p < 4; ++p) {
    int c0 = ((t & 3) + 4 * p) * 4;
    __hip_bfloat16 hv[4], lv[4];
#pragma unroll
    for (int j = 0; j < 4; ++j) split_bf16(Tt[l_l][c0 + j], hv[j], lv[j]);
    size_t base = ((size_t)b * LL + lg + l_l) * CDF + cg + c0;
#pragma unroll
    for (int j = 0; j < 4; ++j) { Th[base + j] = hv[j]; Tl[base + j] = lv[j]; }
  }
}

// ---------------------------------------------------------------------------
// K1 (MFMA bf16 3-term, 3-deep): M = wc*W^T -> Mh/Ml split. UNCHANGED.
// grid 512: (bh, nh-half of 128c). 4 waves x (64i x 32c). BK=32, 32 steps.
// ---------------------------------------------------------------------------
__device__ __forceinline__ void k1_stage(short* dst,
                                         const short* gA_h, const short* gA_l,
                                         const short* gB_h, const short* gB_l,
                                         int wave, int lane, int k0) {
#pragma unroll
  for (int j = 0; j < 6; ++j) {
    int inst = wave * 6 + j;
    const short* src; int tile_off, rb;
    if (inst < 4)       { src = gA_h; tile_off = 0;    rb = inst * 16; }
    else if (inst < 8)  { src = gA_l; tile_off = 2048; rb = (inst - 4) * 16; }
    else if (inst < 16) { src = gB_h; tile_off = 4096; rb = (inst - 8) * 16; }
    else                { src = gB_l; tile_off = 8192; rb = (inst - 16) * 16; }
    int r  = rb + (lane >> 2);
    int gc = (lane & 3) ^ ((r >> 1) & 3);
    GLDS16(src + (size_t)r * SSZ + k0 + gc * 8, dst + tile_off + rb * 32);
  }
}

__global__ __launch_bounds__(256) void k1_mfma(const __hip_bfloat16* __restrict__ wch,
                                               const __hip_bfloat16* __restrict__ wcl,
                                               const __hip_bfloat16* __restrict__ wth,
                                               const __hip_bfloat16* __restrict__ wtl,
                                               __hip_bfloat16* __restrict__ Mh,
                                               __hip_bfloat16* __restrict__ Ml) {
  __shared__ __align__(16) short S[3 * 12288];   // 72 KB

  int blk = blockIdx.x;
  int bh = blk >> 1, nh = blk & 1;
  int b = bh >> 3, h = bh & 7;
  int t = threadIdx.x;
  int lane = t & 63, wave = t >> 6;
  int ln15 = lane & 15, kh = lane >> 4;

  const short* gA_h = (const short*)wch + (size_t)b * IDF * SSZ;
  const short* gA_l = (const short*)wcl + (size_t)b * IDF * SSZ;
  const short* gB_h = (const short*)wth + (size_t)(h * CDF + nh * 128) * SSZ;
  const short* gB_l = (const short*)wtl + (size_t)(h * CDF + nh * 128) * SSZ;

  int offA[4], offB[2];
#pragma unroll
  for (int r = 0; r < 4; ++r) {
    int row = r * 16 + ln15;
    offA[r] = row * 32 + ((kh ^ ((row >> 1) & 3)) * 8);
  }
#pragma unroll
  for (int c = 0; c < 2; ++c) {
    int row = wave * 32 + c * 16 + ln15;
    offB[c] = row * 32 + ((kh ^ ((row >> 1) & 3)) * 8);
  }

  f32x4 acc[4][2] = {};
  k1_stage(&S[0],         gA_h, gA_l, gB_h, gB_l, wave, lane, 0);
  k1_stage(&S[12288],     gA_h, gA_l, gB_h, gB_l, wave, lane, 32);
  k1_stage(&S[2 * 12288], gA_h, gA_l, gB_h, gB_l, wave, lane, 64);
  int cur = 0;

  const int NSTEP = 32;
#pragma unroll 1
  for (int ks = 0; ks < NSTEP; ++ks) {
    short* Sc = &S[cur * 12288];
    WAIT_ENTER3(12, 6)
    short8v fa_h[4], fa_l[4], fb_h[2], fb_l[2];
#pragma unroll
    for (int r = 0; r < 4; ++r) {
      fa_h[r] = *reinterpret_cast<const short8v*>(&Sc[offA[r]]);
      fa_l[r] = *reinterpret_cast<const short8v*>(&Sc[2048 + offA[r]]);
    }
#pragma unroll
    for (int c = 0; c < 2; ++c) {
      fb_h[c] = *reinterpret_cast<const short8v*>(&Sc[4096 + offB[c]]);
      fb_l[c] = *reinterpret_cast<const short8v*>(&Sc[8192 + offB[c]]);
    }
    __builtin_amdgcn_s_setprio(1);
#pragma unroll
    for (int r = 0; r < 4; ++r)
#pragma unroll
      for (int c = 0; c < 2; ++c) {
        acc[r][c] = __builtin_amdgcn_mfma_f32_16x16x32_bf16(fa_h[r], fb_h[c], acc[r][c], 0, 0, 0);
        acc[r][c] = __builtin_amdgcn_mfma_f32_16x16x32_bf16(fa_h[r], fb_l[c], acc[r][c], 0, 0, 0);
        acc[r][c] = __builtin_amdgcn_mfma_f32_16x16x32_bf16(fa_l[r], fb_h[c], acc[r][c], 0, 0, 0);
      }
    __builtin_amdgcn_s_setprio(0);
    BAR_EXIT()
    if (ks + 3 < NSTEP)
      k1_stage(Sc, gA_h, gA_l, gB_h, gB_l, wave, lane, (ks + 3) * 32);
    cur = (cur == 2) ? 0 : cur + 1;
  }

  size_t obase = (size_t)bh * IDF * CDF + nh * 128;
  int rowq = (lane >> 4) * 4;
#pragma unroll
  for (int r = 0; r < 4; ++r)
#pragma unroll
    for (int c = 0; c < 2; ++c)
#pragma unroll
      for (int reg = 0; reg < 4; ++reg) {
        __hip_bfloat16 hb, lb;
        split_bf16(acc[r][c][reg], hb, lb);
        size_t idx = obase + (size_t)(r * 16 + rowq + reg) * CDF + wave * 32 + c * 16 + ln15;
        Mh[idx] = hb; Ml[idx] = lb;
      }
}

// ---------------------------------------------------------------------------
// K2 (MFMA bf16 3-term + fused softmax, 3-deep): P = softmax_l(M*ctxT^T).
// Epilogue now writes P as SINGLE fp16 (2^-11 rounding on probs: harmless).
// ---------------------------------------------------------------------------
__device__ __forceinline__ void k2_stage(short* dst,
                                         const short* gMh, const short* gMl,
                                         const short* gTh, const short* gTl,
                                         int wave, int lane, int k0) {
#pragma unroll
  for (int j = 0; j < 5; ++j) {
    int inst = wave * 5 + j;               // 0..39
    const short* src; int tile_off, rb;
    if (inst < 4)       { src = gMh; tile_off = 0;     rb = inst * 16; }
    else if (inst < 8)  { src = gMl; tile_off = 2048;  rb = (inst - 4) * 16; }
    else if (inst < 24) { src = gTh; tile_off = 4096;  rb = (inst - 8) * 16; }
    else                { src = gTl; tile_off = 12288; rb = (inst - 24) * 16; }
    int r  = rb + (lane >> 2);
    int gc = (lane & 3) ^ ((r >> 1) & 3);
    GLDS16(src + (size_t)r * CDF + k0 + gc * 8, dst + tile_off + rb * 32);
  }
}

__global__ __launch_bounds__(512) void k_attn(const __hip_bfloat16* __restrict__ Mh,
                                              const __hip_bfloat16* __restrict__ Ml,
                                              const __hip_bfloat16* __restrict__ cTh,
                                              const __hip_bfloat16* __restrict__ cTl,
                                              unsigned short* __restrict__ P16) {
  __shared__ __align__(16) short S[3 * 20480];   // 120 KB

  int bh = blockIdx.x;
  int b = bh >> 3;
  int t = threadIdx.x;
  int lane = t & 63, wave = t >> 6;             // wave 0..7
  int ln15 = lane & 15, kh = lane >> 4;

  const short* gMh = (const short*)Mh + (size_t)bh * IDF * CDF;
  const short* gMl = (const short*)Ml + (size_t)bh * IDF * CDF;
  const short* gTh = (const short*)cTh + (size_t)b * LL * CDF;
  const short* gTl = (const short*)cTl + (size_t)b * LL * CDF;

  int offA[4], offB[2];
#pragma unroll
  for (int r = 0; r < 4; ++r) {
    int row = r * 16 + ln15;
    offA[r] = row * 32 + ((kh ^ ((row >> 1) & 3)) * 8);
  }
#pragma unroll
  for (int c = 0; c < 2; ++c) {
    int row = wave * 32 + c * 16 + ln15;
    offB[c] = row * 32 + ((kh ^ ((row >> 1) & 3)) * 8);
  }

  f32x4 acc[4][2] = {};
  k2_stage(&S[0],         gMh, gMl, gTh, gTl, wave, lane, 0);
  k2_stage(&S[20480],     gMh, gMl, gTh, gTl, wave, lane, 32);
  k2_stage(&S[2 * 20480], gMh, gMl, gTh, gTl, wave, lane, 64);
  int cur = 0;

  const int NSTEP = 8;
#pragma unroll 1
  for (int ks = 0; ks < NSTEP; ++ks) {
    short* Sc = &S[cur * 20480];
    WAIT_ENTER3(10, 5)
    short8v fa_h[4], fa_l[4], fb_h[2], fb_l[2];
#pragma unroll
    for (int r = 0; r < 4; ++r) {
      fa_h[r] = *reinterpret_cast<const short8v*>(&Sc[offA[r]]);
      fa_l[r] = *reinterpret_cast<const short8v*>(&Sc[2048 + offA[r]]);
    }
#pragma unroll
    for (int c = 0; c < 2; ++c) {
      fb_h[c] = *reinterpret_cast<const short8v*>(&Sc[4096 + offB[c]]);
      fb_l[c] = *reinterpret_cast<const short8v*>(&Sc[12288 + offB[c]]);
    }
    __builtin_amdgcn_s_setprio(1);
#pragma unroll
    for (int r = 0; r < 4; ++r)
#pragma unroll
      for (int c = 0; c < 2; ++c) {
        acc[r][c] = __builtin_amdgcn_mfma_f32_16x16x32_bf16(fa_h[r], fb_h[c], acc[r][c], 0, 0, 0);
        acc[r][c] = __builtin_amdgcn_mfma_f32_16x16x32_bf16(fa_h[r], fb_l[c], acc[r][c], 0, 0, 0);
        acc[r][c] = __builtin_amdgcn_mfma_f32_16x16x32_bf16(fa_l[r], fb_h[c], acc[r][c], 0, 0, 0);
      }
    __builtin_amdgcn_s_setprio(0);
    BAR_EXIT()
    if (ks + 3 < NSTEP)
      k2_stage(Sc, gMh, gMl, gTh, gTl, wave, lane, (ks + 3) * 32);
    cur = (cur == 2) ? 0 : cur + 1;
  }

  // ---- fused softmax over l (cols). row = r*16+(lane>>4)*4+reg,
  //      col = wave*32 + c*16 + (lane&15). pm[row][w] partials in LDS.
  float* pm = reinterpret_cast<float*>(&S[0]);   // 64*8 floats
  int rowq = (lane >> 4) * 4;
  float gmax[4][4], ginv[4][4];
#pragma unroll
  for (int r = 0; r < 4; ++r)
#pragma unroll
    for (int reg = 0; reg < 4; ++reg) {
      float m = fmaxf(acc[r][0][reg], acc[r][1][reg]);
#pragma unroll
      for (int msk = 8; msk >= 1; msk >>= 1) m = fmaxf(m, __shfl_xor(m, msk, 64));
      if (ln15 == 0) pm[(r * 16 + rowq + reg) * 8 + wave] = m;
    }
  __syncthreads();
#pragma unroll
  for (int r = 0; r < 4; ++r)
#pragma unroll
    for (int reg = 0; reg < 4; ++reg) {
      int row = r * 16 + rowq + reg;
      float4 p0 = *reinterpret_cast<const float4*>(&pm[row * 8]);
      float4 p1 = *reinterpret_cast<const float4*>(&pm[row * 8 + 4]);
      gmax[r][reg] = fmaxf(fmaxf(fmaxf(p0.x, p0.y), fmaxf(p0.z, p0.w)),
                           fmaxf(fmaxf(p1.x, p1.y), fmaxf(p1.z, p1.w)));
    }
  __syncthreads();
#pragma unroll
  for (int r = 0; r < 4; ++r)
#pragma unroll
    for (int reg = 0; reg < 4; ++reg) {
      acc[r][0][reg] = __expf(acc[r][0][reg] - gmax[r][reg]);
      acc[r][1][reg] = __expf(acc[r][1][reg] - gmax[r][reg]);
      float s = acc[r][0][reg] + acc[r][1][reg];
#pragma unroll
      for (int msk = 8; msk >= 1; msk >>= 1) s += __shfl_xor(s, msk, 64);
      if (ln15 == 0) pm[(r * 16 + rowq + reg) * 8 + wave] = s;
    }
  __syncthreads();
#pragma unroll
  for (int r = 0; r < 4; ++r)
#pragma unroll
    for (int reg = 0; reg < 4; ++reg) {
      int row = r * 16 + rowq + reg;
      float4 p0 = *reinterpret_cast<const float4*>(&pm[row * 8]);
      float4 p1 = *reinterpret_cast<const float4*>(&pm[row * 8 + 4]);
      ginv[r][reg] = 1.f / (p0.x + p0.y + p0.z + p0.w + p1.x + p1.y + p1.z + p1.w);
    }
  size_t obase = (size_t)bh * IDF * LL;
#pragma unroll
  for (int r = 0; r < 4; ++r)
#pragma unroll
    for (int c = 0; c < 2; ++c)
#pragma unroll
      for (int reg = 0; reg < 4; ++reg) {
        float p = acc[r][c][reg] * ginv[r][reg];
        size_t idx = obase + (size_t)(r * 16 + rowq + reg) * LL + wave * 32 + c * 16 + ln15;
        P16[idx] = f2h(p);
      }
}

// ---------------------------------------------------------------------------
// K3 (MFMA fp16 SINGLE-TERM, 3-deep): N2[b][i][h*256+c] = sum_l P*ctx.
// grid 512 (bh, ch). 4 waves x (64i x 32c). K=256, BK=32, 8 steps.
// 3 GLDS16 / wave / stage; buffers 12 KB each (A 64 rows + B 128 rows).
// ---------------------------------------------------------------------------
__device__ __forceinline__ void k3_stage(short* dst,
                                         const short* gP, const short* gC,
                                         int wave, int lane, int k0) {
#pragma unroll
  for (int j = 0; j < 3; ++j) {
    int inst = wave * 3 + j;               // 0..11
    const short* src; int tile_off, rb;
    if (inst < 4) { src = gP; tile_off = 0;    rb = inst * 16; }
    else          { src = gC; tile_off = 2048; rb = (inst - 4) * 16; }
    int r  = rb + (lane >> 2);
    int gc = (lane & 3) ^ ((r >> 1) & 3);
    GLDS16(src + (size_t)r * LL + k0 + gc * 8, dst + tile_off + rb * 32);
  }
}

__global__ __launch_bounds__(256) void k_N2(const unsigned short* __restrict__ P16,
                                            const unsigned short* __restrict__ ctx16,
                                            unsigned short* __restrict__ N216) {
  __shared__ __align__(16) short S[3 * 6144];   // 36 KB

  int blk = blockIdx.x;
  int bh = blk >> 1, ch = blk & 1;
  int b = bh >> 3, h = bh & 7;
  int cgbase = ch * 128;
  int t = threadIdx.x;
  int lane = t & 63, wave = t >> 6;
  int ln15 = lane & 15, kh = lane >> 4;

  const short* gP = (const short*)P16 + (size_t)bh * IDF * LL;
  const short* gC = (const short*)ctx16 + (size_t)(b * CDF + cgbase) * LL;

  int offA[4], offB[2];
#pragma unroll
  for (int r = 0; r < 4; ++r) {
    int row = r * 16 + ln15;
    offA[r] = row * 32 + ((kh ^ ((row >> 1) & 3)) * 8);
  }
#pragma unroll
  for (int c = 0; c < 2; ++c) {
    int row = wave * 32 + c * 16 + ln15;
    offB[c] = 2048 + row * 32 + ((kh ^ ((row >> 1) & 3)) * 8);
  }

  f32x4 acc[4][2] = {};
  k3_stage(&S[0],        gP, gC, wave, lane, 0);
  k3_stage(&S[6144],     gP, gC, wave, lane, 32);
  k3_stage(&S[2 * 6144], gP, gC, wave, lane, 64);
  int cur = 0;

  const int NSTEP = 8;
#pragma unroll 1
  for (int ks = 0; ks < NSTEP; ++ks) {
    short* Sc = &S[cur * 6144];
    WAIT_ENTER3(6, 3)
    half8v fa[4], fb[2];
#pragma unroll
    for (int r = 0; r < 4; ++r)
      fa[r] = *reinterpret_cast<const half8v*>(&Sc[offA[r]]);
#pragma unroll
    for (int c = 0; c < 2; ++c)
      fb[c] = *reinterpret_cast<const half8v*>(&Sc[offB[c]]);
    __builtin_amdgcn_s_setprio(1);
#pragma unroll
    for (int r = 0; r < 4; ++r)
#pragma unroll
      for (int c = 0; c < 2; ++c)
        acc[r][c] = __builtin_amdgcn_mfma_f32_16x16x32_f16(fa[r], fb[c], acc[r][c], 0, 0, 0);
    __builtin_amdgcn_s_setprio(0);
    BAR_EXIT()
    if (ks + 3 < NSTEP)
      k3_stage(Sc, gP, gC, wave, lane, (ks + 3) * 32);
    cur = (cur == 2) ? 0 : cur + 1;
  }

  size_t base = (size_t)b * IDF * KHC + h * CDF + cgbase;
  int rowq = (lane >> 4) * 4;
#pragma unroll
  for (int r = 0; r < 4; ++r)
#pragma unroll
    for (int c = 0; c < 2; ++c)
#pragma unroll
      for (int reg = 0; reg < 4; ++reg) {
        size_t idx = base + (size_t)(r * 16 + rowq + reg) * KHC + wave * 32 + c * 16 + ln15;
        N216[idx] = f2h(acc[r][c][reg]);
      }
}

// ---------------------------------------------------------------------------
// K4 (MFMA fp16 SINGLE-TERM, 3-deep): ctx_out[b][i][o] = sum_{hc} N2*W.
// grid 512: g(2) x b(32) x ot(8). 4 waves x (64i x 32o). 32 steps.
// ---------------------------------------------------------------------------
__device__ __forceinline__ void k4_stage(short* dst,
                                         const short* gA, const short* gB,
                                         int wave, int lane, int kk0, int obase) {
  int h4 = kk0 >> 8, cb = kk0 & 255;
#pragma unroll
  for (int j = 0; j < 3; ++j) {
    int inst = wave * 3 + j;               // 0..11
    if (inst < 4) {
      int rb = inst * 16;
      int r  = rb + (lane >> 2);
      int gc = (lane & 3) ^ ((r >> 1) & 3);
      GLDS16(gA + (size_t)r * KHC + kk0 + gc * 8, dst + rb * 32);
    } else {
      int rb = (inst - 4) * 16;
      int r  = rb + (lane >> 2);
      int gc = (lane & 3) ^ ((r >> 1) & 3);
      GLDS16(gB + (size_t)(h4 * SSZ + obase + r) * CDF + cb + gc * 8,
             dst + 2048 + rb * 32);
    }
  }
}

__global__ __launch_bounds__(256) void k4_mfma(const unsigned short* __restrict__ N216,
                                               const unsigned short* __restrict__ W16,
                                               float* __restrict__ out0,
                                               float* __restrict__ out1) {
  __shared__ __align__(16) short S[3 * 6144];   // 36 KB

  int blk = blockIdx.x;
  int g = blk >> 8;
  int r8 = blk & 255;
  int b = r8 >> 3, ot = r8 & 7;
  int obase = ot * 128;
  int t = threadIdx.x;
  int lane = t & 63, wave = t >> 6;
  int ln15 = lane & 15, kh = lane >> 4;

  const short* gA = (const short*)N216 + (size_t)b * IDF * KHC;
  const short* gB = (const short*)W16;

  int offA[4], offB[2];
#pragma unroll
  for (int r = 0; r < 4; ++r) {
    int row = r * 16 + ln15;
    offA[r] = row * 32 + ((kh ^ ((row >> 1) & 3)) * 8);
  }
#pragma unroll
  for (int c = 0; c < 2; ++c) {
    int row = wave * 32 + c * 16 + ln15;
    offB[c] = 2048 + row * 32 + ((kh ^ ((row >> 1) & 3)) * 8);
  }

  int kbase = g * (KHC / 2);
  f32x4 acc[4][2] = {};

  k4_stage(&S[0],        gA, gB, wave, lane, kbase, obase);
  k4_stage(&S[6144],     gA, gB, wave, lane, kbase + 32, obase);
  k4_stage(&S[2 * 6144], gA, gB, wave, lane, kbase + 64, obase);
  int cur = 0;

  const int NSTEP = 32;
#pragma unroll 1
  for (int ks = 0; ks < NSTEP; ++ks) {
    short* Sc = &S[cur * 6144];
    WAIT_ENTER3(6, 3)
    half8v fa[4], fb[2];
#pragma unroll
    for (int r = 0; r < 4; ++r)
      fa[r] = *reinterpret_cast<const half8v*>(&Sc[offA[r]]);
#pragma unroll
    for (int c = 0; c < 2; ++c)
      fb[c] = *reinterpret_cast<const half8v*>(&Sc[offB[c]]);
    __builtin_amdgcn_s_setprio(1);
#pragma unroll
    for (int r = 0; r < 4; ++r)
#pragma unroll
      for (int c = 0; c < 2; ++c)
        acc[r][c] = __builtin_amdgcn_mfma_f32_16x16x32_f16(fa[r], fb[c], acc[r][c], 0, 0, 0);
    __builtin_amdgcn_s_setprio(0);
    BAR_EXIT()
    if (ks + 3 < NSTEP)
      k4_stage(Sc, gA, gB, wave, lane, kbase + (ks + 3) * 32, obase);
    cur = (cur == 2) ? 0 : cur + 1;
  }

  float* dst = (g == 0) ? out0 : out1;
  int rowq = (lane >> 4) * 4;
#pragma unroll
  for (int r = 0; r < 4; ++r)
#pragma unroll
    for (int c = 0; c < 2; ++c)
#pragma unroll
      for (int reg = 0; reg < 4; ++reg)
        dst[((size_t)b * IDF + r * 16 + rowq + reg) * SSZ +
            obase + wave * 32 + c * 16 + ln15] = acc[r][c][reg];
}

// out += P
__global__ __launch_bounds__(256) void k_add(float* __restrict__ out,
                                             const float* __restrict__ P) {
  int idx = blockIdx.x * 256 + threadIdx.x;
  float4 a = reinterpret_cast<float4*>(out)[idx];
  float4 p = reinterpret_cast<const float4*>(P)[idx];
  a.x += p.x; a.y += p.y; a.z += p.z; a.w += p.w;
  reinterpret_cast<float4*>(out)[idx] = a;
}

// ---------------------------------------------------------------------------
// K5: attn_out[b][l][i] = sum_h P16[bh][i][l]  (fp16 input)
// ---------------------------------------------------------------------------
__global__ __launch_bounds__(256) void k_attnout(const unsigned short* __restrict__ P16,
                                                 float* __restrict__ outa) {
  __shared__ float T[64][65];
  int blk = blockIdx.x; int b = blk >> 2, lt = blk & 3;
  int l0 = lt * 64;
  int tid = threadIdx.x;
  float4 acc[4];
#pragma unroll
  for (int p = 0; p < 4; ++p) acc[p] = make_float4(0.f, 0.f, 0.f, 0.f);
  for (int h = 0; h < NH; ++h) {
    size_t src = (size_t)(b * NH + h) * IDF * LL;
#pragma unroll
    for (int p = 0; p < 4; ++p) {
      int f = tid + p * 256;
      int i = f >> 4, lc = (f & 15) * 4;
      ushort4 u = *reinterpret_cast<const ushort4*>(&P16[src + i * LL + l0 + lc]);
      acc[p].x += h2f(u.x); acc[p].y += h2f(u.y);
      acc[p].z += h2f(u.z); acc[p].w += h2f(u.w);
    }
  }
#pragma unroll
  for (int p = 0; p < 4; ++p) {
    int f = tid + p * 256;
    int i = f >> 4, lc = (f & 15) * 4;
    T[i][lc + 0] = acc[p].x; T[i][lc + 1] = acc[p].y;
    T[i][lc + 2] = acc[p].z; T[i][lc + 3] = acc[p].w;
  }
  __syncthreads();
#pragma unroll
  for (int p = 0; p < 4; ++p) {
    int f = tid + p * 256;
    int lr = f >> 4, ic = (f & 15) * 4;
    float4 v = {T[ic + 0][lr], T[ic + 1][lr], T[ic + 2][lr], T[ic + 3][lr]};
    *reinterpret_cast<float4*>(&outa[((size_t)b * LL + l0 + lr) * IDF + ic]) = v;
  }
}

// ---------------------------------------------------------------------------
extern "C" void kernel_launch(void* const* d_in, const int* in_sizes, int n_in,
                              void* d_out, int out_size, void* d_ws, size_t ws_size,
                              hipStream_t stream) {
  const float* wc  = (const float*)d_in[0];   // [32][64][1024]
  const float* ctx = (const float*)d_in[1];   // [32][256][256]
  const float* W   = (const float*)d_in[2];   // [8][1024][256]
  float* out = (float*)d_out;

  const size_t NE = 2097152;   // elems of wc == W == ctx
  const size_t NM = 4194304;   // elems of M == P == N2
  __hip_bfloat16* p = (__hip_bfloat16*)d_ws;
  __hip_bfloat16 *wch = p, *wcl = wch + NE, *wth = wcl + NE, *wtl = wth + NE;
  p = wtl + NE;
  __hip_bfloat16 *Mh = p, *Ml = Mh + NM;            p = Ml + NM;
  __hip_bfloat16 *cTh = p, *cTl = cTh + NE;         p = cTl + NE;
  unsigned short *ctx16 = (unsigned short*)p;       p += NE;
  unsigned short *W16   = (unsigned short*)p;       p += NE;
  unsigned short *P16   = (unsigned short*)p;       p += NM;
  unsigned short *N216  = (unsigned short*)p;       p += NM;
  float* Pbuf = (float*)p;                          // 2.1M floats

  k_split      <<<2048, 256, 0, stream>>>(wc, wch, wcl);
  k_split_Wt   <<<512, 256, 0, stream>>>(W, wth, wtl);
  k_split_f16  <<<2048, 256, 0, stream>>>(W, W16);
  k_split_f16  <<<2048, 256, 0, stream>>>(ctx, ctx16);
  k_split_ctxT <<<512, 256, 0, stream>>>(ctx, cTh, cTl);
  k1_mfma      <<<BB * NH * 2, 256, 0, stream>>>(wch, wcl, wth, wtl, Mh, Ml);
  k_attn       <<<BB * NH, 512, 0, stream>>>(Mh, Ml, cTh, cTl, P16);
  k_N2         <<<BB * NH * 2, 256, 0, stream>>>(P16, ctx16, N216);
  k_attnout    <<<BB * 4, 256, 0, stream>>>(P16, out + (size_t)BB * IDF * SSZ);
  k4_mfma      <<<512, 256, 0, stream>>>(N216, W16, out, Pbuf);
  k_add        <<<2048, 256, 0, stream>>>(out, Pbuf);
}

// Round 15
// 92.832 us; speedup vs baseline: 4.1124x; 1.3057x over previous
//
#include <hip/hip_runtime.h>
#include <hip/hip_bf16.h>

#define BB 32
#define IDF 64
#define CDF 256
#define SSZ 1024
#define NH 8
#define LL 256
#define KHC 2048   // NH*CDF

typedef __attribute__((ext_vector_type(8))) _Float16 half8v;   // 8 fp16
typedef __attribute__((ext_vector_type(4))) float f32x4;       // MFMA acc

// async global->LDS, 16B per lane, LDS dest = wave-uniform base + lane*16
#define GLDS16(g, l) __builtin_amdgcn_global_load_lds(                        \
    (const __attribute__((address_space(1))) void*)(g),                       \
    (__attribute__((address_space(3))) void*)(l), 16, 0, 0)

// 3-deep pipeline phase entry (T3+T4): wait only for the CURRENT buffer's
// DMA, leaving the next TWO stages in flight. Never vmcnt(0) mid-loop.
#define WAIT_ENTER3(NFULL, NHALF)                                             \
  { if (ks < NSTEP - 2)                                                       \
      asm volatile("s_waitcnt vmcnt(" #NFULL ")" ::: "memory");               \
    else if (ks == NSTEP - 2)                                                 \
      asm volatile("s_waitcnt vmcnt(" #NHALF ")" ::: "memory");               \
    else                                                                      \
      asm volatile("s_waitcnt vmcnt(0)" ::: "memory");                        \
    __builtin_amdgcn_s_barrier();                                             \
    __builtin_amdgcn_sched_barrier(0); }
#define BAR_EXIT()                                                            \
  { __builtin_amdgcn_sched_barrier(0);                                        \
    __builtin_amdgcn_s_barrier();                                             \
    __builtin_amdgcn_sched_barrier(0); }

__device__ inline unsigned short f2h(float x) {
  _Float16 h = (_Float16)x;
  return *reinterpret_cast<unsigned short*>(&h);
}
__device__ inline float h2f(unsigned short u) {
  _Float16 h = *reinterpret_cast<_Float16*>(&u);
  return (float)h;
}

// ---------------------------------------------------------------------------
// Elementwise fp16 cast (2.097M elems): wc16, W16, ctx16.
// ---------------------------------------------------------------------------
__global__ __launch_bounds__(256) void k_split_f16(const float* __restrict__ src,
                                                   unsigned short* __restrict__ d) {
  int idx = (blockIdx.x * 256 + threadIdx.x) * 4;
  float4 v = *reinterpret_cast<const float4*>(&src[idx]);
  __align__(8) unsigned short h[4] = {f2h(v.x), f2h(v.y), f2h(v.z), f2h(v.w)};
  *reinterpret_cast<int2*>(&d[idx]) = *reinterpret_cast<int2*>(h);
}

// ---------------------------------------------------------------------------
// Transpose+cast W[h][o][c] -> Wt16 [h][c][o] (fp16). For K1.
// ---------------------------------------------------------------------------
__global__ __launch_bounds__(256) void k_split_Wt16(const float* __restrict__ W,
                                                    unsigned short* __restrict__ wt) {
  __shared__ float Tt[64][65];   // [c][o]
  int blk = blockIdx.x;
  int h = blk >> 6, ot = (blk >> 2) & 15, ct = blk & 3;
  int og = ot * 64, cg = ct * 64;
  int t = threadIdx.x;
  int o_l = t >> 4, c4 = (t & 15) * 4;
#pragma unroll
  for (int p = 0; p < 4; ++p) {
    int o = o_l + 16 * p;
    float4 v = *reinterpret_cast<const float4*>(
        &W[((size_t)h * SSZ + og + o) * CDF + cg + c4]);
    Tt[c4 + 0][o] = v.x; Tt[c4 + 1][o] = v.y;
    Tt[c4 + 2][o] = v.z; Tt[c4 + 3][o] = v.w;
  }
  __syncthreads();
  int c_l = t >> 2;
#pragma unroll
  for (int p = 0; p < 4; ++p) {
    int o0 = ((t & 3) + 4 * p) * 4;
    __align__(8) unsigned short hv[4];
#pragma unroll
    for (int j = 0; j < 4; ++j) hv[j] = f2h(Tt[c_l][o0 + j]);
    size_t base = ((size_t)h * CDF + cg + c_l) * SSZ + og + o0;
    *reinterpret_cast<int2*>(&wt[base]) = *reinterpret_cast<int2*>(hv);
  }
}

// ---------------------------------------------------------------------------
// Transpose+cast ctx[b][c][l] -> cT16 [b][l][c] (fp16). For K2.
// ---------------------------------------------------------------------------
__global__ __launch_bounds__(256) void k_split_cT16(const float* __restrict__ ctx,
                                                    unsigned short* __restrict__ ct) {
  __shared__ float Tt[64][65];   // [l][c]
  int blk = blockIdx.x;
  int b = blk >> 4, cq = (blk >> 2) & 3, lt = blk & 3;
  int cg = cq * 64, lg = lt * 64;
  int t = threadIdx.x;
  int c_l = t >> 4, l4 = (t & 15) * 4;
#pragma unroll
  for (int p = 0; p < 4; ++p) {
    int c = c_l + 16 * p;
    float4 v = *reinterpret_cast<const float4*>(
        &ctx[((size_t)b * CDF + cg + c) * LL + lg + l4]);
    Tt[l4 + 0][c] = v.x; Tt[l4 + 1][c] = v.y;
    Tt[l4 + 2][c] = v.z; Tt[l4 + 3][c] = v.w;
  }
  __syncthreads();
  int l_l = t >> 2;
#pragma unroll
  for (int p = 0; p < 4; ++p) {
    int c0 = ((t & 3) + 4 * p) * 4;
    __align__(8) unsigned short hv[4];
#pragma unroll
    for (int j = 0; j < 4; ++j) hv[j] = f2h(Tt[l_l][c0 + j]);
    size_t base = ((size_t)b * LL + lg + l_l) * CDF + cg + c0;
    *reinterpret_cast<int2*>(&ct[base]) = *reinterpret_cast<int2*>(hv);
  }
}

// ---------------------------------------------------------------------------
// K1 (MFMA fp16 SINGLE-TERM, 3-deep): M16 = wc*W^T.
// grid 512: (bh, nh-half of 128c). 4 waves x (64i x 32c). BK=32, 32 steps.
// 3 GLDS16 / wave / stage; 3 x 12 KB LDS buffers.
// ---------------------------------------------------------------------------
__device__ __forceinline__ void k1_stage(short* dst,
                                         const short* gA, const short* gB,
                                         int wave, int lane, int k0) {
#pragma unroll
  for (int j = 0; j < 3; ++j) {
    int inst = wave * 3 + j;               // 0..11
    if (inst < 4) {
      int rb = inst * 16;
      int r  = rb + (lane >> 2);
      int gc = (lane & 3) ^ ((r >> 1) & 3);
      GLDS16(gA + (size_t)r * SSZ + k0 + gc * 8, dst + rb * 32);
    } else {
      int rb = (inst - 4) * 16;
      int r  = rb + (lane >> 2);
      int gc = (lane & 3) ^ ((r >> 1) & 3);
      GLDS16(gB + (size_t)r * SSZ + k0 + gc * 8, dst + 2048 + rb * 32);
    }
  }
}

__global__ __launch_bounds__(256) void k1_mfma(const unsigned short* __restrict__ wc16,
                                               const unsigned short* __restrict__ Wt16,
                                               unsigned short* __restrict__ M16) {
  __shared__ __align__(16) short S[3 * 6144];   // 36 KB

  int blk = blockIdx.x;
  int bh = blk >> 1, nh = blk & 1;
  int b = bh >> 3, h = bh & 7;
  int t = threadIdx.x;
  int lane = t & 63, wave = t >> 6;
  int ln15 = lane & 15, kh = lane >> 4;

  const short* gA = (const short*)wc16 + (size_t)b * IDF * SSZ;
  const short* gB = (const short*)Wt16 + (size_t)(h * CDF + nh * 128) * SSZ;

  int offA[4], offB[2];
#pragma unroll
  for (int r = 0; r < 4; ++r) {
    int row = r * 16 + ln15;
    offA[r] = row * 32 + ((kh ^ ((row >> 1) & 3)) * 8);
  }
#pragma unroll
  for (int c = 0; c < 2; ++c) {
    int row = wave * 32 + c * 16 + ln15;
    offB[c] = 2048 + row * 32 + ((kh ^ ((row >> 1) & 3)) * 8);
  }

  f32x4 acc[4][2] = {};
  k1_stage(&S[0],        gA, gB, wave, lane, 0);
  k1_stage(&S[6144],     gA, gB, wave, lane, 32);
  k1_stage(&S[2 * 6144], gA, gB, wave, lane, 64);
  int cur = 0;

  const int NSTEP = 32;
#pragma unroll 1
  for (int ks = 0; ks < NSTEP; ++ks) {
    short* Sc = &S[cur * 6144];
    WAIT_ENTER3(6, 3)
    half8v fa[4], fb[2];
#pragma unroll
    for (int r = 0; r < 4; ++r)
      fa[r] = *reinterpret_cast<const half8v*>(&Sc[offA[r]]);
#pragma unroll
    for (int c = 0; c < 2; ++c)
      fb[c] = *reinterpret_cast<const half8v*>(&Sc[offB[c]]);
    __builtin_amdgcn_s_setprio(1);
#pragma unroll
    for (int r = 0; r < 4; ++r)
#pragma unroll
      for (int c = 0; c < 2; ++c)
        acc[r][c] = __builtin_amdgcn_mfma_f32_16x16x32_f16(fa[r], fb[c], acc[r][c], 0, 0, 0);
    __builtin_amdgcn_s_setprio(0);
    BAR_EXIT()
    if (ks + 3 < NSTEP)
      k1_stage(Sc, gA, gB, wave, lane, (ks + 3) * 32);
    cur = (cur == 2) ? 0 : cur + 1;
  }

  size_t obase = (size_t)bh * IDF * CDF + nh * 128;
  int rowq = (lane >> 4) * 4;
#pragma unroll
  for (int r = 0; r < 4; ++r)
#pragma unroll
    for (int c = 0; c < 2; ++c)
#pragma unroll
      for (int reg = 0; reg < 4; ++reg) {
        size_t idx = obase + (size_t)(r * 16 + rowq + reg) * CDF + wave * 32 + c * 16 + ln15;
        M16[idx] = f2h(acc[r][c][reg]);
      }
}

// ---------------------------------------------------------------------------
// K2 (MFMA fp16 SINGLE-TERM + fused softmax, 3-deep): P = softmax_l(M*cT^T).
// grid 256 (bh), 512 thr = 8 waves x (64i x 32l). K=256, BK=32, 8 steps.
// Stage: A(M,4 insts) + B(cT,16) + A-dup(4, keeps vmcnt wave-uniform) = 24
// insts = 3/wave. Buffer 24 KB x 3 = 72 KB.
// ---------------------------------------------------------------------------
__device__ __forceinline__ void k2_stage(short* dst,
                                         const short* gM, const short* gT,
                                         int wave, int lane, int k0) {
#pragma unroll
  for (int j = 0; j < 3; ++j) {
    int inst = wave * 3 + j;               // 0..23
    const short* src; int tile_off, rb;
    if (inst < 4)       { src = gM; tile_off = 0;     rb = inst * 16; }
    else if (inst < 20) { src = gT; tile_off = 2048;  rb = (inst - 4) * 16; }
    else                { src = gM; tile_off = 10240; rb = (inst - 20) * 16; } // dup
    int r  = rb + (lane >> 2);
    int gc = (lane & 3) ^ ((r >> 1) & 3);
    GLDS16(src + (size_t)r * CDF + k0 + gc * 8, dst + tile_off + rb * 32);
  }
}

__global__ __launch_bounds__(512) void k_attn(const unsigned short* __restrict__ M16,
                                              const unsigned short* __restrict__ cT16,
                                              unsigned short* __restrict__ P16) {
  __shared__ __align__(16) short S[3 * 12288];   // 72 KB

  int bh = blockIdx.x;
  int b = bh >> 3;
  int t = threadIdx.x;
  int lane = t & 63, wave = t >> 6;             // wave 0..7
  int ln15 = lane & 15, kh = lane >> 4;

  const short* gM = (const short*)M16 + (size_t)bh * IDF * CDF;
  const short* gT = (const short*)cT16 + (size_t)b * LL * CDF;

  int offA[4], offB[2];
#pragma unroll
  for (int r = 0; r < 4; ++r) {
    int row = r * 16 + ln15;
    offA[r] = row * 32 + ((kh ^ ((row >> 1) & 3)) * 8);
  }
#pragma unroll
  for (int c = 0; c < 2; ++c) {
    int row = wave * 32 + c * 16 + ln15;       // 0..255
    offB[c] = 2048 + row * 32 + ((kh ^ ((row >> 1) & 3)) * 8);
  }

  f32x4 acc[4][2] = {};
  k2_stage(&S[0],         gM, gT, wave, lane, 0);
  k2_stage(&S[12288],     gM, gT, wave, lane, 32);
  k2_stage(&S[2 * 12288], gM, gT, wave, lane, 64);
  int cur = 0;

  const int NSTEP = 8;
#pragma unroll 1
  for (int ks = 0; ks < NSTEP; ++ks) {
    short* Sc = &S[cur * 12288];
    WAIT_ENTER3(6, 3)
    half8v fa[4], fb[2];
#pragma unroll
    for (int r = 0; r < 4; ++r)
      fa[r] = *reinterpret_cast<const half8v*>(&Sc[offA[r]]);
#pragma unroll
    for (int c = 0; c < 2; ++c)
      fb[c] = *reinterpret_cast<const half8v*>(&Sc[offB[c]]);
    __builtin_amdgcn_s_setprio(1);
#pragma unroll
    for (int r = 0; r < 4; ++r)
#pragma unroll
      for (int c = 0; c < 2; ++c)
        acc[r][c] = __builtin_amdgcn_mfma_f32_16x16x32_f16(fa[r], fb[c], acc[r][c], 0, 0, 0);
    __builtin_amdgcn_s_setprio(0);
    BAR_EXIT()
    if (ks + 3 < NSTEP)
      k2_stage(Sc, gM, gT, wave, lane, (ks + 3) * 32);
    cur = (cur == 2) ? 0 : cur + 1;
  }

  // ---- fused softmax over l (cols). row = r*16+(lane>>4)*4+reg,
  //      col = wave*32 + c*16 + (lane&15). pm[row][w] partials in LDS.
  float* pm = reinterpret_cast<float*>(&S[0]);   // 64*8 floats
  int rowq = (lane >> 4) * 4;
  float gmax[4][4], ginv[4][4];
#pragma unroll
  for (int r = 0; r < 4; ++r)
#pragma unroll
    for (int reg = 0; reg < 4; ++reg) {
      float m = fmaxf(acc[r][0][reg], acc[r][1][reg]);
#pragma unroll
      for (int msk = 8; msk >= 1; msk >>= 1) m = fmaxf(m, __shfl_xor(m, msk, 64));
      if (ln15 == 0) pm[(r * 16 + rowq + reg) * 8 + wave] = m;
    }
  __syncthreads();
#pragma unroll
  for (int r = 0; r < 4; ++r)
#pragma unroll
    for (int reg = 0; reg < 4; ++reg) {
      int row = r * 16 + rowq + reg;
      float4 p0 = *reinterpret_cast<const float4*>(&pm[row * 8]);
      float4 p1 = *reinterpret_cast<const float4*>(&pm[row * 8 + 4]);
      gmax[r][reg] = fmaxf(fmaxf(fmaxf(p0.x, p0.y), fmaxf(p0.z, p0.w)),
                           fmaxf(fmaxf(p1.x, p1.y), fmaxf(p1.z, p1.w)));
    }
  __syncthreads();
#pragma unroll
  for (int r = 0; r < 4; ++r)
#pragma unroll
    for (int reg = 0; reg < 4; ++reg) {
      acc[r][0][reg] = __expf(acc[r][0][reg] - gmax[r][reg]);
      acc[r][1][reg] = __expf(acc[r][1][reg] - gmax[r][reg]);
      float s = acc[r][0][reg] + acc[r][1][reg];
#pragma unroll
      for (int msk = 8; msk >= 1; msk >>= 1) s += __shfl_xor(s, msk, 64);
      if (ln15 == 0) pm[(r * 16 + rowq + reg) * 8 + wave] = s;
    }
  __syncthreads();
#pragma unroll
  for (int r = 0; r < 4; ++r)
#pragma unroll
    for (int reg = 0; reg < 4; ++reg) {
      int row = r * 16 + rowq + reg;
      float4 p0 = *reinterpret_cast<const float4*>(&pm[row * 8]);
      float4 p1 = *reinterpret_cast<const float4*>(&pm[row * 8 + 4]);
      ginv[r][reg] = 1.f / (p0.x + p0.y + p0.z + p0.w + p1.x + p1.y + p1.z + p1.w);
    }
  size_t obase = (size_t)bh * IDF * LL;
#pragma unroll
  for (int r = 0; r < 4; ++r)
#pragma unroll
    for (int c = 0; c < 2; ++c)
#pragma unroll
      for (int reg = 0; reg < 4; ++reg) {
        float p = acc[r][c][reg] * ginv[r][reg];
        size_t idx = obase + (size_t)(r * 16 + rowq + reg) * LL + wave * 32 + c * 16 + ln15;
        P16[idx] = f2h(p);
      }
}

// ---------------------------------------------------------------------------
// K3 (MFMA fp16, 3-deep): N2[b][i][h*256+c] = sum_l P*ctx. UNCHANGED.
// ---------------------------------------------------------------------------
__device__ __forceinline__ void k3_stage(short* dst,
                                         const short* gP, const short* gC,
                                         int wave, int lane, int k0) {
#pragma unroll
  for (int j = 0; j < 3; ++j) {
    int inst = wave * 3 + j;               // 0..11
    const short* src; int tile_off, rb;
    if (inst < 4) { src = gP; tile_off = 0;    rb = inst * 16; }
    else          { src = gC; tile_off = 2048; rb = (inst - 4) * 16; }
    int r  = rb + (lane >> 2);
    int gc = (lane & 3) ^ ((r >> 1) & 3);
    GLDS16(src + (size_t)r * LL + k0 + gc * 8, dst + tile_off + rb * 32);
  }
}

__global__ __launch_bounds__(256) void k_N2(const unsigned short* __restrict__ P16,
                                            const unsigned short* __restrict__ ctx16,
                                            unsigned short* __restrict__ N216) {
  __shared__ __align__(16) short S[3 * 6144];   // 36 KB

  int blk = blockIdx.x;
  int bh = blk >> 1, ch = blk & 1;
  int b = bh >> 3, h = bh & 7;
  int cgbase = ch * 128;
  int t = threadIdx.x;
  int lane = t & 63, wave = t >> 6;
  int ln15 = lane & 15, kh = lane >> 4;

  const short* gP = (const short*)P16 + (size_t)bh * IDF * LL;
  const short* gC = (const short*)ctx16 + (size_t)(b * CDF + cgbase) * LL;

  int offA[4], offB[2];
#pragma unroll
  for (int r = 0; r < 4; ++r) {
    int row = r * 16 + ln15;
    offA[r] = row * 32 + ((kh ^ ((row >> 1) & 3)) * 8);
  }
#pragma unroll
  for (int c = 0; c < 2; ++c) {
    int row = wave * 32 + c * 16 + ln15;
    offB[c] = 2048 + row * 32 + ((kh ^ ((row >> 1) & 3)) * 8);
  }

  f32x4 acc[4][2] = {};
  k3_stage(&S[0],        gP, gC, wave, lane, 0);
  k3_stage(&S[6144],     gP, gC, wave, lane, 32);
  k3_stage(&S[2 * 6144], gP, gC, wave, lane, 64);
  int cur = 0;

  const int NSTEP = 8;
#pragma unroll 1
  for (int ks = 0; ks < NSTEP; ++ks) {
    short* Sc = &S[cur * 6144];
    WAIT_ENTER3(6, 3)
    half8v fa[4], fb[2];
#pragma unroll
    for (int r = 0; r < 4; ++r)
      fa[r] = *reinterpret_cast<const half8v*>(&Sc[offA[r]]);
#pragma unroll
    for (int c = 0; c < 2; ++c)
      fb[c] = *reinterpret_cast<const half8v*>(&Sc[offB[c]]);
    __builtin_amdgcn_s_setprio(1);
#pragma unroll
    for (int r = 0; r < 4; ++r)
#pragma unroll
      for (int c = 0; c < 2; ++c)
        acc[r][c] = __builtin_amdgcn_mfma_f32_16x16x32_f16(fa[r], fb[c], acc[r][c], 0, 0, 0);
    __builtin_amdgcn_s_setprio(0);
    BAR_EXIT()
    if (ks + 3 < NSTEP)
      k3_stage(Sc, gP, gC, wave, lane, (ks + 3) * 32);
    cur = (cur == 2) ? 0 : cur + 1;
  }

  size_t base = (size_t)b * IDF * KHC + h * CDF + cgbase;
  int rowq = (lane >> 4) * 4;
#pragma unroll
  for (int r = 0; r < 4; ++r)
#pragma unroll
    for (int c = 0; c < 2; ++c)
#pragma unroll
      for (int reg = 0; reg < 4; ++reg) {
        size_t idx = base + (size_t)(r * 16 + rowq + reg) * KHC + wave * 32 + c * 16 + ln15;
        N216[idx] = f2h(acc[r][c][reg]);
      }
}

// ---------------------------------------------------------------------------
// K4 (MFMA fp16, 3-deep): ctx_out[b][i][o] = sum_{hc} N2*W. UNCHANGED.
// ---------------------------------------------------------------------------
__device__ __forceinline__ void k4_stage(short* dst,
                                         const short* gA, const short* gB,
                                         int wave, int lane, int kk0, int obase) {
  int h4 = kk0 >> 8, cb = kk0 & 255;
#pragma unroll
  for (int j = 0; j < 3; ++j) {
    int inst = wave * 3 + j;               // 0..11
    if (inst < 4) {
      int rb = inst * 16;
      int r  = rb + (lane >> 2);
      int gc = (lane & 3) ^ ((r >> 1) & 3);
      GLDS16(gA + (size_t)r * KHC + kk0 + gc * 8, dst + rb * 32);
    } else {
      int rb = (inst - 4) * 16;
      int r  = rb + (lane >> 2);
      int gc = (lane & 3) ^ ((r >> 1) & 3);
      GLDS16(gB + (size_t)(h4 * SSZ + obase + r) * CDF + cb + gc * 8,
             dst + 2048 + rb * 32);
    }
  }
}

__global__ __launch_bounds__(256) void k4_mfma(const unsigned short* __restrict__ N216,
                                               const unsigned short* __restrict__ W16,
                                               float* __restrict__ out0,
                                               float* __restrict__ out1) {
  __shared__ __align__(16) short S[3 * 6144];   // 36 KB

  int blk = blockIdx.x;
  int g = blk >> 8;
  int r8 = blk & 255;
  int b = r8 >> 3, ot = r8 & 7;
  int obase = ot * 128;
  int t = threadIdx.x;
  int lane = t & 63, wave = t >> 6;
  int ln15 = lane & 15, kh = lane >> 4;

  const short* gA = (const short*)N216 + (size_t)b * IDF * KHC;
  const short* gB = (const short*)W16;

  int offA[4], offB[2];
#pragma unroll
  for (int r = 0; r < 4; ++r) {
    int row = r * 16 + ln15;
    offA[r] = row * 32 + ((kh ^ ((row >> 1) & 3)) * 8);
  }
#pragma unroll
  for (int c = 0; c < 2; ++c) {
    int row = wave * 32 + c * 16 + ln15;
    offB[c] = 2048 + row * 32 + ((kh ^ ((row >> 1) & 3)) * 8);
  }

  int kbase = g * (KHC / 2);
  f32x4 acc[4][2] = {};

  k4_stage(&S[0],        gA, gB, wave, lane, kbase, obase);
  k4_stage(&S[6144],     gA, gB, wave, lane, kbase + 32, obase);
  k4_stage(&S[2 * 6144], gA, gB, wave, lane, kbase + 64, obase);
  int cur = 0;

  const int NSTEP = 32;
#pragma unroll 1
  for (int ks = 0; ks < NSTEP; ++ks) {
    short* Sc = &S[cur * 6144];
    WAIT_ENTER3(6, 3)
    half8v fa[4], fb[2];
#pragma unroll
    for (int r = 0; r < 4; ++r)
      fa[r] = *reinterpret_cast<const half8v*>(&Sc[offA[r]]);
#pragma unroll
    for (int c = 0; c < 2; ++c)
      fb[c] = *reinterpret_cast<const half8v*>(&Sc[offB[c]]);
    __builtin_amdgcn_s_setprio(1);
#pragma unroll
    for (int r = 0; r < 4; ++r)
#pragma unroll
      for (int c = 0; c < 2; ++c)
        acc[r][c] = __builtin_amdgcn_mfma_f32_16x16x32_f16(fa[r], fb[c], acc[r][c], 0, 0, 0);
    __builtin_amdgcn_s_setprio(0);
    BAR_EXIT()
    if (ks + 3 < NSTEP)
      k4_stage(Sc, gA, gB, wave, lane, kbase + (ks + 3) * 32, obase);
    cur = (cur == 2) ? 0 : cur + 1;
  }

  float* dst = (g == 0) ? out0 : out1;
  int rowq = (lane >> 4) * 4;
#pragma unroll
  for (int r = 0; r < 4; ++r)
#pragma unroll
    for (int c = 0; c < 2; ++c)
#pragma unroll
      for (int reg = 0; reg < 4; ++reg)
        dst[((size_t)b * IDF + r * 16 + rowq + reg) * SSZ +
            obase + wave * 32 + c * 16 + ln15] = acc[r][c][reg];
}

// out += P
__global__ __launch_bounds__(256) void k_add(float* __restrict__ out,
                                             const float* __restrict__ P) {
  int idx = blockIdx.x * 256 + threadIdx.x;
  float4 a = reinterpret_cast<float4*>(out)[idx];
  float4 p = reinterpret_cast<const float4*>(P)[idx];
  a.x += p.x; a.y += p.y; a.z += p.z; a.w += p.w;
  reinterpret_cast<float4*>(out)[idx] = a;
}

// ---------------------------------------------------------------------------
// K5: attn_out[b][l][i] = sum_h P16[bh][i][l]  (fp16 input)
// ---------------------------------------------------------------------------
__global__ __launch_bounds__(256) void k_attnout(const unsigned short* __restrict__ P16,
                                                 float* __restrict__ outa) {
  __shared__ float T[64][65];
  int blk = blockIdx.x; int b = blk >> 2, lt = blk & 3;
  int l0 = lt * 64;
  int tid = threadIdx.x;
  float4 acc[4];
#pragma unroll
  for (int p = 0; p < 4; ++p) acc[p] = make_float4(0.f, 0.f, 0.f, 0.f);
  for (int h = 0; h < NH; ++h) {
    size_t src = (size_t)(b * NH + h) * IDF * LL;
#pragma unroll
    for (int p = 0; p < 4; ++p) {
      int f = tid + p * 256;
      int i = f >> 4, lc = (f & 15) * 4;
      ushort4 u = *reinterpret_cast<const ushort4*>(&P16[src + i * LL + l0 + lc]);
      acc[p].x += h2f(u.x); acc[p].y += h2f(u.y);
      acc[p].z += h2f(u.z); acc[p].w += h2f(u.w);
    }
  }
#pragma unroll
  for (int p = 0; p < 4; ++p) {
    int f = tid + p * 256;
    int i = f >> 4, lc = (f & 15) * 4;
    T[i][lc + 0] = acc[p].x; T[i][lc + 1] = acc[p].y;
    T[i][lc + 2] = acc[p].z; T[i][lc + 3] = acc[p].w;
  }
  __syncthreads();
#pragma unroll
  for (int p = 0; p < 4; ++p) {
    int f = tid + p * 256;
    int lr = f >> 4, ic = (f & 15) * 4;
    float4 v = {T[ic + 0][lr], T[ic + 1][lr], T[ic + 2][lr], T[ic + 3][lr]};
    *reinterpret_cast<float4*>(&outa[((size_t)b * LL + l0 + lr) * IDF + ic]) = v;
  }
}

// ---------------------------------------------------------------------------
extern "C" void kernel_launch(void* const* d_in, const int* in_sizes, int n_in,
                              void* d_out, int out_size, void* d_ws, size_t ws_size,
                              hipStream_t stream) {
  const float* wc  = (const float*)d_in[0];   // [32][64][1024]
  const float* ctx = (const float*)d_in[1];   // [32][256][256]
  const float* W   = (const float*)d_in[2];   // [8][1024][256]
  float* out = (float*)d_out;

  const size_t NE = 2097152;   // elems of wc == W == ctx
  const size_t NM = 4194304;   // elems of M == P == N2
  unsigned short* p = (unsigned short*)d_ws;
  unsigned short *wc16 = p;   p += NE;
  unsigned short *Wt16 = p;   p += NE;
  unsigned short *W16  = p;   p += NE;
  unsigned short *ctx16 = p;  p += NE;
  unsigned short *cT16 = p;   p += NE;
  unsigned short *M16  = p;   p += NM;
  unsigned short *P16  = p;   p += NM;
  unsigned short *N216 = p;   p += NM;
  float* Pbuf = (float*)p;    // 2.1M floats

  k_split_f16  <<<2048, 256, 0, stream>>>(wc, wc16);
  k_split_Wt16 <<<512, 256, 0, stream>>>(W, Wt16);
  k_split_f16  <<<2048, 256, 0, stream>>>(W, W16);
  k_split_f16  <<<2048, 256, 0, stream>>>(ctx, ctx16);
  k_split_cT16 <<<512, 256, 0, stream>>>(ctx, cT16);
  k1_mfma      <<<BB * NH * 2, 256, 0, stream>>>(wc16, Wt16, M16);
  k_attn       <<<BB * NH, 512, 0, stream>>>(M16, cT16, P16);
  k_N2         <<<BB * NH * 2, 256, 0, stream>>>(P16, ctx16, N216);
  k_attnout    <<<BB * 4, 256, 0, stream>>>(P16, out + (size_t)BB * IDF * SSZ);
  k4_mfma      <<<512, 256, 0, stream>>>(N216, W16, out, Pbuf);
  k_add        <<<2048, 256, 0, stream>>>(out, Pbuf);
}

// Round 16
// 84.164 us; speedup vs baseline: 4.5359x; 1.1030x over previous
//
#include <hip/hip_runtime.h>
#include <hip/hip_bf16.h>

#define BB 32
#define IDF 64
#define CDF 256
#define SSZ 1024
#define NH 8
#define LL 256
#define KHC 2048   // NH*CDF

typedef __attribute__((ext_vector_type(8))) _Float16 half8v;   // 8 fp16
typedef __attribute__((ext_vector_type(4))) float f32x4;       // MFMA acc

// async global->LDS, 16B per lane, LDS dest = wave-uniform base + lane*16
#define GLDS16(g, l) __builtin_amdgcn_global_load_lds(                        \
    (const __attribute__((address_space(1))) void*)(g),                       \
    (__attribute__((address_space(3))) void*)(l), 16, 0, 0)

// 3-deep pipeline phase entry (T3+T4): wait only for the CURRENT buffer's
// DMA, leaving the next TWO stages in flight. Never vmcnt(0) mid-loop.
#define WAIT_ENTER3(NFULL, NHALF)                                             \
  { if (ks < NSTEP - 2)                                                       \
      asm volatile("s_waitcnt vmcnt(" #NFULL ")" ::: "memory");               \
    else if (ks == NSTEP - 2)                                                 \
      asm volatile("s_waitcnt vmcnt(" #NHALF ")" ::: "memory");               \
    else                                                                      \
      asm volatile("s_waitcnt vmcnt(0)" ::: "memory");                        \
    __builtin_amdgcn_s_barrier();                                             \
    __builtin_amdgcn_sched_barrier(0); }
#define BAR_EXIT()                                                            \
  { __builtin_amdgcn_sched_barrier(0);                                        \
    __builtin_amdgcn_s_barrier();                                             \
    __builtin_amdgcn_sched_barrier(0); }

__device__ inline unsigned short f2h(float x) {
  _Float16 h = (_Float16)x;
  return *reinterpret_cast<unsigned short*>(&h);
}
__device__ inline float h2f(unsigned short u) {
  _Float16 h = *reinterpret_cast<_Float16*>(&u);
  return (float)h;
}

// ---------------------------------------------------------------------------
// Fused elementwise fp16 casts: wc->wc16, W->W16, ctx->ctx16 (same size).
// grid 6144: source selected by block range (2048 blocks each).
// ---------------------------------------------------------------------------
__global__ __launch_bounds__(256) void k_split_all(const float* __restrict__ wc,
                                                   const float* __restrict__ W,
                                                   const float* __restrict__ ctx,
                                                   unsigned short* __restrict__ wc16,
                                                   unsigned short* __restrict__ W16,
                                                   unsigned short* __restrict__ ctx16) {
  int sel = blockIdx.x >> 11;              // 0,1,2
  int idx = ((blockIdx.x & 2047) * 256 + threadIdx.x) * 4;
  const float* src = (sel == 0) ? wc : (sel == 1) ? W : ctx;
  unsigned short* d = (sel == 0) ? wc16 : (sel == 1) ? W16 : ctx16;
  float4 v = *reinterpret_cast<const float4*>(&src[idx]);
  __align__(8) unsigned short h[4] = {f2h(v.x), f2h(v.y), f2h(v.z), f2h(v.w)};
  *reinterpret_cast<int2*>(&d[idx]) = *reinterpret_cast<int2*>(h);
}

// ---------------------------------------------------------------------------
// Fused transpose+cast: blocks 0..511 -> Wt16 [h][c][o]; 512..1023 -> cT16
// [b][l][c]. Both are 64x64-tile fp32->fp16 transposes.
// ---------------------------------------------------------------------------
__global__ __launch_bounds__(256) void k_split_T(const float* __restrict__ W,
                                                 const float* __restrict__ ctx,
                                                 unsigned short* __restrict__ wt,
                                                 unsigned short* __restrict__ ct) {
  __shared__ float Tt[64][65];
  int blk0 = blockIdx.x;
  int t = threadIdx.x;
  if (blk0 < 512) {                        // W[h][o][c] -> wt[h][c][o]
    int blk = blk0;
    int h = blk >> 6, ot = (blk >> 2) & 15, cq = blk & 3;
    int og = ot * 64, cg = cq * 64;
    int o_l = t >> 4, c4 = (t & 15) * 4;
#pragma unroll
    for (int p = 0; p < 4; ++p) {
      int o = o_l + 16 * p;
      float4 v = *reinterpret_cast<const float4*>(
          &W[((size_t)h * SSZ + og + o) * CDF + cg + c4]);
      Tt[c4 + 0][o] = v.x; Tt[c4 + 1][o] = v.y;
      Tt[c4 + 2][o] = v.z; Tt[c4 + 3][o] = v.w;
    }
    __syncthreads();
    int c_l = t >> 2;
#pragma unroll
    for (int p = 0; p < 4; ++p) {
      int o0 = ((t & 3) + 4 * p) * 4;
      __align__(8) unsigned short hv[4];
#pragma unroll
      for (int j = 0; j < 4; ++j) hv[j] = f2h(Tt[c_l][o0 + j]);
      size_t base = ((size_t)h * CDF + cg + c_l) * SSZ + og + o0;
      *reinterpret_cast<int2*>(&wt[base]) = *reinterpret_cast<int2*>(hv);
    }
  } else {                                 // ctx[b][c][l] -> ct[b][l][c]
    int blk = blk0 - 512;
    int b = blk >> 4, cq = (blk >> 2) & 3, lt = blk & 3;
    int cg = cq * 64, lg = lt * 64;
    int c_l = t >> 4, l4 = (t & 15) * 4;
#pragma unroll
    for (int p = 0; p < 4; ++p) {
      int c = c_l + 16 * p;
      float4 v = *reinterpret_cast<const float4*>(
          &ctx[((size_t)b * CDF + cg + c) * LL + lg + l4]);
      Tt[l4 + 0][c] = v.x; Tt[l4 + 1][c] = v.y;
      Tt[l4 + 2][c] = v.z; Tt[l4 + 3][c] = v.w;
    }
    __syncthreads();
    int l_l = t >> 2;
#pragma unroll
    for (int p = 0; p < 4; ++p) {
      int c0 = ((t & 3) + 4 * p) * 4;
      __align__(8) unsigned short hv[4];
#pragma unroll
      for (int j = 0; j < 4; ++j) hv[j] = f2h(Tt[l_l][c0 + j]);
      size_t base = ((size_t)b * LL + lg + l_l) * CDF + cg + c0;
      *reinterpret_cast<int2*>(&ct[base]) = *reinterpret_cast<int2*>(hv);
    }
  }
}

// ---------------------------------------------------------------------------
// K1 (MFMA fp16, 3-deep): M16 = wc*W^T. grid 512: (bh, nh-half of 128c).
// 4 waves x (64i x 32c). BK=32, 32 steps. 3 GLDS16/wave/stage, 3x12KB bufs.
// ---------------------------------------------------------------------------
__device__ __forceinline__ void k1_stage(short* dst,
                                         const short* gA, const short* gB,
                                         int wave, int lane, int k0) {
#pragma unroll
  for (int j = 0; j < 3; ++j) {
    int inst = wave * 3 + j;               // 0..11
    if (inst < 4) {
      int rb = inst * 16;
      int r  = rb + (lane >> 2);
      int gc = (lane & 3) ^ ((r >> 1) & 3);
      GLDS16(gA + (size_t)r * SSZ + k0 + gc * 8, dst + rb * 32);
    } else {
      int rb = (inst - 4) * 16;
      int r  = rb + (lane >> 2);
      int gc = (lane & 3) ^ ((r >> 1) & 3);
      GLDS16(gB + (size_t)r * SSZ + k0 + gc * 8, dst + 2048 + rb * 32);
    }
  }
}

__global__ __launch_bounds__(256) void k1_mfma(const unsigned short* __restrict__ wc16,
                                               const unsigned short* __restrict__ Wt16,
                                               unsigned short* __restrict__ M16) {
  __shared__ __align__(16) short S[3 * 6144];   // 36 KB

  int blk = blockIdx.x;
  int bh = blk >> 1, nh = blk & 1;
  int b = bh >> 3, h = bh & 7;
  int t = threadIdx.x;
  int lane = t & 63, wave = t >> 6;
  int ln15 = lane & 15, kh = lane >> 4;

  const short* gA = (const short*)wc16 + (size_t)b * IDF * SSZ;
  const short* gB = (const short*)Wt16 + (size_t)(h * CDF + nh * 128) * SSZ;

  int offA[4], offB[2];
#pragma unroll
  for (int r = 0; r < 4; ++r) {
    int row = r * 16 + ln15;
    offA[r] = row * 32 + ((kh ^ ((row >> 1) & 3)) * 8);
  }
#pragma unroll
  for (int c = 0; c < 2; ++c) {
    int row = wave * 32 + c * 16 + ln15;
    offB[c] = 2048 + row * 32 + ((kh ^ ((row >> 1) & 3)) * 8);
  }

  f32x4 acc[4][2] = {};
  k1_stage(&S[0],        gA, gB, wave, lane, 0);
  k1_stage(&S[6144],     gA, gB, wave, lane, 32);
  k1_stage(&S[2 * 6144], gA, gB, wave, lane, 64);
  int cur = 0;

  const int NSTEP = 32;
#pragma unroll 1
  for (int ks = 0; ks < NSTEP; ++ks) {
    short* Sc = &S[cur * 6144];
    WAIT_ENTER3(6, 3)
    half8v fa[4], fb[2];
#pragma unroll
    for (int r = 0; r < 4; ++r)
      fa[r] = *reinterpret_cast<const half8v*>(&Sc[offA[r]]);
#pragma unroll
    for (int c = 0; c < 2; ++c)
      fb[c] = *reinterpret_cast<const half8v*>(&Sc[offB[c]]);
    __builtin_amdgcn_s_setprio(1);
#pragma unroll
    for (int r = 0; r < 4; ++r)
#pragma unroll
      for (int c = 0; c < 2; ++c)
        acc[r][c] = __builtin_amdgcn_mfma_f32_16x16x32_f16(fa[r], fb[c], acc[r][c], 0, 0, 0);
    __builtin_amdgcn_s_setprio(0);
    BAR_EXIT()
    if (ks + 3 < NSTEP)
      k1_stage(Sc, gA, gB, wave, lane, (ks + 3) * 32);
    cur = (cur == 2) ? 0 : cur + 1;
  }

  size_t obase = (size_t)bh * IDF * CDF + nh * 128;
  int rowq = (lane >> 4) * 4;
#pragma unroll
  for (int r = 0; r < 4; ++r)
#pragma unroll
    for (int c = 0; c < 2; ++c)
#pragma unroll
      for (int reg = 0; reg < 4; ++reg) {
        size_t idx = obase + (size_t)(r * 16 + rowq + reg) * CDF + wave * 32 + c * 16 + ln15;
        M16[idx] = f2h(acc[r][c][reg]);
      }
}

// ---------------------------------------------------------------------------
// K2 (MFMA fp16 + fused softmax, 3-deep): P = softmax_l(M*cT^T).
// grid 256 (bh), 512 thr = 8 waves x (64i x 32l). K=256, BK=32, 8 steps.
// Stage: A(4) + B(16) + A-dup(4, wave-uniform vmcnt) = 24 insts = 3/wave.
// ---------------------------------------------------------------------------
__device__ __forceinline__ void k2_stage(short* dst,
                                         const short* gM, const short* gT,
                                         int wave, int lane, int k0) {
#pragma unroll
  for (int j = 0; j < 3; ++j) {
    int inst = wave * 3 + j;               // 0..23
    const short* src; int tile_off, rb;
    if (inst < 4)       { src = gM; tile_off = 0;     rb = inst * 16; }
    else if (inst < 20) { src = gT; tile_off = 2048;  rb = (inst - 4) * 16; }
    else                { src = gM; tile_off = 10240; rb = (inst - 20) * 16; } // dup
    int r  = rb + (lane >> 2);
    int gc = (lane & 3) ^ ((r >> 1) & 3);
    GLDS16(src + (size_t)r * CDF + k0 + gc * 8, dst + tile_off + rb * 32);
  }
}

__global__ __launch_bounds__(512) void k_attn(const unsigned short* __restrict__ M16,
                                              const unsigned short* __restrict__ cT16,
                                              unsigned short* __restrict__ P16) {
  __shared__ __align__(16) short S[3 * 12288];   // 72 KB

  int bh = blockIdx.x;
  int b = bh >> 3;
  int t = threadIdx.x;
  int lane = t & 63, wave = t >> 6;             // wave 0..7
  int ln15 = lane & 15, kh = lane >> 4;

  const short* gM = (const short*)M16 + (size_t)bh * IDF * CDF;
  const short* gT = (const short*)cT16 + (size_t)b * LL * CDF;

  int offA[4], offB[2];
#pragma unroll
  for (int r = 0; r < 4; ++r) {
    int row = r * 16 + ln15;
    offA[r] = row * 32 + ((kh ^ ((row >> 1) & 3)) * 8);
  }
#pragma unroll
  for (int c = 0; c < 2; ++c) {
    int row = wave * 32 + c * 16 + ln15;       // 0..255
    offB[c] = 2048 + row * 32 + ((kh ^ ((row >> 1) & 3)) * 8);
  }

  f32x4 acc[4][2] = {};
  k2_stage(&S[0],         gM, gT, wave, lane, 0);
  k2_stage(&S[12288],     gM, gT, wave, lane, 32);
  k2_stage(&S[2 * 12288], gM, gT, wave, lane, 64);
  int cur = 0;

  const int NSTEP = 8;
#pragma unroll 1
  for (int ks = 0; ks < NSTEP; ++ks) {
    short* Sc = &S[cur * 12288];
    WAIT_ENTER3(6, 3)
    half8v fa[4], fb[2];
#pragma unroll
    for (int r = 0; r < 4; ++r)
      fa[r] = *reinterpret_cast<const half8v*>(&Sc[offA[r]]);
#pragma unroll
    for (int c = 0; c < 2; ++c)
      fb[c] = *reinterpret_cast<const half8v*>(&Sc[offB[c]]);
    __builtin_amdgcn_s_setprio(1);
#pragma unroll
    for (int r = 0; r < 4; ++r)
#pragma unroll
      for (int c = 0; c < 2; ++c)
        acc[r][c] = __builtin_amdgcn_mfma_f32_16x16x32_f16(fa[r], fb[c], acc[r][c], 0, 0, 0);
    __builtin_amdgcn_s_setprio(0);
    BAR_EXIT()
    if (ks + 3 < NSTEP)
      k2_stage(Sc, gM, gT, wave, lane, (ks + 3) * 32);
    cur = (cur == 2) ? 0 : cur + 1;
  }

  // ---- fused softmax over l (cols). row = r*16+(lane>>4)*4+reg,
  //      col = wave*32 + c*16 + (lane&15). pm[row][w] partials in LDS.
  float* pm = reinterpret_cast<float*>(&S[0]);   // 64*8 floats
  int rowq = (lane >> 4) * 4;
  float gmax[4][4], ginv[4][4];
#pragma unroll
  for (int r = 0; r < 4; ++r)
#pragma unroll
    for (int reg = 0; reg < 4; ++reg) {
      float m = fmaxf(acc[r][0][reg], acc[r][1][reg]);
#pragma unroll
      for (int msk = 8; msk >= 1; msk >>= 1) m = fmaxf(m, __shfl_xor(m, msk, 64));
      if (ln15 == 0) pm[(r * 16 + rowq + reg) * 8 + wave] = m;
    }
  __syncthreads();
#pragma unroll
  for (int r = 0; r < 4; ++r)
#pragma unroll
    for (int reg = 0; reg < 4; ++reg) {
      int row = r * 16 + rowq + reg;
      float4 p0 = *reinterpret_cast<const float4*>(&pm[row * 8]);
      float4 p1 = *reinterpret_cast<const float4*>(&pm[row * 8 + 4]);
      gmax[r][reg] = fmaxf(fmaxf(fmaxf(p0.x, p0.y), fmaxf(p0.z, p0.w)),
                           fmaxf(fmaxf(p1.x, p1.y), fmaxf(p1.z, p1.w)));
    }
  __syncthreads();
#pragma unroll
  for (int r = 0; r < 4; ++r)
#pragma unroll
    for (int reg = 0; reg < 4; ++reg) {
      acc[r][0][reg] = __expf(acc[r][0][reg] - gmax[r][reg]);
      acc[r][1][reg] = __expf(acc[r][1][reg] - gmax[r][reg]);
      float s = acc[r][0][reg] + acc[r][1][reg];
#pragma unroll
      for (int msk = 8; msk >= 1; msk >>= 1) s += __shfl_xor(s, msk, 64);
      if (ln15 == 0) pm[(r * 16 + rowq + reg) * 8 + wave] = s;
    }
  __syncthreads();
#pragma unroll
  for (int r = 0; r < 4; ++r)
#pragma unroll
    for (int reg = 0; reg < 4; ++reg) {
      int row = r * 16 + rowq + reg;
      float4 p0 = *reinterpret_cast<const float4*>(&pm[row * 8]);
      float4 p1 = *reinterpret_cast<const float4*>(&pm[row * 8 + 4]);
      ginv[r][reg] = 1.f / (p0.x + p0.y + p0.z + p0.w + p1.x + p1.y + p1.z + p1.w);
    }
  size_t obase = (size_t)bh * IDF * LL;
#pragma unroll
  for (int r = 0; r < 4; ++r)
#pragma unroll
    for (int c = 0; c < 2; ++c)
#pragma unroll
      for (int reg = 0; reg < 4; ++reg) {
        float p = acc[r][c][reg] * ginv[r][reg];
        size_t idx = obase + (size_t)(r * 16 + rowq + reg) * LL + wave * 32 + c * 16 + ln15;
        P16[idx] = f2h(p);
      }
}

// ---------------------------------------------------------------------------
// K3 (MFMA fp16, 3-deep): N2[b][i][h*256+c] = sum_l P*ctx.
// ---------------------------------------------------------------------------
__device__ __forceinline__ void k3_stage(short* dst,
                                         const short* gP, const short* gC,
                                         int wave, int lane, int k0) {
#pragma unroll
  for (int j = 0; j < 3; ++j) {
    int inst = wave * 3 + j;               // 0..11
    const short* src; int tile_off, rb;
    if (inst < 4) { src = gP; tile_off = 0;    rb = inst * 16; }
    else          { src = gC; tile_off = 2048; rb = (inst - 4) * 16; }
    int r  = rb + (lane >> 2);
    int gc = (lane & 3) ^ ((r >> 1) & 3);
    GLDS16(src + (size_t)r * LL + k0 + gc * 8, dst + tile_off + rb * 32);
  }
}

__global__ __launch_bounds__(256) void k_N2(const unsigned short* __restrict__ P16,
                                            const unsigned short* __restrict__ ctx16,
                                            unsigned short* __restrict__ N216) {
  __shared__ __align__(16) short S[3 * 6144];   // 36 KB

  int blk = blockIdx.x;
  int bh = blk >> 1, ch = blk & 1;
  int b = bh >> 3, h = bh & 7;
  int cgbase = ch * 128;
  int t = threadIdx.x;
  int lane = t & 63, wave = t >> 6;
  int ln15 = lane & 15, kh = lane >> 4;

  const short* gP = (const short*)P16 + (size_t)bh * IDF * LL;
  const short* gC = (const short*)ctx16 + (size_t)(b * CDF + cgbase) * LL;

  int offA[4], offB[2];
#pragma unroll
  for (int r = 0; r < 4; ++r) {
    int row = r * 16 + ln15;
    offA[r] = row * 32 + ((kh ^ ((row >> 1) & 3)) * 8);
  }
#pragma unroll
  for (int c = 0; c < 2; ++c) {
    int row = wave * 32 + c * 16 + ln15;
    offB[c] = 2048 + row * 32 + ((kh ^ ((row >> 1) & 3)) * 8);
  }

  f32x4 acc[4][2] = {};
  k3_stage(&S[0],        gP, gC, wave, lane, 0);
  k3_stage(&S[6144],     gP, gC, wave, lane, 32);
  k3_stage(&S[2 * 6144], gP, gC, wave, lane, 64);
  int cur = 0;

  const int NSTEP = 8;
#pragma unroll 1
  for (int ks = 0; ks < NSTEP; ++ks) {
    short* Sc = &S[cur * 6144];
    WAIT_ENTER3(6, 3)
    half8v fa[4], fb[2];
#pragma unroll
    for (int r = 0; r < 4; ++r)
      fa[r] = *reinterpret_cast<const half8v*>(&Sc[offA[r]]);
#pragma unroll
    for (int c = 0; c < 2; ++c)
      fb[c] = *reinterpret_cast<const half8v*>(&Sc[offB[c]]);
    __builtin_amdgcn_s_setprio(1);
#pragma unroll
    for (int r = 0; r < 4; ++r)
#pragma unroll
      for (int c = 0; c < 2; ++c)
        acc[r][c] = __builtin_amdgcn_mfma_f32_16x16x32_f16(fa[r], fb[c], acc[r][c], 0, 0, 0);
    __builtin_amdgcn_s_setprio(0);
    BAR_EXIT()
    if (ks + 3 < NSTEP)
      k3_stage(Sc, gP, gC, wave, lane, (ks + 3) * 32);
    cur = (cur == 2) ? 0 : cur + 1;
  }

  size_t base = (size_t)b * IDF * KHC + h * CDF + cgbase;
  int rowq = (lane >> 4) * 4;
#pragma unroll
  for (int r = 0; r < 4; ++r)
#pragma unroll
    for (int c = 0; c < 2; ++c)
#pragma unroll
      for (int reg = 0; reg < 4; ++reg) {
        size_t idx = base + (size_t)(r * 16 + rowq + reg) * KHC + wave * 32 + c * 16 + ln15;
        N216[idx] = f2h(acc[r][c][reg]);
      }
}

// ---------------------------------------------------------------------------
// K4 (MFMA fp16, 3-deep): ctx_out[b][i][o] = sum_{hc} N2*W.
// ---------------------------------------------------------------------------
__device__ __forceinline__ void k4_stage(short* dst,
                                         const short* gA, const short* gB,
                                         int wave, int lane, int kk0, int obase) {
  int h4 = kk0 >> 8, cb = kk0 & 255;
#pragma unroll
  for (int j = 0; j < 3; ++j) {
    int inst = wave * 3 + j;               // 0..11
    if (inst < 4) {
      int rb = inst * 16;
      int r  = rb + (lane >> 2);
      int gc = (lane & 3) ^ ((r >> 1) & 3);
      GLDS16(gA + (size_t)r * KHC + kk0 + gc * 8, dst + rb * 32);
    } else {
      int rb = (inst - 4) * 16;
      int r  = rb + (lane >> 2);
      int gc = (lane & 3) ^ ((r >> 1) & 3);
      GLDS16(gB + (size_t)(h4 * SSZ + obase + r) * CDF + cb + gc * 8,
             dst + 2048 + rb * 32);
    }
  }
}

__global__ __launch_bounds__(256) void k4_mfma(const unsigned short* __restrict__ N216,
                                               const unsigned short* __restrict__ W16,
                                               float* __restrict__ out0,
                                               float* __restrict__ out1) {
  __shared__ __align__(16) short S[3 * 6144];   // 36 KB

  int blk = blockIdx.x;
  int g = blk >> 8;
  int r8 = blk & 255;
  int b = r8 >> 3, ot = r8 & 7;
  int obase = ot * 128;
  int t = threadIdx.x;
  int lane = t & 63, wave = t >> 6;
  int ln15 = lane & 15, kh = lane >> 4;

  const short* gA = (const short*)N216 + (size_t)b * IDF * KHC;
  const short* gB = (const short*)W16;

  int offA[4], offB[2];
#pragma unroll
  for (int r = 0; r < 4; ++r) {
    int row = r * 16 + ln15;
    offA[r] = row * 32 + ((kh ^ ((row >> 1) & 3)) * 8);
  }
#pragma unroll
  for (int c = 0; c < 2; ++c) {
    int row = wave * 32 + c * 16 + ln15;
    offB[c] = 2048 + row * 32 + ((kh ^ ((row >> 1) & 3)) * 8);
  }

  int kbase = g * (KHC / 2);
  f32x4 acc[4][2] = {};

  k4_stage(&S[0],        gA, gB, wave, lane, kbase, obase);
  k4_stage(&S[6144],     gA, gB, wave, lane, kbase + 32, obase);
  k4_stage(&S[2 * 6144], gA, gB, wave, lane, kbase + 64, obase);
  int cur = 0;

  const int NSTEP = 32;
#pragma unroll 1
  for (int ks = 0; ks < NSTEP; ++ks) {
    short* Sc = &S[cur * 6144];
    WAIT_ENTER3(6, 3)
    half8v fa[4], fb[2];
#pragma unroll
    for (int r = 0; r < 4; ++r)
      fa[r] = *reinterpret_cast<const half8v*>(&Sc[offA[r]]);
#pragma unroll
    for (int c = 0; c < 2; ++c)
      fb[c] = *reinterpret_cast<const half8v*>(&Sc[offB[c]]);
    __builtin_amdgcn_s_setprio(1);
#pragma unroll
    for (int r = 0; r < 4; ++r)
#pragma unroll
      for (int c = 0; c < 2; ++c)
        acc[r][c] = __builtin_amdgcn_mfma_f32_16x16x32_f16(fa[r], fb[c], acc[r][c], 0, 0, 0);
    __builtin_amdgcn_s_setprio(0);
    BAR_EXIT()
    if (ks + 3 < NSTEP)
      k4_stage(Sc, gA, gB, wave, lane, kbase + (ks + 3) * 32, obase);
    cur = (cur == 2) ? 0 : cur + 1;
  }

  float* dst = (g == 0) ? out0 : out1;
  int rowq = (lane >> 4) * 4;
#pragma unroll
  for (int r = 0; r < 4; ++r)
#pragma unroll
    for (int c = 0; c < 2; ++c)
#pragma unroll
      for (int reg = 0; reg < 4; ++reg)
        dst[((size_t)b * IDF + r * 16 + rowq + reg) * SSZ +
            obase + wave * 32 + c * 16 + ln15] = acc[r][c][reg];
}

// ---------------------------------------------------------------------------
// Fused epilogue: blocks 0..127 -> attn_out[b][l][i] = sum_h P16[bh][i][l];
// blocks 128..2175 -> out[idx] += Pbuf[idx] (k4 g=1 partial).
// ---------------------------------------------------------------------------
__global__ __launch_bounds__(256) void k_epi(const unsigned short* __restrict__ P16,
                                             float* __restrict__ outa,
                                             float* __restrict__ out,
                                             const float* __restrict__ Pbuf) {
  int blk0 = blockIdx.x;
  int tid = threadIdx.x;
  if (blk0 >= 128) {                       // out += Pbuf
    int idx = (blk0 - 128) * 256 + tid;
    float4 a = reinterpret_cast<float4*>(out)[idx];
    float4 p = reinterpret_cast<const float4*>(Pbuf)[idx];
    a.x += p.x; a.y += p.y; a.z += p.z; a.w += p.w;
    reinterpret_cast<float4*>(out)[idx] = a;
    return;
  }
  __shared__ float T[64][65];
  int b = blk0 >> 2, lt = blk0 & 3;
  int l0 = lt * 64;
  float4 acc[4];
#pragma unroll
  for (int p = 0; p < 4; ++p) acc[p] = make_float4(0.f, 0.f, 0.f, 0.f);
  for (int h = 0; h < NH; ++h) {
    size_t src = (size_t)(b * NH + h) * IDF * LL;
#pragma unroll
    for (int p = 0; p < 4; ++p) {
      int f = tid + p * 256;
      int i = f >> 4, lc = (f & 15) * 4;
      ushort4 u = *reinterpret_cast<const ushort4*>(&P16[src + i * LL + l0 + lc]);
      acc[p].x += h2f(u.x); acc[p].y += h2f(u.y);
      acc[p].z += h2f(u.z); acc[p].w += h2f(u.w);
    }
  }
#pragma unroll
  for (int p = 0; p < 4; ++p) {
    int f = tid + p * 256;
    int i = f >> 4, lc = (f & 15) * 4;
    T[i][lc + 0] = acc[p].x; T[i][lc + 1] = acc[p].y;
    T[i][lc + 2] = acc[p].z; T[i][lc + 3] = acc[p].w;
  }
  __syncthreads();
#pragma unroll
  for (int p = 0; p < 4; ++p) {
    int f = tid + p * 256;
    int lr = f >> 4, ic = (f & 15) * 4;
    float4 v = {T[ic + 0][lr], T[ic + 1][lr], T[ic + 2][lr], T[ic + 3][lr]};
    *reinterpret_cast<float4*>(&outa[((size_t)b * LL + l0 + lr) * IDF + ic]) = v;
  }
}

// ---------------------------------------------------------------------------
extern "C" void kernel_launch(void* const* d_in, const int* in_sizes, int n_in,
                              void* d_out, int out_size, void* d_ws, size_t ws_size,
                              hipStream_t stream) {
  const float* wc  = (const float*)d_in[0];   // [32][64][1024]
  const float* ctx = (const float*)d_in[1];   // [32][256][256]
  const float* W   = (const float*)d_in[2];   // [8][1024][256]
  float* out = (float*)d_out;

  const size_t NE = 2097152;   // elems of wc == W == ctx
  const size_t NM = 4194304;   // elems of M == P == N2
  unsigned short* p = (unsigned short*)d_ws;
  unsigned short *wc16 = p;   p += NE;
  unsigned short *Wt16 = p;   p += NE;
  unsigned short *W16  = p;   p += NE;
  unsigned short *ctx16 = p;  p += NE;
  unsigned short *cT16 = p;   p += NE;
  unsigned short *M16  = p;   p += NM;
  unsigned short *P16  = p;   p += NM;
  unsigned short *N216 = p;   p += NM;
  float* Pbuf = (float*)p;    // 2.1M floats

  k_split_all <<<6144, 256, 0, stream>>>(wc, W, ctx, wc16, W16, ctx16);
  k_split_T   <<<1024, 256, 0, stream>>>(W, ctx, Wt16, cT16);
  k1_mfma     <<<BB * NH * 2, 256, 0, stream>>>(wc16, Wt16, M16);
  k_attn      <<<BB * NH, 512, 0, stream>>>(M16, cT16, P16);
  k_N2        <<<BB * NH * 2, 256, 0, stream>>>(P16, ctx16, N216);
  k4_mfma     <<<512, 256, 0, stream>>>(N216, W16, out, Pbuf);
  k_epi       <<<2176, 256, 0, stream>>>(P16, out + (size_t)BB * IDF * SSZ, out, Pbuf);
}

// Round 17
// 79.784 us; speedup vs baseline: 4.7849x; 1.0549x over previous
//
#include <hip/hip_runtime.h>
#include <hip/hip_bf16.h>

#define BB 32
#define IDF 64
#define CDF 256
#define SSZ 1024
#define NH 8
#define LL 256
#define KHC 2048   // NH*CDF

typedef __attribute__((ext_vector_type(8))) _Float16 half8v;   // 8 fp16
typedef __attribute__((ext_vector_type(4))) float f32x4;       // MFMA acc

// async global->LDS, 16B per lane, LDS dest = wave-uniform base + lane*16
#define GLDS16(g, l) __builtin_amdgcn_global_load_lds(                        \
    (const __attribute__((address_space(1))) void*)(g),                       \
    (__attribute__((address_space(3))) void*)(l), 16, 0, 0)

// 3-deep pipeline phase entry (T3+T4): wait only for the CURRENT buffer's
// DMA, leaving the next TWO stages in flight. Never vmcnt(0) mid-loop.
#define WAIT_ENTER3(NFULL, NHALF)                                             \
  { if (ks < NSTEP - 2)                                                       \
      asm volatile("s_waitcnt vmcnt(" #NFULL ")" ::: "memory");               \
    else if (ks == NSTEP - 2)                                                 \
      asm volatile("s_waitcnt vmcnt(" #NHALF ")" ::: "memory");               \
    else                                                                      \
      asm volatile("s_waitcnt vmcnt(0)" ::: "memory");                        \
    __builtin_amdgcn_s_barrier();                                             \
    __builtin_amdgcn_sched_barrier(0); }
#define BAR_EXIT()                                                            \
  { __builtin_amdgcn_sched_barrier(0);                                        \
    __builtin_amdgcn_s_barrier();                                             \
    __builtin_amdgcn_sched_barrier(0); }
// LDS-only barrier: drains ds ops but leaves global_load_lds (vmcnt) in
// flight — lets phase-3 prefetch ride through the softmax.
#define LDS_BAR()                                                             \
  { asm volatile("s_waitcnt lgkmcnt(0)" ::: "memory");                        \
    __builtin_amdgcn_s_barrier();                                             \
    __builtin_amdgcn_sched_barrier(0); }

__device__ inline unsigned short f2h(float x) {
  _Float16 h = (_Float16)x;
  return *reinterpret_cast<unsigned short*>(&h);
}
__device__ inline float h2f(unsigned short u) {
  _Float16 h = *reinterpret_cast<_Float16*>(&u);
  return (float)h;
}

// ---------------------------------------------------------------------------
// Fused prep: blocks 0..6143 elementwise casts (wc,W,ctx -> fp16);
// blocks 6144..6655 W[h][o][c]->Wt16[h][c][o]; 6656..7679... (512+512=1024)
// blocks 6144..6655 -> Wt16; 6656..7167 -> cT16.
// ---------------------------------------------------------------------------
__global__ __launch_bounds__(256) void k_prep(const float* __restrict__ wc,
                                              const float* __restrict__ W,
                                              const float* __restrict__ ctx,
                                              unsigned short* __restrict__ wc16,
                                              unsigned short* __restrict__ W16,
                                              unsigned short* __restrict__ ctx16,
                                              unsigned short* __restrict__ Wt16,
                                              unsigned short* __restrict__ cT16) {
  __shared__ float Tt[64][65];
  int blk0 = blockIdx.x;
  int t = threadIdx.x;
  if (blk0 < 6144) {                       // elementwise casts
    int sel = blk0 >> 11;
    int idx = ((blk0 & 2047) * 256 + t) * 4;
    const float* src = (sel == 0) ? wc : (sel == 1) ? W : ctx;
    unsigned short* d = (sel == 0) ? wc16 : (sel == 1) ? W16 : ctx16;
    float4 v = *reinterpret_cast<const float4*>(&src[idx]);
    __align__(8) unsigned short h[4] = {f2h(v.x), f2h(v.y), f2h(v.z), f2h(v.w)};
    *reinterpret_cast<int2*>(&d[idx]) = *reinterpret_cast<int2*>(h);
  } else if (blk0 < 6656) {                // W -> Wt16 [h][c][o]
    int blk = blk0 - 6144;
    int h = blk >> 6, ot = (blk >> 2) & 15, cq = blk & 3;
    int og = ot * 64, cg = cq * 64;
    int o_l = t >> 4, c4 = (t & 15) * 4;
#pragma unroll
    for (int p = 0; p < 4; ++p) {
      int o = o_l + 16 * p;
      float4 v = *reinterpret_cast<const float4*>(
          &W[((size_t)h * SSZ + og + o) * CDF + cg + c4]);
      Tt[c4 + 0][o] = v.x; Tt[c4 + 1][o] = v.y;
      Tt[c4 + 2][o] = v.z; Tt[c4 + 3][o] = v.w;
    }
    __syncthreads();
    int c_l = t >> 2;
#pragma unroll
    for (int p = 0; p < 4; ++p) {
      int o0 = ((t & 3) + 4 * p) * 4;
      __align__(8) unsigned short hv[4];
#pragma unroll
      for (int j = 0; j < 4; ++j) hv[j] = f2h(Tt[c_l][o0 + j]);
      size_t base = ((size_t)h * CDF + cg + c_l) * SSZ + og + o0;
      *reinterpret_cast<int2*>(&Wt16[base]) = *reinterpret_cast<int2*>(hv);
    }
  } else {                                 // ctx -> cT16 [b][l][c]
    int blk = blk0 - 6656;
    int b = blk >> 4, cq = (blk >> 2) & 3, lt = blk & 3;
    int cg = cq * 64, lg = lt * 64;
    int c_l = t >> 4, l4 = (t & 15) * 4;
#pragma unroll
    for (int p = 0; p < 4; ++p) {
      int c = c_l + 16 * p;
      float4 v = *reinterpret_cast<const float4*>(
          &ctx[((size_t)b * CDF + cg + c) * LL + lg + l4]);
      Tt[l4 + 0][c] = v.x; Tt[l4 + 1][c] = v.y;
      Tt[l4 + 2][c] = v.z; Tt[l4 + 3][c] = v.w;
    }
    __syncthreads();
    int l_l = t >> 2;
#pragma unroll
    for (int p = 0; p < 4; ++p) {
      int c0 = ((t & 3) + 4 * p) * 4;
      __align__(8) unsigned short hv[4];
#pragma unroll
      for (int j = 0; j < 4; ++j) hv[j] = f2h(Tt[l_l][c0 + j]);
      size_t base = ((size_t)b * LL + lg + l_l) * CDF + cg + c0;
      *reinterpret_cast<int2*>(&cT16[base]) = *reinterpret_cast<int2*>(hv);
    }
  }
}

// ---------------------------------------------------------------------------
// k123: fused K1+K2+K3 per bh. grid 256, 512 thr = 8 waves x (64i x 32col).
// Phase 1: M = wc x Wt^T (K=1024, 32 steps)  -> M_lds (fp16, XOR(row&7))
// Phase 2: logits = M_lds x cT^T (K=256, 8)  -> softmax -> P (M_lds + global)
// Phase 3: N2 = P x ctx^T (K=256, 8)         -> N216 global
// LDS: staging 3x24KB (A 2048 + B 8192 + dup 2048 shorts) + M_lds 32KB = 104KB
// ---------------------------------------------------------------------------
__device__ __forceinline__ void st_p1(short* dst, const short* gA, const short* gB,
                                      int wave, int lane, int k0) {
#pragma unroll
  for (int j = 0; j < 3; ++j) {
    int inst = wave * 3 + j;               // 0..23
    const short* src; int toff, rb;
    if (inst < 4)       { src = gA; toff = 0;     rb = inst * 16; }
    else if (inst < 20) { src = gB; toff = 2048;  rb = (inst - 4) * 16; }
    else                { src = gA; toff = 10240; rb = (inst - 20) * 16; } // dup
    int r  = rb + (lane >> 2);
    int gc = (lane & 3) ^ ((r >> 1) & 3);
    GLDS16(src + (size_t)r * SSZ + k0 + gc * 8, dst + toff + rb * 32);
  }
}
__device__ __forceinline__ void st_pB(short* dst, const short* gB, int ld,
                                      int wave, int lane, int k0) {
#pragma unroll
  for (int j = 0; j < 2; ++j) {
    int inst = wave * 2 + j;               // 0..15
    int rb = inst * 16;
    int r  = rb + (lane >> 2);
    int gc = (lane & 3) ^ ((r >> 1) & 3);
    GLDS16(gB + (size_t)r * ld + k0 + gc * 8, dst + 2048 + rb * 32);
  }
}

__global__ __launch_bounds__(512) void k123(const unsigned short* __restrict__ wc16,
                                            const unsigned short* __restrict__ Wt16,
                                            const unsigned short* __restrict__ cT16,
                                            const unsigned short* __restrict__ ctx16,
                                            unsigned short* __restrict__ P16,
                                            unsigned short* __restrict__ N216) {
  __shared__ __align__(16) short S[3 * 12288 + 16384];   // 104 KB
  short* M_lds = &S[3 * 12288];                           // 64 x 256 fp16

  int bh = blockIdx.x;
  int b = bh >> 3, h = bh & 7;
  int t = threadIdx.x;
  int lane = t & 63, wave = t >> 6;             // wave 0..7
  int ln15 = lane & 15, kh = lane >> 4;
  int rowq = (lane >> 4) * 4;

  const short* gA = (const short*)wc16 + (size_t)b * IDF * SSZ;
  const short* gB = (const short*)Wt16 + (size_t)h * CDF * SSZ;
  const short* gT = (const short*)cT16 + (size_t)b * LL * CDF;
  const short* gC = (const short*)ctx16 + (size_t)b * CDF * LL;

  int offA[4], offB[2], rowM[4], rmask[4];
#pragma unroll
  for (int r = 0; r < 4; ++r) {
    int row = r * 16 + ln15;
    offA[r] = row * 32 + ((kh ^ ((row >> 1) & 3)) * 8);
    rowM[r] = row * 256;
    rmask[r] = row & 7;
  }
#pragma unroll
  for (int c = 0; c < 2; ++c) {
    int row = wave * 32 + c * 16 + ln15;       // 0..255
    offB[c] = 2048 + row * 32 + ((kh ^ ((row >> 1) & 3)) * 8);
  }

  f32x4 acc[4][2] = {};

  // ===== Phase 1: M = wc x Wt^T, K=1024 =====
  st_p1(&S[0],         gA, gB, wave, lane, 0);
  st_p1(&S[12288],     gA, gB, wave, lane, 32);
  st_p1(&S[2 * 12288], gA, gB, wave, lane, 64);
  int cur = 0;
  {
    const int NSTEP = 32;
#pragma unroll 1
    for (int ks = 0; ks < NSTEP; ++ks) {
      short* Sc = &S[cur * 12288];
      WAIT_ENTER3(6, 3)
      half8v fa[4], fb[2];
#pragma unroll
      for (int r = 0; r < 4; ++r)
        fa[r] = *reinterpret_cast<const half8v*>(&Sc[offA[r]]);
#pragma unroll
      for (int c = 0; c < 2; ++c)
        fb[c] = *reinterpret_cast<const half8v*>(&Sc[offB[c]]);
      __builtin_amdgcn_s_setprio(1);
#pragma unroll
      for (int r = 0; r < 4; ++r)
#pragma unroll
        for (int c = 0; c < 2; ++c)
          acc[r][c] = __builtin_amdgcn_mfma_f32_16x16x32_f16(fa[r], fb[c], acc[r][c], 0, 0, 0);
      __builtin_amdgcn_s_setprio(0);
      BAR_EXIT()
      if (ks + 3 < NSTEP)
        st_p1(Sc, gA, gB, wave, lane, (ks + 3) * 32);
      cur = (cur == 2) ? 0 : cur + 1;
    }
  }
  // M -> M_lds (fp16, chunk-XOR(row&7)); vmcnt already 0 after last step.
#pragma unroll
  for (int r = 0; r < 4; ++r)
#pragma unroll
    for (int c = 0; c < 2; ++c)
#pragma unroll
      for (int reg = 0; reg < 4; ++reg) {
        int row = r * 16 + rowq + reg;
        int col = wave * 32 + c * 16 + ln15;
        M_lds[row * 256 + ((((col >> 3) ^ (row & 7)) << 3) + (col & 7))] =
            (short)f2h(acc[r][c][reg]);
      }
  LDS_BAR()

  // ===== Phase 2: logits = M x cT^T, K=256. A from M_lds. =====
#pragma unroll
  for (int r = 0; r < 4; ++r)
#pragma unroll
    for (int c = 0; c < 2; ++c) acc[r][c] = (f32x4){0.f, 0.f, 0.f, 0.f};
  st_pB(&S[0],         gT, CDF, wave, lane, 0);
  st_pB(&S[12288],     gT, CDF, wave, lane, 32);
  st_pB(&S[2 * 12288], gT, CDF, wave, lane, 64);
  cur = 0;
  {
    const int NSTEP = 8;
#pragma unroll 1
    for (int ks = 0; ks < NSTEP; ++ks) {
      short* Sc = &S[cur * 12288];
      WAIT_ENTER3(4, 2)
      half8v fa[4], fb[2];
#pragma unroll
      for (int r = 0; r < 4; ++r) {
        int ck = ((ks * 4 + kh) ^ rmask[r]) << 3;
        fa[r] = *reinterpret_cast<const half8v*>(&M_lds[rowM[r] + ck]);
      }
#pragma unroll
      for (int c = 0; c < 2; ++c)
        fb[c] = *reinterpret_cast<const half8v*>(&Sc[offB[c]]);
      __builtin_amdgcn_s_setprio(1);
#pragma unroll
      for (int r = 0; r < 4; ++r)
#pragma unroll
        for (int c = 0; c < 2; ++c)
          acc[r][c] = __builtin_amdgcn_mfma_f32_16x16x32_f16(fa[r], fb[c], acc[r][c], 0, 0, 0);
      __builtin_amdgcn_s_setprio(0);
      BAR_EXIT()
      if (ks + 3 < NSTEP)
        st_pB(Sc, gT, CDF, wave, lane, (ks + 3) * 32);
      cur = (cur == 2) ? 0 : cur + 1;
    }
  }

  // Prefetch phase 3 B (ctx16) BEFORE softmax; softmax uses LDS_BAR only,
  // so these stay in flight underneath it.
  st_pB(&S[0],         gC, LL, wave, lane, 0);
  st_pB(&S[12288],     gC, LL, wave, lane, 32);
  st_pB(&S[2 * 12288], gC, LL, wave, lane, 64);

  // ===== Softmax over l. pm in M_lds region (M is dead). =====
  float* pm = reinterpret_cast<float*>(M_lds);   // 64*8 floats
  float gmax[4][4], ginv[4][4];
#pragma unroll
  for (int r = 0; r < 4; ++r)
#pragma unroll
    for (int reg = 0; reg < 4; ++reg) {
      float m = fmaxf(acc[r][0][reg], acc[r][1][reg]);
#pragma unroll
      for (int msk = 8; msk >= 1; msk >>= 1) m = fmaxf(m, __shfl_xor(m, msk, 64));
      if (ln15 == 0) pm[(r * 16 + rowq + reg) * 8 + wave] = m;
    }
  LDS_BAR()
#pragma unroll
  for (int r = 0; r < 4; ++r)
#pragma unroll
    for (int reg = 0; reg < 4; ++reg) {
      int row = r * 16 + rowq + reg;
      float4 p0 = *reinterpret_cast<const float4*>(&pm[row * 8]);
      float4 p1 = *reinterpret_cast<const float4*>(&pm[row * 8 + 4]);
      gmax[r][reg] = fmaxf(fmaxf(fmaxf(p0.x, p0.y), fmaxf(p0.z, p0.w)),
                           fmaxf(fmaxf(p1.x, p1.y), fmaxf(p1.z, p1.w)));
    }
  LDS_BAR()
#pragma unroll
  for (int r = 0; r < 4; ++r)
#pragma unroll
    for (int reg = 0; reg < 4; ++reg) {
      acc[r][0][reg] = __expf(acc[r][0][reg] - gmax[r][reg]);
      acc[r][1][reg] = __expf(acc[r][1][reg] - gmax[r][reg]);
      float s = acc[r][0][reg] + acc[r][1][reg];
#pragma unroll
      for (int msk = 8; msk >= 1; msk >>= 1) s += __shfl_xor(s, msk, 64);
      if (ln15 == 0) pm[(r * 16 + rowq + reg) * 8 + wave] = s;
    }
  LDS_BAR()
#pragma unroll
  for (int r = 0; r < 4; ++r)
#pragma unroll
    for (int reg = 0; reg < 4; ++reg) {
      int row = r * 16 + rowq + reg;
      float4 p0 = *reinterpret_cast<const float4*>(&pm[row * 8]);
      float4 p1 = *reinterpret_cast<const float4*>(&pm[row * 8 + 4]);
      ginv[r][reg] = 1.f / (p0.x + p0.y + p0.z + p0.w + p1.x + p1.y + p1.z + p1.w);
    }
  LDS_BAR()   // pm fully consumed before P overwrites M_lds

  // P -> global (for epilogue) and -> M_lds (phase-3 A operand)
  size_t pbase = (size_t)bh * IDF * LL;
#pragma unroll
  for (int r = 0; r < 4; ++r)
#pragma unroll
    for (int c = 0; c < 2; ++c)
#pragma unroll
      for (int reg = 0; reg < 4; ++reg) {
        float p = acc[r][c][reg] * ginv[r][reg];
        int row = r * 16 + rowq + reg;
        int col = wave * 32 + c * 16 + ln15;
        unsigned short ph = f2h(p);
        P16[pbase + (size_t)row * LL + col] = ph;
        M_lds[row * 256 + ((((col >> 3) ^ (row & 7)) << 3) + (col & 7))] = (short)ph;
      }
  LDS_BAR()

  // ===== Phase 3: N2 = P x ctx^T, K=256. A from M_lds (P). =====
#pragma unroll
  for (int r = 0; r < 4; ++r)
#pragma unroll
    for (int c = 0; c < 2; ++c) acc[r][c] = (f32x4){0.f, 0.f, 0.f, 0.f};
  cur = 0;
  {
    const int NSTEP = 8;
#pragma unroll 1
    for (int ks = 0; ks < NSTEP; ++ks) {
      short* Sc = &S[cur * 12288];
      WAIT_ENTER3(4, 2)
      half8v fa[4], fb[2];
#pragma unroll
      for (int r = 0; r < 4; ++r) {
        int ck = ((ks * 4 + kh) ^ rmask[r]) << 3;
        fa[r] = *reinterpret_cast<const half8v*>(&M_lds[rowM[r] + ck]);
      }
#pragma unroll
      for (int c = 0; c < 2; ++c)
        fb[c] = *reinterpret_cast<const half8v*>(&Sc[offB[c]]);
      __builtin_amdgcn_s_setprio(1);
#pragma unroll
      for (int r = 0; r < 4; ++r)
#pragma unroll
        for (int c = 0; c < 2; ++c)
          acc[r][c] = __builtin_amdgcn_mfma_f32_16x16x32_f16(fa[r], fb[c], acc[r][c], 0, 0, 0);
      __builtin_amdgcn_s_setprio(0);
      BAR_EXIT()
      if (ks + 3 < NSTEP)
        st_pB(Sc, gC, LL, wave, lane, (ks + 3) * 32);
      cur = (cur == 2) ? 0 : cur + 1;
    }
  }

  size_t nbase = (size_t)b * IDF * KHC + h * CDF;
#pragma unroll
  for (int r = 0; r < 4; ++r)
#pragma unroll
    for (int c = 0; c < 2; ++c)
#pragma unroll
      for (int reg = 0; reg < 4; ++reg) {
        size_t idx = nbase + (size_t)(r * 16 + rowq + reg) * KHC + wave * 32 + c * 16 + ln15;
        N216[idx] = f2h(acc[r][c][reg]);
      }
}

// ---------------------------------------------------------------------------
// K4 (MFMA fp16, 3-deep): ctx_out[b][i][o] = sum_{hc} N2*W. UNCHANGED.
// ---------------------------------------------------------------------------
__device__ __forceinline__ void k4_stage(short* dst,
                                         const short* gA, const short* gB,
                                         int wave, int lane, int kk0, int obase) {
  int h4 = kk0 >> 8, cb = kk0 & 255;
#pragma unroll
  for (int j = 0; j < 3; ++j) {
    int inst = wave * 3 + j;               // 0..11
    if (inst < 4) {
      int rb = inst * 16;
      int r  = rb + (lane >> 2);
      int gc = (lane & 3) ^ ((r >> 1) & 3);
      GLDS16(gA + (size_t)r * KHC + kk0 + gc * 8, dst + rb * 32);
    } else {
      int rb = (inst - 4) * 16;
      int r  = rb + (lane >> 2);
      int gc = (lane & 3) ^ ((r >> 1) & 3);
      GLDS16(gB + (size_t)(h4 * SSZ + obase + r) * CDF + cb + gc * 8,
             dst + 2048 + rb * 32);
    }
  }
}

__global__ __launch_bounds__(256) void k4_mfma(const unsigned short* __restrict__ N216,
                                               const unsigned short* __restrict__ W16,
                                               float* __restrict__ out0,
                                               float* __restrict__ out1) {
  __shared__ __align__(16) short S[3 * 6144];   // 36 KB

  int blk = blockIdx.x;
  int g = blk >> 8;
  int r8 = blk & 255;
  int b = r8 >> 3, ot = r8 & 7;
  int obase = ot * 128;
  int t = threadIdx.x;
  int lane = t & 63, wave = t >> 6;
  int ln15 = lane & 15, kh = lane >> 4;

  const short* gA = (const short*)N216 + (size_t)b * IDF * KHC;
  const short* gB = (const short*)W16;

  int offA[4], offB[2];
#pragma unroll
  for (int r = 0; r < 4; ++r) {
    int row = r * 16 + ln15;
    offA[r] = row * 32 + ((kh ^ ((row >> 1) & 3)) * 8);
  }
#pragma unroll
  for (int c = 0; c < 2; ++c) {
    int row = wave * 32 + c * 16 + ln15;
    offB[c] = 2048 + row * 32 + ((kh ^ ((row >> 1) & 3)) * 8);
  }

  int kbase = g * (KHC / 2);
  f32x4 acc[4][2] = {};

  k4_stage(&S[0],        gA, gB, wave, lane, kbase, obase);
  k4_stage(&S[6144],     gA, gB, wave, lane, kbase + 32, obase);
  k4_stage(&S[2 * 6144], gA, gB, wave, lane, kbase + 64, obase);
  int cur = 0;

  const int NSTEP = 32;
#pragma unroll 1
  for (int ks = 0; ks < NSTEP; ++ks) {
    short* Sc = &S[cur * 6144];
    WAIT_ENTER3(6, 3)
    half8v fa[4], fb[2];
#pragma unroll
    for (int r = 0; r < 4; ++r)
      fa[r] = *reinterpret_cast<const half8v*>(&Sc[offA[r]]);
#pragma unroll
    for (int c = 0; c < 2; ++c)
      fb[c] = *reinterpret_cast<const half8v*>(&Sc[offB[c]]);
    __builtin_amdgcn_s_setprio(1);
#pragma unroll
    for (int r = 0; r < 4; ++r)
#pragma unroll
      for (int c = 0; c < 2; ++c)
        acc[r][c] = __builtin_amdgcn_mfma_f32_16x16x32_f16(fa[r], fb[c], acc[r][c], 0, 0, 0);
    __builtin_amdgcn_s_setprio(0);
    BAR_EXIT()
    if (ks + 3 < NSTEP)
      k4_stage(Sc, gA, gB, wave, lane, kbase + (ks + 3) * 32, obase);
    cur = (cur == 2) ? 0 : cur + 1;
  }

  float* dst = (g == 0) ? out0 : out1;
  int rowq = (lane >> 4) * 4;
#pragma unroll
  for (int r = 0; r < 4; ++r)
#pragma unroll
    for (int c = 0; c < 2; ++c)
#pragma unroll
      for (int reg = 0; reg < 4; ++reg)
        dst[((size_t)b * IDF + r * 16 + rowq + reg) * SSZ +
            obase + wave * 32 + c * 16 + ln15] = acc[r][c][reg];
}

// ---------------------------------------------------------------------------
// Fused epilogue: blocks 0..127 -> attn_out[b][l][i] = sum_h P16[bh][i][l];
// blocks 128..2175 -> out[idx] += Pbuf[idx] (k4 g=1 partial).
// ---------------------------------------------------------------------------
__global__ __launch_bounds__(256) void k_epi(const unsigned short* __restrict__ P16,
                                             float* __restrict__ outa,
                                             float* __restrict__ out,
                                             const float* __restrict__ Pbuf) {
  int blk0 = blockIdx.x;
  int tid = threadIdx.x;
  if (blk0 >= 128) {                       // out += Pbuf
    int idx = (blk0 - 128) * 256 + tid;
    float4 a = reinterpret_cast<float4*>(out)[idx];
    float4 p = reinterpret_cast<const float4*>(Pbuf)[idx];
    a.x += p.x; a.y += p.y; a.z += p.z; a.w += p.w;
    reinterpret_cast<float4*>(out)[idx] = a;
    return;
  }
  __shared__ float T[64][65];
  int b = blk0 >> 2, lt = blk0 & 3;
  int l0 = lt * 64;
  float4 acc[4];
#pragma unroll
  for (int p = 0; p < 4; ++p) acc[p] = make_float4(0.f, 0.f, 0.f, 0.f);
  for (int h = 0; h < NH; ++h) {
    size_t src = (size_t)(b * NH + h) * IDF * LL;
#pragma unroll
    for (int p = 0; p < 4; ++p) {
      int f = tid + p * 256;
      int i = f >> 4, lc = (f & 15) * 4;
      ushort4 u = *reinterpret_cast<const ushort4*>(&P16[src + i * LL + l0 + lc]);
      acc[p].x += h2f(u.x); acc[p].y += h2f(u.y);
      acc[p].z += h2f(u.z); acc[p].w += h2f(u.w);
    }
  }
#pragma unroll
  for (int p = 0; p < 4; ++p) {
    int f = tid + p * 256;
    int i = f >> 4, lc = (f & 15) * 4;
    T[i][lc + 0] = acc[p].x; T[i][lc + 1] = acc[p].y;
    T[i][lc + 2] = acc[p].z; T[i][lc + 3] = acc[p].w;
  }
  __syncthreads();
#pragma unroll
  for (int p = 0; p < 4; ++p) {
    int f = tid + p * 256;
    int lr = f >> 4, ic = (f & 15) * 4;
    float4 v = {T[ic + 0][lr], T[ic + 1][lr], T[ic + 2][lr], T[ic + 3][lr]};
    *reinterpret_cast<float4*>(&outa[((size_t)b * LL + l0 + lr) * IDF + ic]) = v;
  }
}

// ---------------------------------------------------------------------------
extern "C" void kernel_launch(void* const* d_in, const int* in_sizes, int n_in,
                              void* d_out, int out_size, void* d_ws, size_t ws_size,
                              hipStream_t stream) {
  const float* wc  = (const float*)d_in[0];   // [32][64][1024]
  const float* ctx = (const float*)d_in[1];   // [32][256][256]
  const float* W   = (const float*)d_in[2];   // [8][1024][256]
  float* out = (float*)d_out;

  const size_t NE = 2097152;   // elems of wc == W == ctx
  const size_t NM = 4194304;   // elems of P == N2
  unsigned short* p = (unsigned short*)d_ws;
  unsigned short *wc16 = p;   p += NE;
  unsigned short *Wt16 = p;   p += NE;
  unsigned short *W16  = p;   p += NE;
  unsigned short *ctx16 = p;  p += NE;
  unsigned short *cT16 = p;   p += NE;
  unsigned short *P16  = p;   p += NM;
  unsigned short *N216 = p;   p += NM;
  float* Pbuf = (float*)p;    // 2.1M floats

  k_prep  <<<7168, 256, 0, stream>>>(wc, W, ctx, wc16, W16, ctx16, Wt16, cT16);
  k123    <<<BB * NH, 512, 0, stream>>>(wc16, Wt16, cT16, ctx16, P16, N216);
  k4_mfma <<<512, 256, 0, stream>>>(N216, W16, out, Pbuf);
  k_epi   <<<2176, 256, 0, stream>>>(P16, out + (size_t)BB * IDF * SSZ, out, Pbuf);
}